// Round 1
// baseline (2157.035 us; speedup 1.0000x reference)
//
#include <hip/hip_runtime.h>
#include <hip/hip_bf16.h>
#include <math.h>

// ---------------- problem constants ----------------
#define NN 30000
#define EE 480000
#define ET (EE + NN)   // edges + self loops = 510000
#define NEG_SLOPE 0.2f
#define BN_EPS 1e-5f

struct LayerCfg { int cin, C, H; };
static const LayerCfg g_cfg[5] = {
    {128, 100, 5}, {500, 50, 5}, {250, 32, 4}, {128, 8, 4}, {32, 1, 1}
};

// ---------------- kernels ----------------

// Sum of edge weights (for self-loop fill value = mean)
__global__ void ewsum_kernel(const float* __restrict__ ew, float* __restrict__ out, int E) {
    __shared__ float sdata[256];
    int tid = threadIdx.x;
    float s = 0.f;
    for (int i = blockIdx.x * blockDim.x + tid; i < E; i += gridDim.x * blockDim.x)
        s += ew[i];
    sdata[tid] = s;
    __syncthreads();
    for (int off = 128; off > 0; off >>= 1) {
        if (tid < off) sdata[tid] += sdata[tid + off];
        __syncthreads();
    }
    if (tid == 0) atomicAdd(out, sdata[0]);
}

// Build src/dst/ea arrays with self loops appended
__global__ void build_edges_kernel(const int* __restrict__ ei, const float* __restrict__ ew,
                                   const float* __restrict__ sum,
                                   int* __restrict__ srcv, int* __restrict__ dstv,
                                   float* __restrict__ ea) {
    int e = blockIdx.x * blockDim.x + threadIdx.x;
    if (e >= ET) return;
    if (e < EE) {
        srcv[e] = ei[e];
        dstv[e] = ei[EE + e];
        ea[e]   = ew[e];
    } else {
        int n = e - EE;
        srcv[e] = n;
        dstv[e] = n;
        ea[e]   = sum[0] * (1.0f / (float)EE);
    }
}

__global__ void count_kernel(const int* __restrict__ dstv, int* __restrict__ cnt) {
    int e = blockIdx.x * blockDim.x + threadIdx.x;
    if (e >= ET) return;
    atomicAdd(&cnt[dstv[e]], 1);
}

// Single-block exclusive scan over N counts -> off[N+1], wptr copy
__global__ void scan_kernel(const int* __restrict__ cnt, int* __restrict__ off,
                            int* __restrict__ wptr) {
    __shared__ int lsum[1024];
    __shared__ int loff[1024];
    const int T = 1024;
    int t = threadIdx.x;
    int chunk = (NN + T - 1) / T;   // 30
    int base = t * chunk;
    int end = min(NN, base + chunk);
    int s = 0;
    for (int i = base; i < end; i++) s += cnt[i];
    lsum[t] = s;
    __syncthreads();
    if (t == 0) {
        int run = 0;
        for (int i = 0; i < T; i++) { loff[i] = run; run += lsum[i]; }
    }
    __syncthreads();
    int run = loff[t];
    for (int i = base; i < end; i++) {
        off[i] = run;
        wptr[i] = run;
        run += cnt[i];
    }
    if (t == 0) off[NN] = ET;
}

__global__ void fill_kernel(const int* __restrict__ dstv, int* __restrict__ wptr,
                            int* __restrict__ eid) {
    int e = blockIdx.x * blockDim.x + threadIdx.x;
    if (e >= ET) return;
    int p = atomicAdd(&wptr[dstv[e]], 1);
    eid[p] = e;
}

// we_dot[h] = sum_c We[h*C+c] * a_e[h*C+c]
__global__ void wedot_kernel(const float* __restrict__ We, const float* __restrict__ a_e,
                             float* __restrict__ we_dot, int H, int C) {
    int hd = threadIdx.x;
    if (hd < H) {
        float s = 0.f;
        for (int c = 0; c < C; c++) s += We[hd * C + c] * a_e[hd * C + c];
        we_dot[hd] = s;
    }
}

// C[M,Nc] = A[M,K] @ B[K,Nc]  (f32, 64x64 tile, 4x4 microtile, 256 thr)
#define BM 64
#define BN 64
#define BKK 16
__global__ __launch_bounds__(256) void gemm_kernel(const float* __restrict__ A,
                                                   const float* __restrict__ B,
                                                   float* __restrict__ Cm,
                                                   int M, int K, int Nc) {
    __shared__ float As[BKK][BM + 1];
    __shared__ float Bs[BKK][BN + 1];
    int tid = threadIdx.x;
    int tx = tid & 15;   // N dir
    int ty = tid >> 4;   // M dir
    int m0 = blockIdx.y * BM;
    int n0 = blockIdx.x * BN;
    float acc[4][4] = {};
    int ar = tid >> 2;
    int ac0 = (tid & 3) * 4;
    int br = tid >> 4;
    int bc0 = (tid & 15) * 4;
    for (int k0 = 0; k0 < K; k0 += BKK) {
#pragma unroll
        for (int i = 0; i < 4; i++) {
            int m = m0 + ar, k = k0 + ac0 + i;
            As[ac0 + i][ar] = (m < M && k < K) ? A[(size_t)m * K + k] : 0.f;
        }
#pragma unroll
        for (int i = 0; i < 4; i++) {
            int k = k0 + br, n = n0 + bc0 + i;
            Bs[br][bc0 + i] = (k < K && n < Nc) ? B[(size_t)k * Nc + n] : 0.f;
        }
        __syncthreads();
#pragma unroll
        for (int k = 0; k < BKK; k++) {
            float a[4], b[4];
#pragma unroll
            for (int i = 0; i < 4; i++) a[i] = As[k][ty * 4 + i];
#pragma unroll
            for (int j = 0; j < 4; j++) b[j] = Bs[k][tx * 4 + j];
#pragma unroll
            for (int i = 0; i < 4; i++)
#pragma unroll
                for (int j = 0; j < 4; j++)
                    acc[i][j] += a[i] * b[j];
        }
        __syncthreads();
    }
#pragma unroll
    for (int i = 0; i < 4; i++) {
        int m = m0 + ty * 4 + i;
        if (m >= M) continue;
#pragma unroll
        for (int j = 0; j < 4; j++) {
            int n = n0 + tx * 4 + j;
            if (n < Nc) Cm[(size_t)m * Nc + n] = acc[i][j];
        }
    }
}

// al_src/al_dst[n*H+h] = sum_c h[n, h*C+c] * a_{s,d}[h*C+c]
__global__ void al_kernel(const float* __restrict__ h, const float* __restrict__ a_s,
                          const float* __restrict__ a_d, float* __restrict__ al_src,
                          float* __restrict__ al_dst, int H, int C, int NH) {
    int t = blockIdx.x * blockDim.x + threadIdx.x;
    if (t >= NH) return;
    int n = t / H, hd = t % H;
    const float* hp = h + (size_t)n * H * C + hd * C;
    float s1 = 0.f, s2 = 0.f;
    for (int c = 0; c < C; c++) {
        float v = hp[c];
        s1 += v * a_s[hd * C + c];
        s2 += v * a_d[hd * C + c];
    }
    al_src[t] = s1;
    al_dst[t] = s2;
}

__global__ void edge_logit_kernel(const float* __restrict__ al_src,
                                  const float* __restrict__ al_dst,
                                  const float* __restrict__ ea,
                                  const int* __restrict__ srcv, const int* __restrict__ dstv,
                                  const float* __restrict__ we_dot,
                                  float* __restrict__ logit, int H) {
    int e = blockIdx.x * blockDim.x + threadIdx.x;
    if (e >= ET) return;
    int s = srcv[e], d = dstv[e];
    float w = ea[e];
    for (int hd = 0; hd < H; hd++) {
        float l = al_src[s * H + hd] + al_dst[d * H + hd] + w * we_dot[hd];
        logit[(size_t)e * H + hd] = (l >= 0.f) ? l : NEG_SLOPE * l;
    }
}

// per (n, h): segment softmax over in-edges; alpha written in-place into logit
__global__ void softmax_kernel(float* __restrict__ logit, const int* __restrict__ off,
                               const int* __restrict__ eid, int H, int NH) {
    int t = blockIdx.x * blockDim.x + threadIdx.x;
    if (t >= NH) return;
    int n = t / H, hd = t % H;
    int s = off[n], e = off[n + 1];
    float m = -INFINITY;
    for (int i = s; i < e; i++) m = fmaxf(m, logit[(size_t)eid[i] * H + hd]);
    float den = 0.f;
    for (int i = s; i < e; i++) den += __expf(logit[(size_t)eid[i] * H + hd] - m);
    float inv = 1.f / fmaxf(den, 1e-16f);
    for (int i = s; i < e; i++) {
        size_t idx = (size_t)eid[i] * H + hd;
        logit[idx] = __expf(logit[idx] - m) * inv;
    }
}

// out[n, j] = bias[j] + sum_{in-edges e} alpha[e, j/C] * h[src(e), j]
__global__ void aggregate_kernel(const float* __restrict__ hfeat,
                                 const float* __restrict__ alpha,
                                 const int* __restrict__ off, const int* __restrict__ eid,
                                 const int* __restrict__ srcv,
                                 const float* __restrict__ bias, float* __restrict__ out,
                                 int H, int C, int HC) {
    int n = blockIdx.x;
    int j = blockIdx.y * blockDim.x + threadIdx.x;
    if (j >= HC) return;
    int hd = j / C;
    int s = off[n], e = off[n + 1];
    float acc = 0.f;
    for (int i = s; i < e; i++) {
        int ed = eid[i];
        acc += alpha[(size_t)ed * H + hd] * hfeat[(size_t)srcv[ed] * HC + j];
    }
    out[(size_t)n * HC + j] = acc + bias[j];
}

// BN stats stage 1: per-column sum & sumsq partials (coalesced rows, <=512 cols)
__global__ void bn_stats_kernel(const float* __restrict__ x, float* __restrict__ colsum,
                                float* __restrict__ colsumsq, int D) {
    int rows_per_block = (NN + gridDim.x - 1) / gridDim.x;
    int r0 = blockIdx.x * rows_per_block;
    int r1 = min(NN, r0 + rows_per_block);
    int c0 = threadIdx.x;
    int c1 = threadIdx.x + 256;
    float s0 = 0.f, q0 = 0.f, s1 = 0.f, q1 = 0.f;
    for (int r = r0; r < r1; r++) {
        const float* row = x + (size_t)r * D;
        if (c0 < D) { float v = row[c0]; s0 += v; q0 += v * v; }
        if (c1 < D) { float v = row[c1]; s1 += v; q1 += v * v; }
    }
    if (c0 < D) { atomicAdd(&colsum[c0], s0); atomicAdd(&colsumsq[c0], q0); }
    if (c1 < D) { atomicAdd(&colsum[c1], s1); atomicAdd(&colsumsq[c1], q1); }
}

__global__ void bn_scale_kernel(const float* __restrict__ colsum,
                                const float* __restrict__ colsumsq,
                                const float* __restrict__ g, const float* __restrict__ beta,
                                float* __restrict__ scale, float* __restrict__ shift, int D) {
    int c = blockIdx.x * blockDim.x + threadIdx.x;
    if (c >= D) return;
    float mu = colsum[c] / (float)NN;
    float var = colsumsq[c] / (float)NN - mu * mu;
    float sc = g[c] * rsqrtf(var + BN_EPS);
    scale[c] = sc;
    shift[c] = beta[c] - mu * sc;
}

__global__ void bn_relu_kernel(float* __restrict__ x, const float* __restrict__ scale,
                               const float* __restrict__ shift, int total, int D) {
    for (int i = blockIdx.x * blockDim.x + threadIdx.x; i < total; i += gridDim.x * blockDim.x) {
        int c = i % D;
        float v = x[i] * scale[c] + shift[c];
        x[i] = fmaxf(v, 0.f);
    }
}

__global__ void relu_kernel(float* __restrict__ x, int total) {
    for (int i = blockIdx.x * blockDim.x + threadIdx.x; i < total; i += gridDim.x * blockDim.x)
        x[i] = fmaxf(x[i], 0.f);
}

// ---------------- host orchestration ----------------

static inline size_t align_up(size_t v, size_t a) { return (v + a - 1) / a * a; }

extern "C" void kernel_launch(void* const* d_in, const int* in_sizes, int n_in,
                              void* d_out, int out_size, void* d_ws, size_t ws_size,
                              hipStream_t stream) {
    const float* x_in = (const float*)d_in[0];
    const int* ei     = (const int*)d_in[1];
    const float* ew   = (const float*)d_in[2];

    // workspace carve-up
    char* p = (char*)d_ws;
    size_t off_b = 0;
    auto alloc = [&](size_t bytes) -> void* {
        void* r = p + off_b;
        off_b = align_up(off_b + bytes, 256);
        return r;
    };
    float* B0      = (float*)alloc((size_t)NN * 500 * 4);   // h buffer
    float* B1      = (float*)alloc((size_t)NN * 500 * 4);   // activation buffer
    float* logit   = (float*)alloc((size_t)ET * 5 * 4);     // logit/alpha
    float* al_src  = (float*)alloc((size_t)NN * 5 * 4);
    float* al_dst  = (float*)alloc((size_t)NN * 5 * 4);
    float* ea      = (float*)alloc((size_t)ET * 4);
    int* srcv      = (int*)alloc((size_t)ET * 4);
    int* dstv      = (int*)alloc((size_t)ET * 4);
    int* eid       = (int*)alloc((size_t)ET * 4);
    int* offarr    = (int*)alloc((size_t)(NN + 1) * 4);
    int* wptr      = (int*)alloc((size_t)NN * 4);
    int* cnt       = (int*)alloc((size_t)NN * 4);
    float* esum    = (float*)alloc(4);
    float* we_dot  = (float*)alloc(8 * 4);
    float* colsum  = (float*)alloc(512 * 4);
    float* colsumsq= (float*)alloc(512 * 4);
    float* scale   = (float*)alloc(512 * 4);
    float* shift   = (float*)alloc(512 * 4);
    (void)ws_size; (void)n_in; (void)in_sizes; (void)out_size;

    // graph & CSR build (once per launch)
    hipMemsetAsync(esum, 0, 4, stream);
    hipMemsetAsync(cnt, 0, (size_t)NN * 4, stream);
    ewsum_kernel<<<256, 256, 0, stream>>>(ew, esum, EE);
    int ebl = (ET + 255) / 256;
    build_edges_kernel<<<ebl, 256, 0, stream>>>(ei, ew, esum, srcv, dstv, ea);
    count_kernel<<<ebl, 256, 0, stream>>>(dstv, cnt);
    scan_kernel<<<1, 1024, 0, stream>>>(cnt, offarr, wptr);
    fill_kernel<<<ebl, 256, 0, stream>>>(dstv, wptr, eid);

    int bn_idx = 0;
    for (int l = 0; l < 5; l++) {
        const LayerCfg& cf = g_cfg[l];
        int H = cf.H, C = cf.C, K = cf.cin;
        int HC = H * C;
        const float* W   = (const float*)d_in[3 + l * 6 + 0];
        const float* a_s = (const float*)d_in[3 + l * 6 + 1];
        const float* a_d = (const float*)d_in[3 + l * 6 + 2];
        const float* We  = (const float*)d_in[3 + l * 6 + 3];
        const float* a_e = (const float*)d_in[3 + l * 6 + 4];
        const float* b   = (const float*)d_in[3 + l * 6 + 5];

        const float* X = (l == 0) ? x_in : B1;
        float* hbuf = B0;
        float* outbuf = (l == 4) ? (float*)d_out : B1;

        wedot_kernel<<<1, 8, 0, stream>>>(We, a_e, we_dot, H, C);

        dim3 ggrid((HC + BN - 1) / BN, (NN + BM - 1) / BM);
        gemm_kernel<<<ggrid, 256, 0, stream>>>(X, W, hbuf, NN, K, HC);

        int NH = NN * H;
        al_kernel<<<(NH + 255) / 256, 256, 0, stream>>>(hbuf, a_s, a_d, al_src, al_dst, H, C, NH);
        edge_logit_kernel<<<ebl, 256, 0, stream>>>(al_src, al_dst, ea, srcv, dstv, we_dot, logit, H);
        softmax_kernel<<<(NH + 255) / 256, 256, 0, stream>>>(logit, offarr, eid, H, NH);

        dim3 agrid(NN, (HC + 255) / 256);
        aggregate_kernel<<<agrid, 256, 0, stream>>>(hbuf, logit, offarr, eid, srcv, b, outbuf, H, C, HC);

        int total = NN * HC;
        if (l < 3) {
            int D = HC;
            const float* g    = (const float*)d_in[33 + bn_idx * 2 + 0];
            const float* beta = (const float*)d_in[33 + bn_idx * 2 + 1];
            hipMemsetAsync(colsum, 0, 512 * 4, stream);
            hipMemsetAsync(colsumsq, 0, 512 * 4, stream);
            bn_stats_kernel<<<256, 256, 0, stream>>>(outbuf, colsum, colsumsq, D);
            bn_scale_kernel<<<(D + 255) / 256, 256, 0, stream>>>(colsum, colsumsq, g, beta, scale, shift, D);
            bn_relu_kernel<<<2048, 256, 0, stream>>>(outbuf, scale, shift, total, D);
            bn_idx++;
        } else if (l == 3) {
            relu_kernel<<<1024, 256, 0, stream>>>(outbuf, total);
        }
    }
}

// Round 3
// 1713.302 us; speedup vs baseline: 1.2590x; 1.2590x over previous
//
#include <hip/hip_runtime.h>
#include <hip/hip_bf16.h>
#include <math.h>

// ---------------- problem constants ----------------
#define NN 30000
#define EE 480000
#define ET (EE + NN)   // edges + self loops = 510000
#define NEG_SLOPE 0.2f
#define BN_EPS 1e-5f

struct LayerCfg { int cin, C, H; };
static const LayerCfg g_cfg[5] = {
    {128, 100, 5}, {500, 50, 5}, {250, 32, 4}, {128, 8, 4}, {32, 1, 1}
};

typedef short short8 __attribute__((ext_vector_type(8)));
typedef float f32x4 __attribute__((ext_vector_type(4)));

__device__ __forceinline__ unsigned short f2bf(float f) {
    unsigned int u = __builtin_bit_cast(unsigned int, f);
    u = (u + 0x7FFFu + ((u >> 16) & 1u)) >> 16;
    return (unsigned short)u;
}
__device__ __forceinline__ float bf2f(unsigned short h) {
    unsigned int u = ((unsigned int)h) << 16;
    return __builtin_bit_cast(float, u);
}

// ---------------- graph / CSR kernels ----------------

__global__ void ewsum_kernel(const float* __restrict__ ew, float* __restrict__ out, int E) {
    __shared__ float sdata[256];
    int tid = threadIdx.x;
    float s = 0.f;
    for (int i = blockIdx.x * blockDim.x + tid; i < E; i += gridDim.x * blockDim.x)
        s += ew[i];
    sdata[tid] = s;
    __syncthreads();
    for (int off = 128; off > 0; off >>= 1) {
        if (tid < off) sdata[tid] += sdata[tid + off];
        __syncthreads();
    }
    if (tid == 0) atomicAdd(out, sdata[0]);
}

__global__ void build_edges_kernel(const int* __restrict__ ei, const float* __restrict__ ew,
                                   const float* __restrict__ sum,
                                   int* __restrict__ srcv, int* __restrict__ dstv,
                                   float* __restrict__ ea) {
    int e = blockIdx.x * blockDim.x + threadIdx.x;
    if (e >= ET) return;
    if (e < EE) {
        srcv[e] = ei[e];
        dstv[e] = ei[EE + e];
        ea[e]   = ew[e];
    } else {
        int n = e - EE;
        srcv[e] = n;
        dstv[e] = n;
        ea[e]   = sum[0] * (1.0f / (float)EE);
    }
}

__global__ void count_kernel(const int* __restrict__ dstv, int* __restrict__ cnt) {
    int e = blockIdx.x * blockDim.x + threadIdx.x;
    if (e >= ET) return;
    atomicAdd(&cnt[dstv[e]], 1);
}

__global__ void scan_kernel(const int* __restrict__ cnt, int* __restrict__ off,
                            int* __restrict__ wptr) {
    __shared__ int lsum[1024];
    __shared__ int loff[1024];
    const int T = 1024;
    int t = threadIdx.x;
    int chunk = (NN + T - 1) / T;
    int base = t * chunk;
    int end = min(NN, base + chunk);
    int s = 0;
    for (int i = base; i < end; i++) s += cnt[i];
    lsum[t] = s;
    __syncthreads();
    if (t == 0) {
        int run = 0;
        for (int i = 0; i < T; i++) { loff[i] = run; run += lsum[i]; }
    }
    __syncthreads();
    int run = loff[t];
    for (int i = base; i < end; i++) {
        off[i] = run;
        wptr[i] = run;
        run += cnt[i];
    }
    if (t == 0) off[NN] = ET;
}

// emits inverse permutation (pose) and CSR-ordered src list
__global__ void fill_kernel(const int* __restrict__ dstv, const int* __restrict__ srcv,
                            int* __restrict__ wptr, int* __restrict__ pose,
                            int* __restrict__ csr_src) {
    int e = blockIdx.x * blockDim.x + threadIdx.x;
    if (e >= ET) return;
    int p = atomicAdd(&wptr[dstv[e]], 1);
    pose[e] = p;
    csr_src[p] = srcv[e];
}

// ---------------- per-layer small kernels ----------------

__global__ void wedot_kernel(const float* __restrict__ We, const float* __restrict__ a_e,
                             float* __restrict__ we_dot, int H, int C) {
    int hd = threadIdx.x;
    if (hd < H) {
        float s = 0.f;
        for (int c = 0; c < C; c++) s += We[hd * C + c] * a_e[hd * C + c];
        we_dot[hd] = s;
    }
}

// transpose + split f32 -> (hi,lo) bf16 + zero-pad: W[K,N] -> Wt_hi/Wt_lo[Npad][Kpad]
__global__ void transpose_pad_kernel(const float* __restrict__ B,
                                     unsigned short* __restrict__ Bt_hi,
                                     unsigned short* __restrict__ Bt_lo,
                                     int K, int N, int Kpad, int Npad) {
    __shared__ float tile[32][33];
    int kb = blockIdx.x * 32, nb = blockIdx.y * 32;
    int tx = threadIdx.x, ty = threadIdx.y;   // 32 x 8
#pragma unroll
    for (int i = 0; i < 4; i++) {
        int k = kb + ty + i * 8, n = nb + tx;
        tile[ty + i * 8][tx] = (k < K && n < N) ? B[(size_t)k * N + n] : 0.f;
    }
    __syncthreads();
#pragma unroll
    for (int i = 0; i < 4; i++) {
        int n = nb + ty + i * 8, k = kb + tx;
        if (n < Npad && k < Kpad) {
            float v = tile[tx][ty + i * 8];
            unsigned short hi = f2bf(v);
            unsigned short lo = f2bf(v - bf2f(hi));
            size_t idx = (size_t)n * Kpad + k;
            Bt_hi[idx] = hi;
            Bt_lo[idx] = lo;
        }
    }
}

// ---------------- split-bf16 MFMA GEMM: C[M,Nc](f32) = A[M,K](f32) @ W ----------------
// a = hi + lo; a*b ~= hi*hi + hi*lo + lo*hi (3 MFMAs, ~f32 precision)
#define GBM 128
#define GBNT 128
#define GBK 32
#define ASTR 40   // shorts per LDS row (32 data + 8 pad)
__global__ __launch_bounds__(256) void gemm_split_kernel(const float* __restrict__ A,
                                                         const unsigned short* __restrict__ Bt_hi,
                                                         const unsigned short* __restrict__ Bt_lo,
                                                         float* __restrict__ Cm,
                                                         int M, int K, int Nc, int Kpad) {
    __shared__ short AsH[GBM * ASTR];
    __shared__ short AsL[GBM * ASTR];
    __shared__ short BsH[GBNT * ASTR];
    __shared__ short BsL[GBNT * ASTR];
    int tid = threadIdx.x;
    int wave = tid >> 6, lane = tid & 63;
    int q = lane >> 4, r = lane & 15;
    int m0 = blockIdx.y * GBM, n0 = blockIdx.x * GBNT;
    int wm = (wave & 1) * 64, wn = (wave >> 1) * 64;
    f32x4 acc[4][4];
#pragma unroll
    for (int i = 0; i < 4; i++)
#pragma unroll
        for (int j = 0; j < 4; j++) acc[i][j] = (f32x4)(0.f);

    int arow = tid >> 3;           // 0..31
    int alk  = tid & 7;            // 0..7
    int brow = tid >> 2;           // 0..63
    int bcol = (tid & 3) * 8;      // 0,8,16,24

    int ksteps = (K + GBK - 1) / GBK;
    for (int ks = 0; ks < ksteps; ks++) {
        int k0 = ks * GBK;
        // ---- stage A (f32 -> hi/lo bf16), 128 rows x 32 k ----
#pragma unroll
        for (int p = 0; p < 4; p++) {
            int row = p * 32 + arow;
            int m = m0 + row;
#pragma unroll
            for (int i = 0; i < 4; i++) {
                int k = alk + 8 * i;
                float v = 0.f;
                if (m < M && (k0 + k) < K) v = A[(size_t)m * K + k0 + k];
                unsigned short hi = f2bf(v);
                unsigned short lo = f2bf(v - bf2f(hi));
                AsH[row * ASTR + k] = (short)hi;
                AsL[row * ASTR + k] = (short)lo;
            }
        }
        // ---- stage B from padded planes ----
#pragma unroll
        for (int p = 0; p < 2; p++) {
            int row = p * 64 + brow;
            size_t gidx = (size_t)(n0 + row) * Kpad + k0 + bcol;
            *((uint4*)(BsH + row * ASTR + bcol)) = *((const uint4*)(Bt_hi + gidx));
            *((uint4*)(BsL + row * ASTR + bcol)) = *((const uint4*)(Bt_lo + gidx));
        }
        __syncthreads();
        // ---- MFMA: hi*hi + hi*lo + lo*hi ----
        short8 ah[4], al[4], bh[4], bl[4];
#pragma unroll
        for (int i = 0; i < 4; i++) {
            ah[i] = *((const short8*)(AsH + (wm + i * 16 + r) * ASTR + q * 8));
            al[i] = *((const short8*)(AsL + (wm + i * 16 + r) * ASTR + q * 8));
        }
#pragma unroll
        for (int j = 0; j < 4; j++) {
            bh[j] = *((const short8*)(BsH + (wn + j * 16 + r) * ASTR + q * 8));
            bl[j] = *((const short8*)(BsL + (wn + j * 16 + r) * ASTR + q * 8));
        }
#pragma unroll
        for (int i = 0; i < 4; i++)
#pragma unroll
            for (int j = 0; j < 4; j++) {
                acc[i][j] = __builtin_amdgcn_mfma_f32_16x16x32_bf16(ah[i], bh[j], acc[i][j], 0, 0, 0);
                acc[i][j] = __builtin_amdgcn_mfma_f32_16x16x32_bf16(ah[i], bl[j], acc[i][j], 0, 0, 0);
                acc[i][j] = __builtin_amdgcn_mfma_f32_16x16x32_bf16(al[i], bh[j], acc[i][j], 0, 0, 0);
            }
        __syncthreads();
    }
    // ---- epilogue: f32 store ----
#pragma unroll
    for (int i = 0; i < 4; i++) {
#pragma unroll
        for (int j = 0; j < 4; j++) {
#pragma unroll
            for (int reg = 0; reg < 4; reg++) {
                int mrow = m0 + wm + i * 16 + q * 4 + reg;
                int ncol = n0 + wn + j * 16 + r;
                if (mrow < M && ncol < Nc)
                    Cm[(size_t)mrow * Nc + ncol] = acc[i][j][reg];
            }
        }
    }
}

// al_src/al_dst[n*H+h] = sum_c h[n, h*C+c] * a_{s,d}[h*C+c]
__global__ void al_kernel(const float* __restrict__ h, const float* __restrict__ a_s,
                          const float* __restrict__ a_d, float* __restrict__ al_src,
                          float* __restrict__ al_dst, int H, int C, int NH) {
    int t = blockIdx.x * blockDim.x + threadIdx.x;
    if (t >= NH) return;
    int n = t / H, hd = t % H;
    const float* hp = h + (size_t)n * H * C + hd * C;
    float s1 = 0.f, s2 = 0.f;
    for (int c = 0; c < C; c++) {
        float v = hp[c];
        s1 += v * a_s[hd * C + c];
        s2 += v * a_d[hd * C + c];
    }
    al_src[t] = s1;
    al_dst[t] = s2;
}

// writes leaky-relu logits at CSR position
__global__ void edge_logit_kernel(const float* __restrict__ al_src,
                                  const float* __restrict__ al_dst,
                                  const float* __restrict__ ea,
                                  const int* __restrict__ srcv, const int* __restrict__ dstv,
                                  const int* __restrict__ pose,
                                  const float* __restrict__ we_dot,
                                  float* __restrict__ logit, int H) {
    int e = blockIdx.x * blockDim.x + threadIdx.x;
    if (e >= ET) return;
    int s = srcv[e], d = dstv[e];
    int p = pose[e];
    float w = ea[e];
    for (int hd = 0; hd < H; hd++) {
        float l = al_src[s * H + hd] + al_dst[d * H + hd] + w * we_dot[hd];
        logit[(size_t)p * H + hd] = (l >= 0.f) ? l : NEG_SLOPE * l;
    }
}

// per (n, h): segment softmax over CSR range; alpha in-place
__global__ void softmax_kernel(float* __restrict__ logit, const int* __restrict__ off,
                               int H, int NH) {
    int t = blockIdx.x * blockDim.x + threadIdx.x;
    if (t >= NH) return;
    int n = t / H, hd = t % H;
    int s = off[n], e = off[n + 1];
    float m = -INFINITY;
    for (int p = s; p < e; p++) m = fmaxf(m, logit[(size_t)p * H + hd]);
    float den = 0.f;
    for (int p = s; p < e; p++) den += __expf(logit[(size_t)p * H + hd] - m);
    float inv = 1.f / fmaxf(den, 1e-16f);
    for (int p = s; p < e; p++) {
        size_t idx = (size_t)p * H + hd;
        logit[idx] = __expf(logit[idx] - m) * inv;
    }
}

// out[n, j] = bias[j] + sum_{p in CSR(n)} alpha[p, j/C] * h[csr_src[p], j]
__global__ void aggregate_kernel(const float* __restrict__ hfeat,
                                 const float* __restrict__ alpha,
                                 const int* __restrict__ off, const int* __restrict__ csr_src,
                                 const float* __restrict__ bias, float* __restrict__ out,
                                 int H, int C, int HC, int total) {
    int t = blockIdx.x * blockDim.x + threadIdx.x;
    if (t >= total) return;
    int n = t / HC, j = t - n * HC;
    int hd = j / C;
    int s = off[n], e = off[n + 1];
    float acc = 0.f;
    for (int p = s; p < e; p++) {
        acc += alpha[(size_t)p * H + hd] * hfeat[(size_t)csr_src[p] * HC + j];
    }
    out[(size_t)n * HC + j] = acc + bias[j];
}

// ---------------- BN / activations ----------------

__global__ void bn_stats_kernel(const float* __restrict__ x, float* __restrict__ colsum,
                                float* __restrict__ colsumsq, int D) {
    int rows_per_block = (NN + gridDim.x - 1) / gridDim.x;
    int r0 = blockIdx.x * rows_per_block;
    int r1 = min(NN, r0 + rows_per_block);
    int c0 = threadIdx.x;
    int c1 = threadIdx.x + 256;
    float s0 = 0.f, q0 = 0.f, s1 = 0.f, q1 = 0.f;
    for (int r = r0; r < r1; r++) {
        const float* row = x + (size_t)r * D;
        if (c0 < D) { float v = row[c0]; s0 += v; q0 += v * v; }
        if (c1 < D) { float v = row[c1]; s1 += v; q1 += v * v; }
    }
    if (c0 < D) { atomicAdd(&colsum[c0], s0); atomicAdd(&colsumsq[c0], q0); }
    if (c1 < D) { atomicAdd(&colsum[c1], s1); atomicAdd(&colsumsq[c1], q1); }
}

__global__ void bn_scale_kernel(const float* __restrict__ colsum,
                                const float* __restrict__ colsumsq,
                                const float* __restrict__ g, const float* __restrict__ beta,
                                float* __restrict__ scale, float* __restrict__ shift, int D) {
    int c = blockIdx.x * blockDim.x + threadIdx.x;
    if (c >= D) return;
    float mu = colsum[c] / (float)NN;
    float var = colsumsq[c] / (float)NN - mu * mu;
    float sc = g[c] * rsqrtf(var + BN_EPS);
    scale[c] = sc;
    shift[c] = beta[c] - mu * sc;
}

__global__ void bn_relu_kernel(float* __restrict__ x, const float* __restrict__ scale,
                               const float* __restrict__ shift, int total, int D) {
    for (int i = blockIdx.x * blockDim.x + threadIdx.x; i < total; i += gridDim.x * blockDim.x) {
        int c = i % D;
        float v = x[i] * scale[c] + shift[c];
        x[i] = fmaxf(v, 0.f);
    }
}

__global__ void relu_kernel(float* __restrict__ x, int total) {
    for (int i = blockIdx.x * blockDim.x + threadIdx.x; i < total; i += gridDim.x * blockDim.x)
        x[i] = fmaxf(x[i], 0.f);
}

// ---------------- host orchestration ----------------

static inline size_t align_up(size_t v, size_t a) { return (v + a - 1) / a * a; }

extern "C" void kernel_launch(void* const* d_in, const int* in_sizes, int n_in,
                              void* d_out, int out_size, void* d_ws, size_t ws_size,
                              hipStream_t stream) {
    const float* x_in = (const float*)d_in[0];
    const int* ei     = (const int*)d_in[1];
    const float* ew   = (const float*)d_in[2];

    char* pws = (char*)d_ws;
    size_t off_b = 0;
    auto alloc = [&](size_t bytes) -> void* {
        void* rp = pws + off_b;
        off_b = align_up(off_b + bytes, 256);
        return rp;
    };
    float* B0      = (float*)alloc((size_t)NN * 500 * 4);   // h (f32)
    float* B1      = (float*)alloc((size_t)NN * 500 * 4);   // activations (f32)
    float* logit   = (float*)alloc((size_t)ET * 5 * 4);
    unsigned short* Wt_hi = (unsigned short*)alloc((size_t)512 * 512 * 2);
    unsigned short* Wt_lo = (unsigned short*)alloc((size_t)512 * 512 * 2);
    float* al_src  = (float*)alloc((size_t)NN * 5 * 4);
    float* al_dst  = (float*)alloc((size_t)NN * 5 * 4);
    float* ea      = (float*)alloc((size_t)ET * 4);
    int* srcv      = (int*)alloc((size_t)ET * 4);
    int* dstv      = (int*)alloc((size_t)ET * 4);
    int* pose      = (int*)alloc((size_t)ET * 4);
    int* csr_src   = (int*)alloc((size_t)ET * 4);
    int* offarr    = (int*)alloc((size_t)(NN + 1) * 4);
    int* wptr      = (int*)alloc((size_t)NN * 4);
    int* cnt       = (int*)alloc((size_t)NN * 4);
    float* esum    = (float*)alloc(4);
    float* we_dot  = (float*)alloc(8 * 4);
    float* colsum  = (float*)alloc(512 * 4);
    float* colsumsq= (float*)alloc(512 * 4);
    float* scale   = (float*)alloc(512 * 4);
    float* shift   = (float*)alloc(512 * 4);
    (void)ws_size; (void)n_in; (void)in_sizes; (void)out_size;

    // graph & CSR build
    hipMemsetAsync(esum, 0, 4, stream);
    hipMemsetAsync(cnt, 0, (size_t)NN * 4, stream);
    ewsum_kernel<<<256, 256, 0, stream>>>(ew, esum, EE);
    int ebl = (ET + 255) / 256;
    build_edges_kernel<<<ebl, 256, 0, stream>>>(ei, ew, esum, srcv, dstv, ea);
    count_kernel<<<ebl, 256, 0, stream>>>(dstv, cnt);
    scan_kernel<<<1, 1024, 0, stream>>>(cnt, offarr, wptr);
    fill_kernel<<<ebl, 256, 0, stream>>>(dstv, srcv, wptr, pose, csr_src);

    int bn_idx = 0;
    for (int l = 0; l < 5; l++) {
        const LayerCfg& cf = g_cfg[l];
        int H = cf.H, C = cf.C, K = cf.cin;
        int HC = H * C;
        int Kpad = (K + 31) / 32 * 32;
        int Npad = (HC + 127) / 128 * 128;
        const float* W   = (const float*)d_in[3 + l * 6 + 0];
        const float* a_s = (const float*)d_in[3 + l * 6 + 1];
        const float* a_d = (const float*)d_in[3 + l * 6 + 2];
        const float* We  = (const float*)d_in[3 + l * 6 + 3];
        const float* a_e = (const float*)d_in[3 + l * 6 + 4];
        const float* b   = (const float*)d_in[3 + l * 6 + 5];

        const float* X = (l == 0) ? x_in : B1;
        float* hbuf = B0;
        float* outbuf = (l == 4) ? (float*)d_out : B1;

        wedot_kernel<<<1, 8, 0, stream>>>(We, a_e, we_dot, H, C);

        dim3 tgrid((Kpad + 31) / 32, (Npad + 31) / 32);
        transpose_pad_kernel<<<tgrid, dim3(32, 8), 0, stream>>>(W, Wt_hi, Wt_lo, K, HC, Kpad, Npad);

        dim3 ggrid(Npad / GBNT, (NN + GBM - 1) / GBM);
        gemm_split_kernel<<<ggrid, 256, 0, stream>>>(X, Wt_hi, Wt_lo, hbuf, NN, K, HC, Kpad);

        int NH = NN * H;
        al_kernel<<<(NH + 255) / 256, 256, 0, stream>>>(hbuf, a_s, a_d, al_src, al_dst, H, C, NH);
        edge_logit_kernel<<<ebl, 256, 0, stream>>>(al_src, al_dst, ea, srcv, dstv, pose, we_dot, logit, H);
        softmax_kernel<<<(NH + 255) / 256, 256, 0, stream>>>(logit, offarr, H, NH);

        int total = NN * HC;
        aggregate_kernel<<<(total + 255) / 256, 256, 0, stream>>>(hbuf, logit, offarr, csr_src, b, outbuf, H, C, HC, total);

        if (l < 3) {
            int D = HC;
            const float* g    = (const float*)d_in[33 + bn_idx * 2 + 0];
            const float* beta = (const float*)d_in[33 + bn_idx * 2 + 1];
            hipMemsetAsync(colsum, 0, 512 * 4, stream);
            hipMemsetAsync(colsumsq, 0, 512 * 4, stream);
            bn_stats_kernel<<<256, 256, 0, stream>>>(outbuf, colsum, colsumsq, D);
            bn_scale_kernel<<<(D + 255) / 256, 256, 0, stream>>>(colsum, colsumsq, g, beta, scale, shift, D);
            bn_relu_kernel<<<2048, 256, 0, stream>>>(outbuf, scale, shift, total, D);
            bn_idx++;
        } else if (l == 3) {
            relu_kernel<<<1024, 256, 0, stream>>>(outbuf, total);
        }
    }
}

// Round 4
// 1285.482 us; speedup vs baseline: 1.6780x; 1.3328x over previous
//
#include <hip/hip_runtime.h>
#include <hip/hip_bf16.h>
#include <math.h>

// ---------------- problem constants ----------------
#define NN 30000
#define EE 480000
#define ET (EE + NN)   // edges + self loops = 510000
#define NEG_SLOPE 0.2f
#define BN_EPS 1e-5f

struct LayerCfg { int cin, C, H; };
static const LayerCfg g_cfg[5] = {
    {128, 100, 5}, {500, 50, 5}, {250, 32, 4}, {128, 8, 4}, {32, 1, 1}
};

typedef short short8 __attribute__((ext_vector_type(8)));
typedef float f32x4 __attribute__((ext_vector_type(4)));

__device__ __forceinline__ unsigned short f2bf(float f) {
    unsigned int u = __builtin_bit_cast(unsigned int, f);
    u = (u + 0x7FFFu + ((u >> 16) & 1u)) >> 16;
    return (unsigned short)u;
}
__device__ __forceinline__ float bf2f(unsigned short h) {
    unsigned int u = ((unsigned int)h) << 16;
    return __builtin_bit_cast(float, u);
}

// ---------------- graph / CSR kernels ----------------

__global__ void ewsum_kernel(const float* __restrict__ ew, float* __restrict__ out, int E) {
    __shared__ float sdata[256];
    int tid = threadIdx.x;
    float s = 0.f;
    for (int i = blockIdx.x * blockDim.x + tid; i < E; i += gridDim.x * blockDim.x)
        s += ew[i];
    sdata[tid] = s;
    __syncthreads();
    for (int off = 128; off > 0; off >>= 1) {
        if (tid < off) sdata[tid] += sdata[tid + off];
        __syncthreads();
    }
    if (tid == 0) atomicAdd(out, sdata[0]);
}

__global__ void build_edges_kernel(const int* __restrict__ ei, const float* __restrict__ ew,
                                   const float* __restrict__ sum,
                                   int* __restrict__ srcv, int* __restrict__ dstv,
                                   float* __restrict__ ea) {
    int e = blockIdx.x * blockDim.x + threadIdx.x;
    if (e >= ET) return;
    if (e < EE) {
        srcv[e] = ei[e];
        dstv[e] = ei[EE + e];
        ea[e]   = ew[e];
    } else {
        int n = e - EE;
        srcv[e] = n;
        dstv[e] = n;
        ea[e]   = sum[0] * (1.0f / (float)EE);
    }
}

__global__ void count_kernel(const int* __restrict__ dstv, int* __restrict__ cnt) {
    int e = blockIdx.x * blockDim.x + threadIdx.x;
    if (e >= ET) return;
    atomicAdd(&cnt[dstv[e]], 1);
}

__global__ void scan_kernel(const int* __restrict__ cnt, int* __restrict__ off,
                            int* __restrict__ wptr) {
    __shared__ int lsum[1024];
    __shared__ int loff[1024];
    const int T = 1024;
    int t = threadIdx.x;
    int chunk = (NN + T - 1) / T;
    int base = t * chunk;
    int end = min(NN, base + chunk);
    int s = 0;
    for (int i = base; i < end; i++) s += cnt[i];
    lsum[t] = s;
    __syncthreads();
    if (t == 0) {
        int run = 0;
        for (int i = 0; i < T; i++) { loff[i] = run; run += lsum[i]; }
    }
    __syncthreads();
    int run = loff[t];
    for (int i = base; i < end; i++) {
        off[i] = run;
        wptr[i] = run;
        run += cnt[i];
    }
    if (t == 0) off[NN] = ET;
}

// emits CSR-ordered src list and CSR-ordered edge weight
__global__ void fill_kernel(const int* __restrict__ dstv, const int* __restrict__ srcv,
                            const float* __restrict__ ea,
                            int* __restrict__ wptr, int* __restrict__ csr_src,
                            float* __restrict__ csr_ea) {
    int e = blockIdx.x * blockDim.x + threadIdx.x;
    if (e >= ET) return;
    int p = atomicAdd(&wptr[dstv[e]], 1);
    csr_src[p] = srcv[e];
    csr_ea[p]  = ea[e];
}

// ---------------- per-layer small kernels ----------------

__global__ void wedot_kernel(const float* __restrict__ We, const float* __restrict__ a_e,
                             float* __restrict__ we_dot, int H, int C) {
    int hd = threadIdx.x;
    if (hd < H) {
        float s = 0.f;
        for (int c = 0; c < C; c++) s += We[hd * C + c] * a_e[hd * C + c];
        we_dot[hd] = s;
    }
}

// transpose + split f32 -> (hi,lo) bf16 + zero-pad: W[K,N] -> Wt_hi/Wt_lo[Npad][Kpad]
__global__ void transpose_pad_kernel(const float* __restrict__ B,
                                     unsigned short* __restrict__ Bt_hi,
                                     unsigned short* __restrict__ Bt_lo,
                                     int K, int N, int Kpad, int Npad) {
    __shared__ float tile[32][33];
    int kb = blockIdx.x * 32, nb = blockIdx.y * 32;
    int tx = threadIdx.x, ty = threadIdx.y;   // 32 x 8
#pragma unroll
    for (int i = 0; i < 4; i++) {
        int k = kb + ty + i * 8, n = nb + tx;
        tile[ty + i * 8][tx] = (k < K && n < N) ? B[(size_t)k * N + n] : 0.f;
    }
    __syncthreads();
#pragma unroll
    for (int i = 0; i < 4; i++) {
        int n = nb + ty + i * 8, k = kb + tx;
        if (n < Npad && k < Kpad) {
            float v = tile[tx][ty + i * 8];
            unsigned short hi = f2bf(v);
            unsigned short lo = f2bf(v - bf2f(hi));
            size_t idx = (size_t)n * Kpad + k;
            Bt_hi[idx] = hi;
            Bt_lo[idx] = lo;
        }
    }
}

// ---------------- split-bf16 MFMA GEMM: C[M,Nc](f32) = A[M,K](f32) @ W ----------------
#define GBM 128
#define GBNT 128
#define GBK 32
#define ASTR 40
__global__ __launch_bounds__(256) void gemm_split_kernel(const float* __restrict__ A,
                                                         const unsigned short* __restrict__ Bt_hi,
                                                         const unsigned short* __restrict__ Bt_lo,
                                                         float* __restrict__ Cm,
                                                         int M, int K, int Nc, int Kpad) {
    __shared__ short AsH[GBM * ASTR];
    __shared__ short AsL[GBM * ASTR];
    __shared__ short BsH[GBNT * ASTR];
    __shared__ short BsL[GBNT * ASTR];
    int tid = threadIdx.x;
    int wave = tid >> 6, lane = tid & 63;
    int q = lane >> 4, r = lane & 15;
    int m0 = blockIdx.y * GBM, n0 = blockIdx.x * GBNT;
    int wm = (wave & 1) * 64, wn = (wave >> 1) * 64;
    f32x4 acc[4][4];
#pragma unroll
    for (int i = 0; i < 4; i++)
#pragma unroll
        for (int j = 0; j < 4; j++) acc[i][j] = (f32x4)(0.f);

    int arow = tid >> 3;
    int alk  = tid & 7;
    int brow = tid >> 2;
    int bcol = (tid & 3) * 8;

    int ksteps = (K + GBK - 1) / GBK;
    for (int ks = 0; ks < ksteps; ks++) {
        int k0 = ks * GBK;
#pragma unroll
        for (int p = 0; p < 4; p++) {
            int row = p * 32 + arow;
            int m = m0 + row;
#pragma unroll
            for (int i = 0; i < 4; i++) {
                int k = alk + 8 * i;
                float v = 0.f;
                if (m < M && (k0 + k) < K) v = A[(size_t)m * K + k0 + k];
                unsigned short hi = f2bf(v);
                unsigned short lo = f2bf(v - bf2f(hi));
                AsH[row * ASTR + k] = (short)hi;
                AsL[row * ASTR + k] = (short)lo;
            }
        }
#pragma unroll
        for (int p = 0; p < 2; p++) {
            int row = p * 64 + brow;
            size_t gidx = (size_t)(n0 + row) * Kpad + k0 + bcol;
            *((uint4*)(BsH + row * ASTR + bcol)) = *((const uint4*)(Bt_hi + gidx));
            *((uint4*)(BsL + row * ASTR + bcol)) = *((const uint4*)(Bt_lo + gidx));
        }
        __syncthreads();
        short8 ah[4], al[4], bh[4], bl[4];
#pragma unroll
        for (int i = 0; i < 4; i++) {
            ah[i] = *((const short8*)(AsH + (wm + i * 16 + r) * ASTR + q * 8));
            al[i] = *((const short8*)(AsL + (wm + i * 16 + r) * ASTR + q * 8));
        }
#pragma unroll
        for (int j = 0; j < 4; j++) {
            bh[j] = *((const short8*)(BsH + (wn + j * 16 + r) * ASTR + q * 8));
            bl[j] = *((const short8*)(BsL + (wn + j * 16 + r) * ASTR + q * 8));
        }
#pragma unroll
        for (int i = 0; i < 4; i++)
#pragma unroll
            for (int j = 0; j < 4; j++) {
                acc[i][j] = __builtin_amdgcn_mfma_f32_16x16x32_bf16(ah[i], bh[j], acc[i][j], 0, 0, 0);
                acc[i][j] = __builtin_amdgcn_mfma_f32_16x16x32_bf16(ah[i], bl[j], acc[i][j], 0, 0, 0);
                acc[i][j] = __builtin_amdgcn_mfma_f32_16x16x32_bf16(al[i], bh[j], acc[i][j], 0, 0, 0);
            }
        __syncthreads();
    }
#pragma unroll
    for (int i = 0; i < 4; i++) {
#pragma unroll
        for (int j = 0; j < 4; j++) {
#pragma unroll
            for (int reg = 0; reg < 4; reg++) {
                int mrow = m0 + wm + i * 16 + q * 4 + reg;
                int ncol = n0 + wn + j * 16 + r;
                if (mrow < M && ncol < Nc)
                    Cm[(size_t)mrow * Nc + ncol] = acc[i][j][reg];
            }
        }
    }
}

// al_src/al_dst[n*H+h] = sum_c h[n, h*C+c] * a_{s,d}[h*C+c]
__global__ void al_kernel(const float* __restrict__ h, const float* __restrict__ a_s,
                          const float* __restrict__ a_d, float* __restrict__ al_src,
                          float* __restrict__ al_dst, int H, int C, int NH) {
    int t = blockIdx.x * blockDim.x + threadIdx.x;
    if (t >= NH) return;
    int n = t / H, hd = t % H;
    const float* hp = h + (size_t)n * H * C + hd * C;
    float s1 = 0.f, s2 = 0.f;
    for (int c = 0; c < C; c++) {
        float v = hp[c];
        s1 += v * a_s[hd * C + c];
        s2 += v * a_d[hd * C + c];
    }
    al_src[t] = s1;
    al_dst[t] = s2;
}

// fused logit + segment softmax, alpha written in CSR order.
// thread t = (n, hd). Pass 1: online max/denominator. Pass 2: recompute+write.
__global__ void attn_kernel(const float* __restrict__ al_src,
                            const float* __restrict__ al_dst,
                            const int* __restrict__ csr_src,
                            const float* __restrict__ csr_ea,
                            const float* __restrict__ we_dot,
                            const int* __restrict__ off,
                            float* __restrict__ alpha, int H, int NH) {
    int t = blockIdx.x * blockDim.x + threadIdx.x;
    if (t >= NH) return;
    int n = t / H, hd = t - n * H;
    int s = off[n], e = off[n + 1];
    float ad = al_dst[(size_t)n * H + hd];
    float wd = we_dot[hd];
    float m = -INFINITY, l = 0.f;
    for (int p = s; p < e; p++) {
        float lg = al_src[(size_t)csr_src[p] * H + hd] + ad + csr_ea[p] * wd;
        lg = (lg >= 0.f) ? lg : NEG_SLOPE * lg;
        float nm = fmaxf(m, lg);
        l = l * __expf(m - nm) + __expf(lg - nm);
        m = nm;
    }
    float inv = 1.f / fmaxf(l, 1e-16f);
    for (int p = s; p < e; p++) {
        float lg = al_src[(size_t)csr_src[p] * H + hd] + ad + csr_ea[p] * wd;
        lg = (lg >= 0.f) ? lg : NEG_SLOPE * lg;
        alpha[(size_t)p * H + hd] = __expf(lg - m) * inv;
    }
}

// vectorized aggregate: each thread owns a float2 column pair of one node.
// requires C even (layers 1-4). p-loop unrolled x4 for gather ILP.
__global__ void aggregate_v2_kernel(const float* __restrict__ hfeat,
                                    const float* __restrict__ alpha,
                                    const int* __restrict__ off,
                                    const int* __restrict__ csr_src,
                                    const float* __restrict__ bias,
                                    float* __restrict__ out,
                                    int H, int C, int HC, int HC2, int total2) {
    int t = blockIdx.x * blockDim.x + threadIdx.x;
    if (t >= total2) return;
    int n = t / HC2, j2 = t - n * HC2;
    int j = j2 * 2;
    int hd = j / C;
    int s = off[n], e = off[n + 1];
    float2 acc = make_float2(0.f, 0.f);
    int p = s;
    for (; p + 3 < e; p += 4) {
        int s0 = csr_src[p], s1 = csr_src[p + 1], s2 = csr_src[p + 2], s3 = csr_src[p + 3];
        float a0 = alpha[(size_t)p * H + hd];
        float a1 = alpha[(size_t)(p + 1) * H + hd];
        float a2 = alpha[(size_t)(p + 2) * H + hd];
        float a3 = alpha[(size_t)(p + 3) * H + hd];
        float2 f0 = *(const float2*)(hfeat + (size_t)s0 * HC + j);
        float2 f1 = *(const float2*)(hfeat + (size_t)s1 * HC + j);
        float2 f2 = *(const float2*)(hfeat + (size_t)s2 * HC + j);
        float2 f3 = *(const float2*)(hfeat + (size_t)s3 * HC + j);
        acc.x += a0 * f0.x + a1 * f1.x + a2 * f2.x + a3 * f3.x;
        acc.y += a0 * f0.y + a1 * f1.y + a2 * f2.y + a3 * f3.y;
    }
    for (; p < e; p++) {
        int s0 = csr_src[p];
        float a0 = alpha[(size_t)p * H + hd];
        float2 f0 = *(const float2*)(hfeat + (size_t)s0 * HC + j);
        acc.x += a0 * f0.x;
        acc.y += a0 * f0.y;
    }
    float2 bi = *(const float2*)(bias + j);
    float2 r = make_float2(acc.x + bi.x, acc.y + bi.y);
    *(float2*)(out + (size_t)n * HC + j) = r;
}

// scalar fallback (layer 5, HC==1)
__global__ void aggregate_kernel(const float* __restrict__ hfeat,
                                 const float* __restrict__ alpha,
                                 const int* __restrict__ off, const int* __restrict__ csr_src,
                                 const float* __restrict__ bias, float* __restrict__ out,
                                 int H, int C, int HC, int total) {
    int t = blockIdx.x * blockDim.x + threadIdx.x;
    if (t >= total) return;
    int n = t / HC, j = t - n * HC;
    int hd = j / C;
    int s = off[n], e = off[n + 1];
    float acc = 0.f;
    for (int p = s; p < e; p++) {
        acc += alpha[(size_t)p * H + hd] * hfeat[(size_t)csr_src[p] * HC + j];
    }
    out[(size_t)n * HC + j] = acc + bias[j];
}

// ---------------- BN / activations ----------------

__global__ void bn_stats_kernel(const float* __restrict__ x, float* __restrict__ colsum,
                                float* __restrict__ colsumsq, int D) {
    int rows_per_block = (NN + gridDim.x - 1) / gridDim.x;
    int r0 = blockIdx.x * rows_per_block;
    int r1 = min(NN, r0 + rows_per_block);
    int c0 = threadIdx.x;
    int c1 = threadIdx.x + 256;
    float s0 = 0.f, q0 = 0.f, s1 = 0.f, q1 = 0.f;
    for (int r = r0; r < r1; r++) {
        const float* row = x + (size_t)r * D;
        if (c0 < D) { float v = row[c0]; s0 += v; q0 += v * v; }
        if (c1 < D) { float v = row[c1]; s1 += v; q1 += v * v; }
    }
    if (c0 < D) { atomicAdd(&colsum[c0], s0); atomicAdd(&colsumsq[c0], q0); }
    if (c1 < D) { atomicAdd(&colsum[c1], s1); atomicAdd(&colsumsq[c1], q1); }
}

__global__ void bn_scale_kernel(const float* __restrict__ colsum,
                                const float* __restrict__ colsumsq,
                                const float* __restrict__ g, const float* __restrict__ beta,
                                float* __restrict__ scale, float* __restrict__ shift, int D) {
    int c = blockIdx.x * blockDim.x + threadIdx.x;
    if (c >= D) return;
    float mu = colsum[c] / (float)NN;
    float var = colsumsq[c] / (float)NN - mu * mu;
    float sc = g[c] * rsqrtf(var + BN_EPS);
    scale[c] = sc;
    shift[c] = beta[c] - mu * sc;
}

__global__ void bn_relu_kernel(float* __restrict__ x, const float* __restrict__ scale,
                               const float* __restrict__ shift, int total, int D) {
    for (int i = blockIdx.x * blockDim.x + threadIdx.x; i < total; i += gridDim.x * blockDim.x) {
        int c = i % D;
        float v = x[i] * scale[c] + shift[c];
        x[i] = fmaxf(v, 0.f);
    }
}

__global__ void relu_kernel(float* __restrict__ x, int total) {
    for (int i = blockIdx.x * blockDim.x + threadIdx.x; i < total; i += gridDim.x * blockDim.x)
        x[i] = fmaxf(x[i], 0.f);
}

// ---------------- host orchestration ----------------

static inline size_t align_up(size_t v, size_t a) { return (v + a - 1) / a * a; }

extern "C" void kernel_launch(void* const* d_in, const int* in_sizes, int n_in,
                              void* d_out, int out_size, void* d_ws, size_t ws_size,
                              hipStream_t stream) {
    const float* x_in = (const float*)d_in[0];
    const int* ei     = (const int*)d_in[1];
    const float* ew   = (const float*)d_in[2];

    char* pws = (char*)d_ws;
    size_t off_b = 0;
    auto alloc = [&](size_t bytes) -> void* {
        void* rp = pws + off_b;
        off_b = align_up(off_b + bytes, 256);
        return rp;
    };
    float* B0      = (float*)alloc((size_t)NN * 500 * 4);   // h (f32)
    float* B1      = (float*)alloc((size_t)NN * 500 * 4);   // activations (f32)
    float* alpha   = (float*)alloc((size_t)ET * 5 * 4);
    unsigned short* Wt_hi = (unsigned short*)alloc((size_t)512 * 512 * 2);
    unsigned short* Wt_lo = (unsigned short*)alloc((size_t)512 * 512 * 2);
    float* al_src  = (float*)alloc((size_t)NN * 5 * 4);
    float* al_dst  = (float*)alloc((size_t)NN * 5 * 4);
    float* ea      = (float*)alloc((size_t)ET * 4);
    float* csr_ea  = (float*)alloc((size_t)ET * 4);
    int* srcv      = (int*)alloc((size_t)ET * 4);
    int* dstv      = (int*)alloc((size_t)ET * 4);
    int* csr_src   = (int*)alloc((size_t)ET * 4);
    int* offarr    = (int*)alloc((size_t)(NN + 1) * 4);
    int* wptr      = (int*)alloc((size_t)NN * 4);
    int* cnt       = (int*)alloc((size_t)NN * 4);
    float* esum    = (float*)alloc(4);
    float* we_dot  = (float*)alloc(8 * 4);
    float* colsum  = (float*)alloc(512 * 4);
    float* colsumsq= (float*)alloc(512 * 4);
    float* scale   = (float*)alloc(512 * 4);
    float* shift   = (float*)alloc(512 * 4);
    (void)ws_size; (void)n_in; (void)in_sizes; (void)out_size;

    // graph & CSR build
    hipMemsetAsync(esum, 0, 4, stream);
    hipMemsetAsync(cnt, 0, (size_t)NN * 4, stream);
    ewsum_kernel<<<256, 256, 0, stream>>>(ew, esum, EE);
    int ebl = (ET + 255) / 256;
    build_edges_kernel<<<ebl, 256, 0, stream>>>(ei, ew, esum, srcv, dstv, ea);
    count_kernel<<<ebl, 256, 0, stream>>>(dstv, cnt);
    scan_kernel<<<1, 1024, 0, stream>>>(cnt, offarr, wptr);
    fill_kernel<<<ebl, 256, 0, stream>>>(dstv, srcv, ea, wptr, csr_src, csr_ea);

    int bn_idx = 0;
    for (int l = 0; l < 5; l++) {
        const LayerCfg& cf = g_cfg[l];
        int H = cf.H, C = cf.C, K = cf.cin;
        int HC = H * C;
        int Kpad = (K + 31) / 32 * 32;
        int Npad = (HC + 127) / 128 * 128;
        const float* W   = (const float*)d_in[3 + l * 6 + 0];
        const float* a_s = (const float*)d_in[3 + l * 6 + 1];
        const float* a_d = (const float*)d_in[3 + l * 6 + 2];
        const float* We  = (const float*)d_in[3 + l * 6 + 3];
        const float* a_e = (const float*)d_in[3 + l * 6 + 4];
        const float* b   = (const float*)d_in[3 + l * 6 + 5];

        const float* X = (l == 0) ? x_in : B1;
        float* hbuf = B0;
        float* outbuf = (l == 4) ? (float*)d_out : B1;

        wedot_kernel<<<1, 8, 0, stream>>>(We, a_e, we_dot, H, C);

        dim3 tgrid((Kpad + 31) / 32, (Npad + 31) / 32);
        transpose_pad_kernel<<<tgrid, dim3(32, 8), 0, stream>>>(W, Wt_hi, Wt_lo, K, HC, Kpad, Npad);

        dim3 ggrid(Npad / GBNT, (NN + GBM - 1) / GBM);
        gemm_split_kernel<<<ggrid, 256, 0, stream>>>(X, Wt_hi, Wt_lo, hbuf, NN, K, HC, Kpad);

        int NH = NN * H;
        al_kernel<<<(NH + 255) / 256, 256, 0, stream>>>(hbuf, a_s, a_d, al_src, al_dst, H, C, NH);
        attn_kernel<<<(NH + 255) / 256, 256, 0, stream>>>(al_src, al_dst, csr_src, csr_ea, we_dot,
                                                          offarr, alpha, H, NH);

        if (HC >= 2) {
            int HC2 = HC / 2;
            int total2 = NN * HC2;
            aggregate_v2_kernel<<<(total2 + 255) / 256, 256, 0, stream>>>(
                hbuf, alpha, offarr, csr_src, b, outbuf, H, C, HC, HC2, total2);
        } else {
            int total = NN * HC;
            aggregate_kernel<<<(total + 255) / 256, 256, 0, stream>>>(
                hbuf, alpha, offarr, csr_src, b, outbuf, H, C, HC, total);
        }

        int total = NN * HC;
        if (l < 3) {
            int D = HC;
            const float* g    = (const float*)d_in[33 + bn_idx * 2 + 0];
            const float* beta = (const float*)d_in[33 + bn_idx * 2 + 1];
            hipMemsetAsync(colsum, 0, 512 * 4, stream);
            hipMemsetAsync(colsumsq, 0, 512 * 4, stream);
            bn_stats_kernel<<<256, 256, 0, stream>>>(outbuf, colsum, colsumsq, D);
            bn_scale_kernel<<<(D + 255) / 256, 256, 0, stream>>>(colsum, colsumsq, g, beta, scale, shift, D);
            bn_relu_kernel<<<2048, 256, 0, stream>>>(outbuf, scale, shift, total, D);
            bn_idx++;
        } else if (l == 3) {
            relu_kernel<<<1024, 256, 0, stream>>>(outbuf, total);
        }
    }
}

// Round 6
// 1281.840 us; speedup vs baseline: 1.6828x; 1.0028x over previous
//
#include <hip/hip_runtime.h>
#include <hip/hip_bf16.h>
#include <math.h>

// ---------------- problem constants ----------------
#define NN 30000
#define EE 480000
#define ET (EE + NN)   // edges + self loops = 510000
#define NEG_SLOPE 0.2f
#define BN_EPS 1e-5f

struct LayerCfg { int cin, C, H; };
static const LayerCfg g_cfg[5] = {
    {128, 100, 5}, {500, 50, 5}, {250, 32, 4}, {128, 8, 4}, {32, 1, 1}
};

typedef short short8 __attribute__((ext_vector_type(8)));
typedef float f32x4 __attribute__((ext_vector_type(4)));

__device__ __forceinline__ unsigned short f2bf(float f) {
    unsigned int u = __builtin_bit_cast(unsigned int, f);
    u = (u + 0x7FFFu + ((u >> 16) & 1u)) >> 16;
    return (unsigned short)u;
}
__device__ __forceinline__ float bf2f(unsigned short h) {
    unsigned int u = ((unsigned int)h) << 16;
    return __builtin_bit_cast(float, u);
}

// ---------------- graph / CSR kernels ----------------

__global__ void ewsum_kernel(const float* __restrict__ ew, float* __restrict__ out, int E) {
    __shared__ float sdata[256];
    int tid = threadIdx.x;
    float s = 0.f;
    for (int i = blockIdx.x * blockDim.x + tid; i < E; i += gridDim.x * blockDim.x)
        s += ew[i];
    sdata[tid] = s;
    __syncthreads();
    for (int off = 128; off > 0; off >>= 1) {
        if (tid < off) sdata[tid] += sdata[tid + off];
        __syncthreads();
    }
    if (tid == 0) atomicAdd(out, sdata[0]);
}

__global__ void build_edges_kernel(const int* __restrict__ ei, const float* __restrict__ ew,
                                   const float* __restrict__ sum,
                                   int* __restrict__ srcv, int* __restrict__ dstv,
                                   float* __restrict__ ea) {
    int e = blockIdx.x * blockDim.x + threadIdx.x;
    if (e >= ET) return;
    if (e < EE) {
        srcv[e] = ei[e];
        dstv[e] = ei[EE + e];
        ea[e]   = ew[e];
    } else {
        int n = e - EE;
        srcv[e] = n;
        dstv[e] = n;
        ea[e]   = sum[0] * (1.0f / (float)EE);
    }
}

__global__ void count_kernel(const int* __restrict__ dstv, int* __restrict__ cnt) {
    int e = blockIdx.x * blockDim.x + threadIdx.x;
    if (e >= ET) return;
    atomicAdd(&cnt[dstv[e]], 1);
}

__global__ void scan_kernel(const int* __restrict__ cnt, int* __restrict__ off,
                            int* __restrict__ wptr) {
    __shared__ int lsum[1024];
    __shared__ int loff[1024];
    const int T = 1024;
    int t = threadIdx.x;
    int chunk = (NN + T - 1) / T;
    int base = t * chunk;
    int end = min(NN, base + chunk);
    int s = 0;
    for (int i = base; i < end; i++) s += cnt[i];
    lsum[t] = s;
    __syncthreads();
    if (t == 0) {
        int run = 0;
        for (int i = 0; i < T; i++) { loff[i] = run; run += lsum[i]; }
    }
    __syncthreads();
    int run = loff[t];
    for (int i = base; i < end; i++) {
        off[i] = run;
        wptr[i] = run;
        run += cnt[i];
    }
    if (t == 0) off[NN] = ET;
}

__global__ void fill_kernel(const int* __restrict__ dstv, const int* __restrict__ srcv,
                            const float* __restrict__ ea,
                            int* __restrict__ wptr, int* __restrict__ csr_src,
                            float* __restrict__ csr_ea) {
    int e = blockIdx.x * blockDim.x + threadIdx.x;
    if (e >= ET) return;
    int p = atomicAdd(&wptr[dstv[e]], 1);
    csr_src[p] = srcv[e];
    csr_ea[p]  = ea[e];
}

// ---------------- per-layer small kernels ----------------

__global__ void wedot_kernel(const float* __restrict__ We, const float* __restrict__ a_e,
                             float* __restrict__ we_dot, int H, int C) {
    int hd = threadIdx.x;
    if (hd < H) {
        float s = 0.f;
        for (int c = 0; c < C; c++) s += We[hd * C + c] * a_e[hd * C + c];
        we_dot[hd] = s;
    }
}

__global__ void transpose_pad_kernel(const float* __restrict__ B,
                                     unsigned short* __restrict__ Bt_hi,
                                     unsigned short* __restrict__ Bt_lo,
                                     int K, int N, int Kpad, int Npad) {
    __shared__ float tile[32][33];
    int kb = blockIdx.x * 32, nb = blockIdx.y * 32;
    int tx = threadIdx.x, ty = threadIdx.y;   // 32 x 8
#pragma unroll
    for (int i = 0; i < 4; i++) {
        int k = kb + ty + i * 8, n = nb + tx;
        tile[ty + i * 8][tx] = (k < K && n < N) ? B[(size_t)k * N + n] : 0.f;
    }
    __syncthreads();
#pragma unroll
    for (int i = 0; i < 4; i++) {
        int n = nb + ty + i * 8, k = kb + tx;
        if (n < Npad && k < Kpad) {
            float v = tile[tx][ty + i * 8];
            unsigned short hi = f2bf(v);
            unsigned short lo = f2bf(v - bf2f(hi));
            size_t idx = (size_t)n * Kpad + k;
            Bt_hi[idx] = hi;
            Bt_lo[idx] = lo;
        }
    }
}

// ---------------- split-bf16 MFMA GEMM ----------------
#define GBM 128
#define GBNT 128
#define GBK 32
#define ASTR 40
__global__ __launch_bounds__(256) void gemm_split_kernel(const float* __restrict__ A,
                                                         const unsigned short* __restrict__ Bt_hi,
                                                         const unsigned short* __restrict__ Bt_lo,
                                                         float* __restrict__ Cm,
                                                         int M, int K, int Nc, int Kpad) {
    __shared__ short AsH[GBM * ASTR];
    __shared__ short AsL[GBM * ASTR];
    __shared__ short BsH[GBNT * ASTR];
    __shared__ short BsL[GBNT * ASTR];
    int tid = threadIdx.x;
    int wave = tid >> 6, lane = tid & 63;
    int q = lane >> 4, r = lane & 15;
    int m0 = blockIdx.y * GBM, n0 = blockIdx.x * GBNT;
    int wm = (wave & 1) * 64, wn = (wave >> 1) * 64;
    f32x4 acc[4][4];
#pragma unroll
    for (int i = 0; i < 4; i++)
#pragma unroll
        for (int j = 0; j < 4; j++) acc[i][j] = (f32x4)(0.f);

    int arow = tid >> 3;
    int alk  = tid & 7;
    int brow = tid >> 2;
    int bcol = (tid & 3) * 8;

    int ksteps = (K + GBK - 1) / GBK;
    for (int ks = 0; ks < ksteps; ks++) {
        int k0 = ks * GBK;
#pragma unroll
        for (int p = 0; p < 4; p++) {
            int row = p * 32 + arow;
            int m = m0 + row;
#pragma unroll
            for (int i = 0; i < 4; i++) {
                int k = alk + 8 * i;
                float v = 0.f;
                if (m < M && (k0 + k) < K) v = A[(size_t)m * K + k0 + k];
                unsigned short hi = f2bf(v);
                unsigned short lo = f2bf(v - bf2f(hi));
                AsH[row * ASTR + k] = (short)hi;
                AsL[row * ASTR + k] = (short)lo;
            }
        }
#pragma unroll
        for (int p = 0; p < 2; p++) {
            int row = p * 64 + brow;
            size_t gidx = (size_t)(n0 + row) * Kpad + k0 + bcol;
            *((uint4*)(BsH + row * ASTR + bcol)) = *((const uint4*)(Bt_hi + gidx));
            *((uint4*)(BsL + row * ASTR + bcol)) = *((const uint4*)(Bt_lo + gidx));
        }
        __syncthreads();
        short8 ah[4], al[4], bh[4], bl[4];
#pragma unroll
        for (int i = 0; i < 4; i++) {
            ah[i] = *((const short8*)(AsH + (wm + i * 16 + r) * ASTR + q * 8));
            al[i] = *((const short8*)(AsL + (wm + i * 16 + r) * ASTR + q * 8));
        }
#pragma unroll
        for (int j = 0; j < 4; j++) {
            bh[j] = *((const short8*)(BsH + (wn + j * 16 + r) * ASTR + q * 8));
            bl[j] = *((const short8*)(BsL + (wn + j * 16 + r) * ASTR + q * 8));
        }
#pragma unroll
        for (int i = 0; i < 4; i++)
#pragma unroll
            for (int j = 0; j < 4; j++) {
                acc[i][j] = __builtin_amdgcn_mfma_f32_16x16x32_bf16(ah[i], bh[j], acc[i][j], 0, 0, 0);
                acc[i][j] = __builtin_amdgcn_mfma_f32_16x16x32_bf16(ah[i], bl[j], acc[i][j], 0, 0, 0);
                acc[i][j] = __builtin_amdgcn_mfma_f32_16x16x32_bf16(al[i], bh[j], acc[i][j], 0, 0, 0);
            }
        __syncthreads();
    }
#pragma unroll
    for (int i = 0; i < 4; i++) {
#pragma unroll
        for (int j = 0; j < 4; j++) {
#pragma unroll
            for (int reg = 0; reg < 4; reg++) {
                int mrow = m0 + wm + i * 16 + q * 4 + reg;
                int ncol = n0 + wn + j * 16 + r;
                if (mrow < M && ncol < Nc)
                    Cm[(size_t)mrow * Nc + ncol] = acc[i][j][reg];
            }
        }
    }
}

// al_src/al_dst[n*H+h] = sum_c h[n, h*C+c] * a_{s,d}[h*C+c]
__global__ void al_kernel(const float* __restrict__ h, const float* __restrict__ a_s,
                          const float* __restrict__ a_d, float* __restrict__ al_src,
                          float* __restrict__ al_dst, int H, int C, int NH) {
    int t = blockIdx.x * blockDim.x + threadIdx.x;
    if (t >= NH) return;
    int n = t / H, hd = t % H;
    const float* hp = h + (size_t)n * H * C + hd * C;
    float s1 = 0.f, s2 = 0.f;
    for (int c = 0; c < C; c++) {
        float v = hp[c];
        s1 += v * a_s[hd * C + c];
        s2 += v * a_d[hd * C + c];
    }
    al_src[t] = s1;
    al_dst[t] = s2;
}

// fused logit + segment softmax; alpha transposed: alpha_t[hd*ET + p]
__global__ void attn_kernel(const float* __restrict__ al_src,
                            const float* __restrict__ al_dst,
                            const int* __restrict__ csr_src,
                            const float* __restrict__ csr_ea,
                            const float* __restrict__ we_dot,
                            const int* __restrict__ off,
                            float* __restrict__ alpha_t, int H, int NH) {
    int t = blockIdx.x * blockDim.x + threadIdx.x;
    if (t >= NH) return;
    int n = t / H, hd = t - n * H;
    int s = off[n], e = off[n + 1];
    float ad = al_dst[(size_t)n * H + hd];
    float wd = we_dot[hd];
    float m = -INFINITY, l = 0.f;
    for (int p = s; p < e; p++) {
        float lg = al_src[(size_t)csr_src[p] * H + hd] + ad + csr_ea[p] * wd;
        lg = (lg >= 0.f) ? lg : NEG_SLOPE * lg;
        float nm = fmaxf(m, lg);
        l = l * __expf(m - nm) + __expf(lg - nm);
        m = nm;
    }
    float inv = 1.f / fmaxf(l, 1e-16f);
    float* arow = alpha_t + (size_t)hd * ET;
    for (int p = s; p < e; p++) {
        float lg = al_src[(size_t)csr_src[p] * H + hd] + ad + csr_ea[p] * wd;
        lg = (lg >= 0.f) ? lg : NEG_SLOPE * lg;
        arow[p] = __expf(lg - m) * inv;
    }
}

// float4 aggregate: each thread owns 4 cols of one node (requires 4|C)
__global__ void aggregate_v4_kernel(const float* __restrict__ hfeat,
                                    const float* __restrict__ alpha_t,
                                    const int* __restrict__ off,
                                    const int* __restrict__ csr_src,
                                    const float* __restrict__ bias,
                                    float* __restrict__ out,
                                    int C, int HC, int HC4, int total4) {
    int t = blockIdx.x * blockDim.x + threadIdx.x;
    if (t >= total4) return;
    int n = t / HC4, j4 = t - n * HC4;
    int j = j4 * 4;
    int hd = j / C;
    const float* arow = alpha_t + (size_t)hd * ET;
    int s = off[n], e = off[n + 1];
    float4 acc = make_float4(0.f, 0.f, 0.f, 0.f);
    int p = s;
    for (; p + 3 < e; p += 4) {
        int s0 = csr_src[p], s1 = csr_src[p + 1], s2 = csr_src[p + 2], s3 = csr_src[p + 3];
        float a0 = arow[p], a1 = arow[p + 1], a2 = arow[p + 2], a3 = arow[p + 3];
        float4 f0 = *(const float4*)(hfeat + (size_t)s0 * HC + j);
        float4 f1 = *(const float4*)(hfeat + (size_t)s1 * HC + j);
        float4 f2 = *(const float4*)(hfeat + (size_t)s2 * HC + j);
        float4 f3 = *(const float4*)(hfeat + (size_t)s3 * HC + j);
        acc.x += a0 * f0.x + a1 * f1.x + a2 * f2.x + a3 * f3.x;
        acc.y += a0 * f0.y + a1 * f1.y + a2 * f2.y + a3 * f3.y;
        acc.z += a0 * f0.z + a1 * f1.z + a2 * f2.z + a3 * f3.z;
        acc.w += a0 * f0.w + a1 * f1.w + a2 * f2.w + a3 * f3.w;
    }
    for (; p < e; p++) {
        int s0 = csr_src[p];
        float a0 = arow[p];
        float4 f0 = *(const float4*)(hfeat + (size_t)s0 * HC + j);
        acc.x += a0 * f0.x; acc.y += a0 * f0.y; acc.z += a0 * f0.z; acc.w += a0 * f0.w;
    }
    float4 bi = *(const float4*)(bias + j);
    float4 rr = make_float4(acc.x + bi.x, acc.y + bi.y, acc.z + bi.z, acc.w + bi.w);
    *(float4*)(out + (size_t)n * HC + j) = rr;
}

// float2 aggregate (2|C), for C=50
__global__ void aggregate_v2_kernel(const float* __restrict__ hfeat,
                                    const float* __restrict__ alpha_t,
                                    const int* __restrict__ off,
                                    const int* __restrict__ csr_src,
                                    const float* __restrict__ bias,
                                    float* __restrict__ out,
                                    int C, int HC, int HC2, int total2) {
    int t = blockIdx.x * blockDim.x + threadIdx.x;
    if (t >= total2) return;
    int n = t / HC2, j2 = t - n * HC2;
    int j = j2 * 2;
    int hd = j / C;
    const float* arow = alpha_t + (size_t)hd * ET;
    int s = off[n], e = off[n + 1];
    float2 acc = make_float2(0.f, 0.f);
    int p = s;
    for (; p + 3 < e; p += 4) {
        int s0 = csr_src[p], s1 = csr_src[p + 1], s2 = csr_src[p + 2], s3 = csr_src[p + 3];
        float a0 = arow[p], a1 = arow[p + 1], a2 = arow[p + 2], a3 = arow[p + 3];
        float2 f0 = *(const float2*)(hfeat + (size_t)s0 * HC + j);
        float2 f1 = *(const float2*)(hfeat + (size_t)s1 * HC + j);
        float2 f2 = *(const float2*)(hfeat + (size_t)s2 * HC + j);
        float2 f3 = *(const float2*)(hfeat + (size_t)s3 * HC + j);
        acc.x += a0 * f0.x + a1 * f1.x + a2 * f2.x + a3 * f3.x;
        acc.y += a0 * f0.y + a1 * f1.y + a2 * f2.y + a3 * f3.y;
    }
    for (; p < e; p++) {
        int s0 = csr_src[p];
        float a0 = arow[p];
        float2 f0 = *(const float2*)(hfeat + (size_t)s0 * HC + j);
        acc.x += a0 * f0.x; acc.y += a0 * f0.y;
    }
    float2 bi = *(const float2*)(bias + j);
    *(float2*)(out + (size_t)n * HC + j) = make_float2(acc.x + bi.x, acc.y + bi.y);
}

// scalar fallback (layer 5, HC==1)
__global__ void aggregate_kernel(const float* __restrict__ hfeat,
                                 const float* __restrict__ alpha_t,
                                 const int* __restrict__ off, const int* __restrict__ csr_src,
                                 const float* __restrict__ bias, float* __restrict__ out,
                                 int total) {
    int t = blockIdx.x * blockDim.x + threadIdx.x;
    if (t >= total) return;
    int n = t;
    int s = off[n], e = off[n + 1];
    float acc = 0.f;
    int p = s;
    for (; p + 3 < e; p += 4) {
        acc += alpha_t[p] * hfeat[csr_src[p]]
             + alpha_t[p + 1] * hfeat[csr_src[p + 1]]
             + alpha_t[p + 2] * hfeat[csr_src[p + 2]]
             + alpha_t[p + 3] * hfeat[csr_src[p + 3]];
    }
    for (; p < e; p++) acc += alpha_t[p] * hfeat[csr_src[p]];
    out[n] = acc + bias[0];
}

// ---------------- BN / activations ----------------

__global__ void bn_stats_kernel(const float* __restrict__ x, float* __restrict__ colsum,
                                float* __restrict__ colsumsq, int D) {
    int rows_per_block = (NN + gridDim.x - 1) / gridDim.x;
    int r0 = blockIdx.x * rows_per_block;
    int r1 = min(NN, r0 + rows_per_block);
    int c0 = threadIdx.x;
    int c1 = threadIdx.x + 256;
    float s0 = 0.f, q0 = 0.f, s1 = 0.f, q1 = 0.f;
    for (int r = r0; r < r1; r++) {
        const float* row = x + (size_t)r * D;
        if (c0 < D) { float v = row[c0]; s0 += v; q0 += v * v; }
        if (c1 < D) { float v = row[c1]; s1 += v; q1 += v * v; }
    }
    if (c0 < D) { atomicAdd(&colsum[c0], s0); atomicAdd(&colsumsq[c0], q0); }
    if (c1 < D) { atomicAdd(&colsum[c1], s1); atomicAdd(&colsumsq[c1], q1); }
}

// fused BN+ReLU, float4 path (requires 4|D)
__global__ void bn_relu_v4_kernel(float* __restrict__ x,
                                  const float* __restrict__ colsum,
                                  const float* __restrict__ colsumsq,
                                  const float* __restrict__ g, const float* __restrict__ beta,
                                  int total4, int D) {
    __shared__ float sscale[512];
    __shared__ float sshift[512];
    for (int c = threadIdx.x; c < D; c += blockDim.x) {
        float mu = colsum[c] * (1.0f / (float)NN);
        float var = colsumsq[c] * (1.0f / (float)NN) - mu * mu;
        float sc = g[c] * rsqrtf(var + BN_EPS);
        sscale[c] = sc;
        sshift[c] = beta[c] - mu * sc;
    }
    __syncthreads();
    int D4 = D >> 2;
    for (int i = blockIdx.x * blockDim.x + threadIdx.x; i < total4; i += gridDim.x * blockDim.x) {
        int c4 = (i % D4) * 4;
        float4 v = *(float4*)(x + (size_t)i * 4);
        v.x = fmaxf(v.x * sscale[c4]     + sshift[c4],     0.f);
        v.y = fmaxf(v.y * sscale[c4 + 1] + sshift[c4 + 1], 0.f);
        v.z = fmaxf(v.z * sscale[c4 + 2] + sshift[c4 + 2], 0.f);
        v.w = fmaxf(v.w * sscale[c4 + 3] + sshift[c4 + 3], 0.f);
        *(float4*)(x + (size_t)i * 4) = v;
    }
}

// fused BN+ReLU, float2 path (requires 2|D; used for D=250)
__global__ void bn_relu_v2_kernel(float* __restrict__ x,
                                  const float* __restrict__ colsum,
                                  const float* __restrict__ colsumsq,
                                  const float* __restrict__ g, const float* __restrict__ beta,
                                  int total2, int D) {
    __shared__ float sscale[512];
    __shared__ float sshift[512];
    for (int c = threadIdx.x; c < D; c += blockDim.x) {
        float mu = colsum[c] * (1.0f / (float)NN);
        float var = colsumsq[c] * (1.0f / (float)NN) - mu * mu;
        float sc = g[c] * rsqrtf(var + BN_EPS);
        sscale[c] = sc;
        sshift[c] = beta[c] - mu * sc;
    }
    __syncthreads();
    int D2 = D >> 1;
    for (int i = blockIdx.x * blockDim.x + threadIdx.x; i < total2; i += gridDim.x * blockDim.x) {
        int c2 = (i % D2) * 2;
        float2 v = *(float2*)(x + (size_t)i * 2);
        v.x = fmaxf(v.x * sscale[c2]     + sshift[c2],     0.f);
        v.y = fmaxf(v.y * sscale[c2 + 1] + sshift[c2 + 1], 0.f);
        *(float2*)(x + (size_t)i * 2) = v;
    }
}

__global__ void relu_kernel(float* __restrict__ x, int total) {
    for (int i = blockIdx.x * blockDim.x + threadIdx.x; i < total; i += gridDim.x * blockDim.x)
        x[i] = fmaxf(x[i], 0.f);
}

// ---------------- host orchestration ----------------

static inline size_t align_up(size_t v, size_t a) { return (v + a - 1) / a * a; }

extern "C" void kernel_launch(void* const* d_in, const int* in_sizes, int n_in,
                              void* d_out, int out_size, void* d_ws, size_t ws_size,
                              hipStream_t stream) {
    const float* x_in = (const float*)d_in[0];
    const int* ei     = (const int*)d_in[1];
    const float* ew   = (const float*)d_in[2];

    char* pws = (char*)d_ws;
    size_t off_b = 0;
    auto alloc = [&](size_t bytes) -> void* {
        void* rp = pws + off_b;
        off_b = align_up(off_b + bytes, 256);
        return rp;
    };
    float* B0      = (float*)alloc((size_t)NN * 500 * 4);   // h (f32)
    float* B1      = (float*)alloc((size_t)NN * 500 * 4);   // activations (f32)
    float* alpha_t = (float*)alloc((size_t)ET * 5 * 4);     // [H][ET]
    unsigned short* Wt_hi = (unsigned short*)alloc((size_t)512 * 512 * 2);
    unsigned short* Wt_lo = (unsigned short*)alloc((size_t)512 * 512 * 2);
    float* al_src  = (float*)alloc((size_t)NN * 5 * 4);
    float* al_dst  = (float*)alloc((size_t)NN * 5 * 4);
    float* ea      = (float*)alloc((size_t)ET * 4);
    float* csr_ea  = (float*)alloc((size_t)ET * 4);
    int* srcv      = (int*)alloc((size_t)ET * 4);
    int* dstv      = (int*)alloc((size_t)ET * 4);
    int* csr_src   = (int*)alloc((size_t)ET * 4);
    int* offarr    = (int*)alloc((size_t)(NN + 1) * 4);
    int* wptr      = (int*)alloc((size_t)NN * 4);
    int* cnt       = (int*)alloc((size_t)NN * 4);
    float* esum    = (float*)alloc(4);
    float* we_dot  = (float*)alloc(8 * 4);
    float* colsum  = (float*)alloc(512 * 4);   // colsum+colsumsq contiguous: one memset
    float* colsumsq= (float*)alloc(512 * 4);
    (void)ws_size; (void)n_in; (void)in_sizes; (void)out_size;

    // graph & CSR build
    hipMemsetAsync(esum, 0, 4, stream);
    hipMemsetAsync(cnt, 0, (size_t)NN * 4, stream);
    ewsum_kernel<<<256, 256, 0, stream>>>(ew, esum, EE);
    int ebl = (ET + 255) / 256;
    build_edges_kernel<<<ebl, 256, 0, stream>>>(ei, ew, esum, srcv, dstv, ea);
    count_kernel<<<ebl, 256, 0, stream>>>(dstv, cnt);
    scan_kernel<<<1, 1024, 0, stream>>>(cnt, offarr, wptr);
    fill_kernel<<<ebl, 256, 0, stream>>>(dstv, srcv, ea, wptr, csr_src, csr_ea);

    int bn_idx = 0;
    for (int l = 0; l < 5; l++) {
        const LayerCfg& cf = g_cfg[l];
        int H = cf.H, C = cf.C, K = cf.cin;
        int HC = H * C;
        int Kpad = (K + 31) / 32 * 32;
        int Npad = (HC + 127) / 128 * 128;
        const float* W   = (const float*)d_in[3 + l * 6 + 0];
        const float* a_s = (const float*)d_in[3 + l * 6 + 1];
        const float* a_d = (const float*)d_in[3 + l * 6 + 2];
        const float* We  = (const float*)d_in[3 + l * 6 + 3];
        const float* a_e = (const float*)d_in[3 + l * 6 + 4];
        const float* b   = (const float*)d_in[3 + l * 6 + 5];

        const float* X = (l == 0) ? x_in : B1;
        float* hbuf = B0;
        float* outbuf = (l == 4) ? (float*)d_out : B1;

        wedot_kernel<<<1, 8, 0, stream>>>(We, a_e, we_dot, H, C);

        dim3 tgrid((Kpad + 31) / 32, (Npad + 31) / 32);
        transpose_pad_kernel<<<tgrid, dim3(32, 8), 0, stream>>>(W, Wt_hi, Wt_lo, K, HC, Kpad, Npad);

        dim3 ggrid(Npad / GBNT, (NN + GBM - 1) / GBM);
        gemm_split_kernel<<<ggrid, 256, 0, stream>>>(X, Wt_hi, Wt_lo, hbuf, NN, K, HC, Kpad);

        int NH = NN * H;
        al_kernel<<<(NH + 255) / 256, 256, 0, stream>>>(hbuf, a_s, a_d, al_src, al_dst, H, C, NH);
        attn_kernel<<<(NH + 255) / 256, 256, 0, stream>>>(al_src, al_dst, csr_src, csr_ea, we_dot,
                                                          offarr, alpha_t, H, NH);

        if ((C & 3) == 0) {
            int HC4 = HC / 4;
            int total4 = NN * HC4;
            aggregate_v4_kernel<<<(total4 + 255) / 256, 256, 0, stream>>>(
                hbuf, alpha_t, offarr, csr_src, b, outbuf, C, HC, HC4, total4);
        } else if ((C & 1) == 0) {
            int HC2 = HC / 2;
            int total2 = NN * HC2;
            aggregate_v2_kernel<<<(total2 + 255) / 256, 256, 0, stream>>>(
                hbuf, alpha_t, offarr, csr_src, b, outbuf, C, HC, HC2, total2);
        } else {
            aggregate_kernel<<<(NN + 255) / 256, 256, 0, stream>>>(
                hbuf, alpha_t, offarr, csr_src, b, outbuf, NN);
        }

        int total = NN * HC;
        if (l < 3) {
            int D = HC;
            const float* g    = (const float*)d_in[33 + bn_idx * 2 + 0];
            const float* beta = (const float*)d_in[33 + bn_idx * 2 + 1];
            hipMemsetAsync(colsum, 0, 2 * 512 * 4, stream);   // colsum+colsumsq adjacent
            bn_stats_kernel<<<256, 256, 0, stream>>>(outbuf, colsum, colsumsq, D);
            if ((D & 3) == 0) {
                bn_relu_v4_kernel<<<2048, 256, 0, stream>>>(outbuf, colsum, colsumsq, g, beta, total / 4, D);
            } else {
                bn_relu_v2_kernel<<<2048, 256, 0, stream>>>(outbuf, colsum, colsumsq, g, beta, total / 2, D);
            }
            bn_idx++;
        } else if (l == 3) {
            relu_kernel<<<1024, 256, 0, stream>>>(outbuf, total);
        }
    }
}

// Round 7
// 1279.357 us; speedup vs baseline: 1.6860x; 1.0019x over previous
//
#include <hip/hip_runtime.h>
#include <hip/hip_bf16.h>
#include <math.h>

// ---------------- problem constants ----------------
#define NN 30000
#define EE 480000
#define ET (EE + NN)   // edges + self loops = 510000
#define NEG_SLOPE 0.2f
#define BN_EPS 1e-5f

struct LayerCfg { int cin, C, H; };
static const LayerCfg g_cfg[5] = {
    {128, 100, 5}, {500, 50, 5}, {250, 32, 4}, {128, 8, 4}, {32, 1, 1}
};

typedef short short8 __attribute__((ext_vector_type(8)));
typedef float f32x4 __attribute__((ext_vector_type(4)));

__device__ __forceinline__ unsigned short f2bf(float f) {
    unsigned int u = __builtin_bit_cast(unsigned int, f);
    u = (u + 0x7FFFu + ((u >> 16) & 1u)) >> 16;
    return (unsigned short)u;
}
__device__ __forceinline__ float bf2f(unsigned short h) {
    unsigned int u = ((unsigned int)h) << 16;
    return __builtin_bit_cast(float, u);
}

// ---------------- graph / CSR kernels ----------------

__global__ void ewsum_kernel(const float* __restrict__ ew, float* __restrict__ out, int E) {
    __shared__ float sdata[256];
    int tid = threadIdx.x;
    float s = 0.f;
    for (int i = blockIdx.x * blockDim.x + tid; i < E; i += gridDim.x * blockDim.x)
        s += ew[i];
    sdata[tid] = s;
    __syncthreads();
    for (int off = 128; off > 0; off >>= 1) {
        if (tid < off) sdata[tid] += sdata[tid + off];
        __syncthreads();
    }
    if (tid == 0) atomicAdd(out, sdata[0]);
}

// build src/dst/ea arrays AND count in-degrees in one pass
__global__ void build_edges_kernel(const int* __restrict__ ei, const float* __restrict__ ew,
                                   const float* __restrict__ sum,
                                   int* __restrict__ srcv, int* __restrict__ dstv,
                                   float* __restrict__ ea, int* __restrict__ cnt) {
    int e = blockIdx.x * blockDim.x + threadIdx.x;
    if (e >= ET) return;
    int d;
    if (e < EE) {
        srcv[e] = ei[e];
        d = ei[EE + e];
        dstv[e] = d;
        ea[e]   = ew[e];
    } else {
        int n = e - EE;
        srcv[e] = n;
        d = n;
        dstv[e] = n;
        ea[e]   = sum[0] * (1.0f / (float)EE);
    }
    atomicAdd(&cnt[d], 1);
}

__global__ void scan_kernel(const int* __restrict__ cnt, int* __restrict__ off,
                            int* __restrict__ wptr) {
    __shared__ int lsum[1024];
    __shared__ int loff[1024];
    const int T = 1024;
    int t = threadIdx.x;
    int chunk = (NN + T - 1) / T;
    int base = t * chunk;
    int end = min(NN, base + chunk);
    int s = 0;
    for (int i = base; i < end; i++) s += cnt[i];
    lsum[t] = s;
    __syncthreads();
    if (t == 0) {
        int run = 0;
        for (int i = 0; i < T; i++) { loff[i] = run; run += lsum[i]; }
    }
    __syncthreads();
    int run = loff[t];
    for (int i = base; i < end; i++) {
        off[i] = run;
        wptr[i] = run;
        run += cnt[i];
    }
    if (t == 0) off[NN] = ET;
}

__global__ void fill_kernel(const int* __restrict__ dstv, const int* __restrict__ srcv,
                            const float* __restrict__ ea,
                            int* __restrict__ wptr, int* __restrict__ csr_src,
                            float* __restrict__ csr_ea) {
    int e = blockIdx.x * blockDim.x + threadIdx.x;
    if (e >= ET) return;
    int p = atomicAdd(&wptr[dstv[e]], 1);
    csr_src[p] = srcv[e];
    csr_ea[p]  = ea[e];
}

// ---------------- all-layer weight prep (2 dispatches total) ----------------

struct PrepArgs {
    const float* W[5];
    const float* We[5];
    const float* ae[5];
    unsigned short* bh[5];
    unsigned short* bl[5];
    float* wedot;            // out: [5][8]
    int K[5], N[5], Kp[5], Np[5], C[5], H[5];
};

__global__ void wedot_all_kernel(PrepArgs a) {
    int tid = threadIdx.x;   // 64
    int l = tid >> 3, hd = tid & 7;
    if (l < 5 && hd < a.H[l]) {
        int C = a.C[l];
        const float* We = a.We[l] + hd * C;
        const float* ae = a.ae[l] + hd * C;
        float s = 0.f;
        for (int c = 0; c < C; c++) s += We[c] * ae[c];
        a.wedot[l * 8 + hd] = s;
    }
}

__global__ void transpose_all_kernel(PrepArgs a) {
    int l = blockIdx.z;
    int Kp = a.Kp[l], Np = a.Np[l], K = a.K[l], N = a.N[l];
    int kb = blockIdx.x * 32, nb = blockIdx.y * 32;
    if (kb >= Kp || nb >= Np) return;
    const float* B = a.W[l];
    unsigned short* Bth = a.bh[l];
    unsigned short* Btl = a.bl[l];
    __shared__ float tile[32][33];
    int tx = threadIdx.x, ty = threadIdx.y;   // 32 x 8
#pragma unroll
    for (int i = 0; i < 4; i++) {
        int k = kb + ty + i * 8, n = nb + tx;
        tile[ty + i * 8][tx] = (k < K && n < N) ? B[(size_t)k * N + n] : 0.f;
    }
    __syncthreads();
#pragma unroll
    for (int i = 0; i < 4; i++) {
        int n = nb + ty + i * 8, k = kb + tx;
        if (n < Np && k < Kp) {
            float v = tile[tx][ty + i * 8];
            unsigned short hi = f2bf(v);
            unsigned short lo = f2bf(v - bf2f(hi));
            size_t idx = (size_t)n * Kp + k;
            Bth[idx] = hi;
            Btl[idx] = lo;
        }
    }
}

// ---------------- split-bf16 MFMA GEMM ----------------
#define GBM 128
#define GBNT 128
#define GBK 32
#define ASTR 40
__global__ __launch_bounds__(256) void gemm_split_kernel(const float* __restrict__ A,
                                                         const unsigned short* __restrict__ Bt_hi,
                                                         const unsigned short* __restrict__ Bt_lo,
                                                         float* __restrict__ Cm,
                                                         int M, int K, int Nc, int Kpad) {
    __shared__ short AsH[GBM * ASTR];
    __shared__ short AsL[GBM * ASTR];
    __shared__ short BsH[GBNT * ASTR];
    __shared__ short BsL[GBNT * ASTR];
    int tid = threadIdx.x;
    int wave = tid >> 6, lane = tid & 63;
    int q = lane >> 4, r = lane & 15;
    int m0 = blockIdx.y * GBM, n0 = blockIdx.x * GBNT;
    int wm = (wave & 1) * 64, wn = (wave >> 1) * 64;
    f32x4 acc[4][4];
#pragma unroll
    for (int i = 0; i < 4; i++)
#pragma unroll
        for (int j = 0; j < 4; j++) acc[i][j] = (f32x4)(0.f);

    int arow = tid >> 3;
    int alk  = tid & 7;
    int brow = tid >> 2;
    int bcol = (tid & 3) * 8;

    int ksteps = (K + GBK - 1) / GBK;
    for (int ks = 0; ks < ksteps; ks++) {
        int k0 = ks * GBK;
#pragma unroll
        for (int p = 0; p < 4; p++) {
            int row = p * 32 + arow;
            int m = m0 + row;
#pragma unroll
            for (int i = 0; i < 4; i++) {
                int k = alk + 8 * i;
                float v = 0.f;
                if (m < M && (k0 + k) < K) v = A[(size_t)m * K + k0 + k];
                unsigned short hi = f2bf(v);
                unsigned short lo = f2bf(v - bf2f(hi));
                AsH[row * ASTR + k] = (short)hi;
                AsL[row * ASTR + k] = (short)lo;
            }
        }
#pragma unroll
        for (int p = 0; p < 2; p++) {
            int row = p * 64 + brow;
            size_t gidx = (size_t)(n0 + row) * Kpad + k0 + bcol;
            *((uint4*)(BsH + row * ASTR + bcol)) = *((const uint4*)(Bt_hi + gidx));
            *((uint4*)(BsL + row * ASTR + bcol)) = *((const uint4*)(Bt_lo + gidx));
        }
        __syncthreads();
        short8 ah[4], al[4], bh[4], bl[4];
#pragma unroll
        for (int i = 0; i < 4; i++) {
            ah[i] = *((const short8*)(AsH + (wm + i * 16 + r) * ASTR + q * 8));
            al[i] = *((const short8*)(AsL + (wm + i * 16 + r) * ASTR + q * 8));
        }
#pragma unroll
        for (int j = 0; j < 4; j++) {
            bh[j] = *((const short8*)(BsH + (wn + j * 16 + r) * ASTR + q * 8));
            bl[j] = *((const short8*)(BsL + (wn + j * 16 + r) * ASTR + q * 8));
        }
#pragma unroll
        for (int i = 0; i < 4; i++)
#pragma unroll
            for (int j = 0; j < 4; j++) {
                acc[i][j] = __builtin_amdgcn_mfma_f32_16x16x32_bf16(ah[i], bh[j], acc[i][j], 0, 0, 0);
                acc[i][j] = __builtin_amdgcn_mfma_f32_16x16x32_bf16(ah[i], bl[j], acc[i][j], 0, 0, 0);
                acc[i][j] = __builtin_amdgcn_mfma_f32_16x16x32_bf16(al[i], bh[j], acc[i][j], 0, 0, 0);
            }
        __syncthreads();
    }
#pragma unroll
    for (int i = 0; i < 4; i++) {
#pragma unroll
        for (int j = 0; j < 4; j++) {
#pragma unroll
            for (int reg = 0; reg < 4; reg++) {
                int mrow = m0 + wm + i * 16 + q * 4 + reg;
                int ncol = n0 + wn + j * 16 + r;
                if (mrow < M && ncol < Nc)
                    Cm[(size_t)mrow * Nc + ncol] = acc[i][j][reg];
            }
        }
    }
}

// al_src/al_dst[n*H+h] = sum_c h[n, h*C+c] * a_{s,d}[h*C+c]
__global__ void al_kernel(const float* __restrict__ h, const float* __restrict__ a_s,
                          const float* __restrict__ a_d, float* __restrict__ al_src,
                          float* __restrict__ al_dst, int H, int C, int NH) {
    int t = blockIdx.x * blockDim.x + threadIdx.x;
    if (t >= NH) return;
    int n = t / H, hd = t % H;
    const float* hp = h + (size_t)n * H * C + hd * C;
    float s1 = 0.f, s2 = 0.f;
    for (int c = 0; c < C; c++) {
        float v = hp[c];
        s1 += v * a_s[hd * C + c];
        s2 += v * a_d[hd * C + c];
    }
    al_src[t] = s1;
    al_dst[t] = s2;
}

// fused logit + segment softmax. Single random-gather pass:
//  pass1: gather al_src, compute leaky logit, STORE at CSR slot, track max (unroll 4)
//  pass2: linear re-read own slice, exp, sum, store exp
//  pass3: linear scale by 1/sum
__global__ void attn_kernel(const float* __restrict__ al_src,
                            const float* __restrict__ al_dst,
                            const int* __restrict__ csr_src,
                            const float* __restrict__ csr_ea,
                            const float* __restrict__ we_dot,
                            const int* __restrict__ off,
                            float* __restrict__ alpha_t, int H, int NH) {
    int t = blockIdx.x * blockDim.x + threadIdx.x;
    if (t >= NH) return;
    int n = t / H, hd = t - n * H;
    int s = off[n], e = off[n + 1];
    float ad = al_dst[(size_t)n * H + hd];
    float wd = we_dot[hd];
    float* arow = alpha_t + (size_t)hd * ET;
    float m = -INFINITY;
    int p = s;
    for (; p + 3 < e; p += 4) {
        int s0 = csr_src[p], s1 = csr_src[p + 1], s2 = csr_src[p + 2], s3 = csr_src[p + 3];
        float w0 = csr_ea[p], w1 = csr_ea[p + 1], w2 = csr_ea[p + 2], w3 = csr_ea[p + 3];
        float l0 = al_src[(size_t)s0 * H + hd] + ad + w0 * wd;
        float l1 = al_src[(size_t)s1 * H + hd] + ad + w1 * wd;
        float l2 = al_src[(size_t)s2 * H + hd] + ad + w2 * wd;
        float l3 = al_src[(size_t)s3 * H + hd] + ad + w3 * wd;
        l0 = (l0 >= 0.f) ? l0 : NEG_SLOPE * l0;
        l1 = (l1 >= 0.f) ? l1 : NEG_SLOPE * l1;
        l2 = (l2 >= 0.f) ? l2 : NEG_SLOPE * l2;
        l3 = (l3 >= 0.f) ? l3 : NEG_SLOPE * l3;
        arow[p] = l0; arow[p + 1] = l1; arow[p + 2] = l2; arow[p + 3] = l3;
        m = fmaxf(m, fmaxf(fmaxf(l0, l1), fmaxf(l2, l3)));
    }
    for (; p < e; p++) {
        float lg = al_src[(size_t)csr_src[p] * H + hd] + ad + csr_ea[p] * wd;
        lg = (lg >= 0.f) ? lg : NEG_SLOPE * lg;
        arow[p] = lg;
        m = fmaxf(m, lg);
    }
    float l = 0.f;
    for (p = s; p < e; p++) {
        float ev = __expf(arow[p] - m);
        arow[p] = ev;
        l += ev;
    }
    float inv = 1.f / fmaxf(l, 1e-16f);
    for (p = s; p < e; p++) arow[p] *= inv;
}

// float4 aggregate, unroll 8 (requires 4|C); optional fused relu
__global__ void aggregate_v4_kernel(const float* __restrict__ hfeat,
                                    const float* __restrict__ alpha_t,
                                    const int* __restrict__ off,
                                    const int* __restrict__ csr_src,
                                    const float* __restrict__ bias,
                                    float* __restrict__ out,
                                    int C, int HC, int HC4, int total4, int relu) {
    int t = blockIdx.x * blockDim.x + threadIdx.x;
    if (t >= total4) return;
    int n = t / HC4, j4 = t - n * HC4;
    int j = j4 * 4;
    int hd = j / C;
    const float* arow = alpha_t + (size_t)hd * ET;
    int s = off[n], e = off[n + 1];
    float4 acc = make_float4(0.f, 0.f, 0.f, 0.f);
    int p = s;
    for (; p + 7 < e; p += 8) {
        int idx[8]; float a[8];
#pragma unroll
        for (int u = 0; u < 8; u++) { idx[u] = csr_src[p + u]; a[u] = arow[p + u]; }
#pragma unroll
        for (int u = 0; u < 8; u++) {
            float4 f = *(const float4*)(hfeat + (size_t)idx[u] * HC + j);
            acc.x += a[u] * f.x; acc.y += a[u] * f.y; acc.z += a[u] * f.z; acc.w += a[u] * f.w;
        }
    }
    for (; p + 3 < e; p += 4) {
        int idx[4]; float a[4];
#pragma unroll
        for (int u = 0; u < 4; u++) { idx[u] = csr_src[p + u]; a[u] = arow[p + u]; }
#pragma unroll
        for (int u = 0; u < 4; u++) {
            float4 f = *(const float4*)(hfeat + (size_t)idx[u] * HC + j);
            acc.x += a[u] * f.x; acc.y += a[u] * f.y; acc.z += a[u] * f.z; acc.w += a[u] * f.w;
        }
    }
    for (; p < e; p++) {
        int s0 = csr_src[p];
        float a0 = arow[p];
        float4 f0 = *(const float4*)(hfeat + (size_t)s0 * HC + j);
        acc.x += a0 * f0.x; acc.y += a0 * f0.y; acc.z += a0 * f0.z; acc.w += a0 * f0.w;
    }
    float4 bi = *(const float4*)(bias + j);
    float4 rr = make_float4(acc.x + bi.x, acc.y + bi.y, acc.z + bi.z, acc.w + bi.w);
    if (relu) {
        rr.x = fmaxf(rr.x, 0.f); rr.y = fmaxf(rr.y, 0.f);
        rr.z = fmaxf(rr.z, 0.f); rr.w = fmaxf(rr.w, 0.f);
    }
    *(float4*)(out + (size_t)n * HC + j) = rr;
}

// float2 aggregate (2|C), for C=50
__global__ void aggregate_v2_kernel(const float* __restrict__ hfeat,
                                    const float* __restrict__ alpha_t,
                                    const int* __restrict__ off,
                                    const int* __restrict__ csr_src,
                                    const float* __restrict__ bias,
                                    float* __restrict__ out,
                                    int C, int HC, int HC2, int total2) {
    int t = blockIdx.x * blockDim.x + threadIdx.x;
    if (t >= total2) return;
    int n = t / HC2, j2 = t - n * HC2;
    int j = j2 * 2;
    int hd = j / C;
    const float* arow = alpha_t + (size_t)hd * ET;
    int s = off[n], e = off[n + 1];
    float2 acc = make_float2(0.f, 0.f);
    int p = s;
    for (; p + 7 < e; p += 8) {
        int idx[8]; float a[8];
#pragma unroll
        for (int u = 0; u < 8; u++) { idx[u] = csr_src[p + u]; a[u] = arow[p + u]; }
#pragma unroll
        for (int u = 0; u < 8; u++) {
            float2 f = *(const float2*)(hfeat + (size_t)idx[u] * HC + j);
            acc.x += a[u] * f.x; acc.y += a[u] * f.y;
        }
    }
    for (; p + 3 < e; p += 4) {
        int idx[4]; float a[4];
#pragma unroll
        for (int u = 0; u < 4; u++) { idx[u] = csr_src[p + u]; a[u] = arow[p + u]; }
#pragma unroll
        for (int u = 0; u < 4; u++) {
            float2 f = *(const float2*)(hfeat + (size_t)idx[u] * HC + j);
            acc.x += a[u] * f.x; acc.y += a[u] * f.y;
        }
    }
    for (; p < e; p++) {
        int s0 = csr_src[p];
        float a0 = arow[p];
        float2 f0 = *(const float2*)(hfeat + (size_t)s0 * HC + j);
        acc.x += a0 * f0.x; acc.y += a0 * f0.y;
    }
    float2 bi = *(const float2*)(bias + j);
    *(float2*)(out + (size_t)n * HC + j) = make_float2(acc.x + bi.x, acc.y + bi.y);
}

// scalar fallback (layer 5, HC==1)
__global__ void aggregate_kernel(const float* __restrict__ hfeat,
                                 const float* __restrict__ alpha_t,
                                 const int* __restrict__ off, const int* __restrict__ csr_src,
                                 const float* __restrict__ bias, float* __restrict__ out,
                                 int total) {
    int t = blockIdx.x * blockDim.x + threadIdx.x;
    if (t >= total) return;
    int n = t;
    int s = off[n], e = off[n + 1];
    float acc = 0.f;
    int p = s;
    for (; p + 3 < e; p += 4) {
        acc += alpha_t[p] * hfeat[csr_src[p]]
             + alpha_t[p + 1] * hfeat[csr_src[p + 1]]
             + alpha_t[p + 2] * hfeat[csr_src[p + 2]]
             + alpha_t[p + 3] * hfeat[csr_src[p + 3]];
    }
    for (; p < e; p++) acc += alpha_t[p] * hfeat[csr_src[p]];
    out[n] = acc + bias[0];
}

// ---------------- BN / activations ----------------

__global__ void bn_stats_kernel(const float* __restrict__ x, float* __restrict__ colsum,
                                float* __restrict__ colsumsq, int D) {
    int rows_per_block = (NN + gridDim.x - 1) / gridDim.x;
    int r0 = blockIdx.x * rows_per_block;
    int r1 = min(NN, r0 + rows_per_block);
    int c0 = threadIdx.x;
    int c1 = threadIdx.x + 256;
    float s0 = 0.f, q0 = 0.f, s1 = 0.f, q1 = 0.f;
    for (int r = r0; r < r1; r++) {
        const float* row = x + (size_t)r * D;
        if (c0 < D) { float v = row[c0]; s0 += v; q0 += v * v; }
        if (c1 < D) { float v = row[c1]; s1 += v; q1 += v * v; }
    }
    if (c0 < D) { atomicAdd(&colsum[c0], s0); atomicAdd(&colsumsq[c0], q0); }
    if (c1 < D) { atomicAdd(&colsum[c1], s1); atomicAdd(&colsumsq[c1], q1); }
}

// fused BN+ReLU, float4 path (requires 4|D)
__global__ void bn_relu_v4_kernel(float* __restrict__ x,
                                  const float* __restrict__ colsum,
                                  const float* __restrict__ colsumsq,
                                  const float* __restrict__ g, const float* __restrict__ beta,
                                  int total4, int D) {
    __shared__ float sscale[512];
    __shared__ float sshift[512];
    for (int c = threadIdx.x; c < D; c += blockDim.x) {
        float mu = colsum[c] * (1.0f / (float)NN);
        float var = colsumsq[c] * (1.0f / (float)NN) - mu * mu;
        float sc = g[c] * rsqrtf(var + BN_EPS);
        sscale[c] = sc;
        sshift[c] = beta[c] - mu * sc;
    }
    __syncthreads();
    int D4 = D >> 2;
    for (int i = blockIdx.x * blockDim.x + threadIdx.x; i < total4; i += gridDim.x * blockDim.x) {
        int c4 = (i % D4) * 4;
        float4 v = *(float4*)(x + (size_t)i * 4);
        v.x = fmaxf(v.x * sscale[c4]     + sshift[c4],     0.f);
        v.y = fmaxf(v.y * sscale[c4 + 1] + sshift[c4 + 1], 0.f);
        v.z = fmaxf(v.z * sscale[c4 + 2] + sshift[c4 + 2], 0.f);
        v.w = fmaxf(v.w * sscale[c4 + 3] + sshift[c4 + 3], 0.f);
        *(float4*)(x + (size_t)i * 4) = v;
    }
}

// fused BN+ReLU, float2 path (2|D; used for D=250)
__global__ void bn_relu_v2_kernel(float* __restrict__ x,
                                  const float* __restrict__ colsum,
                                  const float* __restrict__ colsumsq,
                                  const float* __restrict__ g, const float* __restrict__ beta,
                                  int total2, int D) {
    __shared__ float sscale[512];
    __shared__ float sshift[512];
    for (int c = threadIdx.x; c < D; c += blockDim.x) {
        float mu = colsum[c] * (1.0f / (float)NN);
        float var = colsumsq[c] * (1.0f / (float)NN) - mu * mu;
        float sc = g[c] * rsqrtf(var + BN_EPS);
        sscale[c] = sc;
        sshift[c] = beta[c] - mu * sc;
    }
    __syncthreads();
    int D2 = D >> 1;
    for (int i = blockIdx.x * blockDim.x + threadIdx.x; i < total2; i += gridDim.x * blockDim.x) {
        int c2 = (i % D2) * 2;
        float2 v = *(float2*)(x + (size_t)i * 2);
        v.x = fmaxf(v.x * sscale[c2]     + sshift[c2],     0.f);
        v.y = fmaxf(v.y * sscale[c2 + 1] + sshift[c2 + 1], 0.f);
        *(float2*)(x + (size_t)i * 2) = v;
    }
}

// ---------------- host orchestration ----------------

static inline size_t align_up(size_t v, size_t a) { return (v + a - 1) / a * a; }

extern "C" void kernel_launch(void* const* d_in, const int* in_sizes, int n_in,
                              void* d_out, int out_size, void* d_ws, size_t ws_size,
                              hipStream_t stream) {
    const float* x_in = (const float*)d_in[0];
    const int* ei     = (const int*)d_in[1];
    const float* ew   = (const float*)d_in[2];

    char* pws = (char*)d_ws;
    size_t off_b = 0;
    auto alloc = [&](size_t bytes) -> void* {
        void* rp = pws + off_b;
        off_b = align_up(off_b + bytes, 256);
        return rp;
    };
    float* B0      = (float*)alloc((size_t)NN * 500 * 4);
    float* B1      = (float*)alloc((size_t)NN * 500 * 4);
    float* alpha_t = (float*)alloc((size_t)ET * 5 * 4);
    unsigned short* Wt_hi = (unsigned short*)alloc((size_t)512 * 512 * 2);
    unsigned short* Wt_lo = (unsigned short*)alloc((size_t)512 * 512 * 2);
    float* al_src  = (float*)alloc((size_t)NN * 5 * 4);
    float* al_dst  = (float*)alloc((size_t)NN * 5 * 4);
    float* ea      = (float*)alloc((size_t)ET * 4);
    float* csr_ea  = (float*)alloc((size_t)ET * 4);
    int* srcv      = (int*)alloc((size_t)ET * 4);
    int* dstv      = (int*)alloc((size_t)ET * 4);
    int* csr_src   = (int*)alloc((size_t)ET * 4);
    int* offarr    = (int*)alloc((size_t)(NN + 1) * 4);
    int* wptr      = (int*)alloc((size_t)NN * 4);
    int* cnt       = (int*)alloc((size_t)NN * 4);
    float* esum    = (float*)alloc(4);
    float* we_dot  = (float*)alloc(40 * 4);
    float* colsum  = (float*)alloc(512 * 4);
    float* colsumsq= (float*)alloc(512 * 4);
    (void)ws_size; (void)n_in; (void)in_sizes; (void)out_size;

    // per-layer padded dims and Wt offsets
    int Kp[5], Np[5];
    size_t wtoff[5];
    size_t acc_off = 0;
    for (int l = 0; l < 5; l++) {
        int K = g_cfg[l].cin, HC = g_cfg[l].C * g_cfg[l].H;
        Kp[l] = (K + 31) / 32 * 32;
        Np[l] = (HC + 127) / 128 * 128;
        wtoff[l] = acc_off;
        acc_off += (size_t)Kp[l] * Np[l];
    }

    PrepArgs pa;
    for (int l = 0; l < 5; l++) {
        pa.W[l]  = (const float*)d_in[3 + l * 6 + 0];
        pa.We[l] = (const float*)d_in[3 + l * 6 + 3];
        pa.ae[l] = (const float*)d_in[3 + l * 6 + 4];
        pa.bh[l] = Wt_hi + wtoff[l];
        pa.bl[l] = Wt_lo + wtoff[l];
        pa.K[l] = g_cfg[l].cin;
        pa.N[l] = g_cfg[l].C * g_cfg[l].H;
        pa.Kp[l] = Kp[l];
        pa.Np[l] = Np[l];
        pa.C[l] = g_cfg[l].C;
        pa.H[l] = g_cfg[l].H;
    }
    pa.wedot = we_dot;

    // graph & CSR build
    hipMemsetAsync(esum, 0, 4, stream);
    hipMemsetAsync(cnt, 0, (size_t)NN * 4, stream);
    ewsum_kernel<<<256, 256, 0, stream>>>(ew, esum, EE);
    int ebl = (ET + 255) / 256;
    build_edges_kernel<<<ebl, 256, 0, stream>>>(ei, ew, esum, srcv, dstv, ea, cnt);
    scan_kernel<<<1, 1024, 0, stream>>>(cnt, offarr, wptr);
    fill_kernel<<<ebl, 256, 0, stream>>>(dstv, srcv, ea, wptr, csr_src, csr_ea);

    // all-layer weight prep
    wedot_all_kernel<<<1, 64, 0, stream>>>(pa);
    transpose_all_kernel<<<dim3(16, 16, 5), dim3(32, 8), 0, stream>>>(pa);

    int bn_idx = 0;
    for (int l = 0; l < 5; l++) {
        const LayerCfg& cf = g_cfg[l];
        int H = cf.H, C = cf.C, K = cf.cin;
        int HC = H * C;
        const float* a_s = (const float*)d_in[3 + l * 6 + 1];
        const float* a_d = (const float*)d_in[3 + l * 6 + 2];
        const float* b   = (const float*)d_in[3 + l * 6 + 5];

        const float* X = (l == 0) ? x_in : B1;
        float* hbuf = B0;
        float* outbuf = (l == 4) ? (float*)d_out : B1;

        dim3 ggrid(Np[l] / GBNT, (NN + GBM - 1) / GBM);
        gemm_split_kernel<<<ggrid, 256, 0, stream>>>(X, Wt_hi + wtoff[l], Wt_lo + wtoff[l],
                                                     hbuf, NN, K, HC, Kp[l]);

        int NH = NN * H;
        al_kernel<<<(NH + 255) / 256, 256, 0, stream>>>(hbuf, a_s, a_d, al_src, al_dst, H, C, NH);
        attn_kernel<<<(NH + 255) / 256, 256, 0, stream>>>(al_src, al_dst, csr_src, csr_ea,
                                                          we_dot + l * 8, offarr, alpha_t, H, NH);

        int do_relu = (l == 3) ? 1 : 0;
        if ((C & 3) == 0) {
            int HC4 = HC / 4;
            int total4 = NN * HC4;
            aggregate_v4_kernel<<<(total4 + 255) / 256, 256, 0, stream>>>(
                hbuf, alpha_t, offarr, csr_src, b, outbuf, C, HC, HC4, total4, do_relu);
        } else if ((C & 1) == 0) {
            int HC2 = HC / 2;
            int total2 = NN * HC2;
            aggregate_v2_kernel<<<(total2 + 255) / 256, 256, 0, stream>>>(
                hbuf, alpha_t, offarr, csr_src, b, outbuf, C, HC, HC2, total2);
        } else {
            aggregate_kernel<<<(NN + 255) / 256, 256, 0, stream>>>(
                hbuf, alpha_t, offarr, csr_src, b, outbuf, NN);
        }

        int total = NN * HC;
        if (l < 3) {
            int D = HC;
            const float* g    = (const float*)d_in[33 + bn_idx * 2 + 0];
            const float* beta = (const float*)d_in[33 + bn_idx * 2 + 1];
            hipMemsetAsync(colsum, 0, 2 * 512 * 4, stream);
            bn_stats_kernel<<<256, 256, 0, stream>>>(outbuf, colsum, colsumsq, D);
            if ((D & 3) == 0) {
                bn_relu_v4_kernel<<<2048, 256, 0, stream>>>(outbuf, colsum, colsumsq, g, beta, total / 4, D);
            } else {
                bn_relu_v2_kernel<<<2048, 256, 0, stream>>>(outbuf, colsum, colsumsq, g, beta, total / 2, D);
            }
            bn_idx++;
        }
    }
}

// Round 8
// 1126.889 us; speedup vs baseline: 1.9142x; 1.1353x over previous
//
#include <hip/hip_runtime.h>
#include <hip/hip_bf16.h>
#include <math.h>

// ---------------- problem constants ----------------
#define NN 30000
#define EE 480000
#define ET (EE + NN)   // edges + self loops = 510000
#define NEG_SLOPE 0.2f
#define BN_EPS 1e-5f

struct LayerCfg { int cin, C, H; };
static const LayerCfg g_cfg[5] = {
    {128, 100, 5}, {500, 50, 5}, {250, 32, 4}, {128, 8, 4}, {32, 1, 1}
};

typedef short short8 __attribute__((ext_vector_type(8)));
typedef float f32x4 __attribute__((ext_vector_type(4)));

__device__ __forceinline__ unsigned short f2bf(float f) {
    unsigned int u = __builtin_bit_cast(unsigned int, f);
    u = (u + 0x7FFFu + ((u >> 16) & 1u)) >> 16;
    return (unsigned short)u;
}
__device__ __forceinline__ float bf2f(unsigned short h) {
    unsigned int u = ((unsigned int)h) << 16;
    return __builtin_bit_cast(float, u);
}

// ---------------- graph / CSR kernels ----------------

__global__ void ewsum_kernel(const float* __restrict__ ew, float* __restrict__ out, int E) {
    __shared__ float sdata[256];
    int tid = threadIdx.x;
    float s = 0.f;
    for (int i = blockIdx.x * blockDim.x + tid; i < E; i += gridDim.x * blockDim.x)
        s += ew[i];
    sdata[tid] = s;
    __syncthreads();
    for (int off = 128; off > 0; off >>= 1) {
        if (tid < off) sdata[tid] += sdata[tid + off];
        __syncthreads();
    }
    if (tid == 0) atomicAdd(out, sdata[0]);
}

__global__ void build_edges_kernel(const int* __restrict__ ei, const float* __restrict__ ew,
                                   const float* __restrict__ sum,
                                   int* __restrict__ srcv, int* __restrict__ dstv,
                                   float* __restrict__ ea, int* __restrict__ cnt) {
    int e = blockIdx.x * blockDim.x + threadIdx.x;
    if (e >= ET) return;
    int d;
    if (e < EE) {
        srcv[e] = ei[e];
        d = ei[EE + e];
        dstv[e] = d;
        ea[e]   = ew[e];
    } else {
        int n = e - EE;
        srcv[e] = n;
        d = n;
        dstv[e] = n;
        ea[e]   = sum[0] * (1.0f / (float)EE);
    }
    atomicAdd(&cnt[d], 1);
}

__global__ void scan_kernel(const int* __restrict__ cnt, int* __restrict__ off,
                            int* __restrict__ wptr) {
    __shared__ int lsum[1024];
    __shared__ int loff[1024];
    const int T = 1024;
    int t = threadIdx.x;
    int chunk = (NN + T - 1) / T;
    int base = t * chunk;
    int end = min(NN, base + chunk);
    int s = 0;
    for (int i = base; i < end; i++) s += cnt[i];
    lsum[t] = s;
    __syncthreads();
    if (t == 0) {
        int run = 0;
        for (int i = 0; i < T; i++) { loff[i] = run; run += lsum[i]; }
    }
    __syncthreads();
    int run = loff[t];
    for (int i = base; i < end; i++) {
        off[i] = run;
        wptr[i] = run;
        run += cnt[i];
    }
    if (t == 0) off[NN] = ET;
}

__global__ void fill_kernel(const int* __restrict__ dstv, const int* __restrict__ srcv,
                            const float* __restrict__ ea,
                            int* __restrict__ wptr, int* __restrict__ csr_src,
                            float* __restrict__ csr_ea) {
    int e = blockIdx.x * blockDim.x + threadIdx.x;
    if (e >= ET) return;
    int p = atomicAdd(&wptr[dstv[e]], 1);
    csr_src[p] = srcv[e];
    csr_ea[p]  = ea[e];
}

// ---------------- all-layer weight prep ----------------

struct PrepArgs {
    const float* W[5];
    const float* We[5];
    const float* ae[5];
    unsigned short* bh[5];
    unsigned short* bl[5];
    float* wedot;            // out: [5][8]
    int K[5], N[5], Kp[5], Np[5], C[5], H[5];
};

__global__ void wedot_all_kernel(PrepArgs a) {
    int tid = threadIdx.x;   // 64
    int l = tid >> 3, hd = tid & 7;
    if (l < 5 && hd < a.H[l]) {
        int C = a.C[l];
        const float* We = a.We[l] + hd * C;
        const float* ae = a.ae[l] + hd * C;
        float s = 0.f;
        for (int c = 0; c < C; c++) s += We[c] * ae[c];
        a.wedot[l * 8 + hd] = s;
    }
}

__global__ void transpose_all_kernel(PrepArgs a) {
    int l = blockIdx.z;
    int Kp = a.Kp[l], Np = a.Np[l], K = a.K[l], N = a.N[l];
    int kb = blockIdx.x * 32, nb = blockIdx.y * 32;
    if (kb >= Kp || nb >= Np) return;
    const float* B = a.W[l];
    unsigned short* Bth = a.bh[l];
    unsigned short* Btl = a.bl[l];
    __shared__ float tile[32][33];
    int tx = threadIdx.x, ty = threadIdx.y;   // 32 x 8
#pragma unroll
    for (int i = 0; i < 4; i++) {
        int k = kb + ty + i * 8, n = nb + tx;
        tile[ty + i * 8][tx] = (k < K && n < N) ? B[(size_t)k * N + n] : 0.f;
    }
    __syncthreads();
#pragma unroll
    for (int i = 0; i < 4; i++) {
        int n = nb + ty + i * 8, k = kb + tx;
        if (n < Np && k < Kp) {
            float v = tile[tx][ty + i * 8];
            unsigned short hi = f2bf(v);
            unsigned short lo = f2bf(v - bf2f(hi));
            size_t idx = (size_t)n * Kp + k;
            Bth[idx] = hi;
            Btl[idx] = lo;
        }
    }
}

// ---------------- split-bf16 MFMA GEMM ----------------
// Optional bf16 copy of output (Ch16 != nullptr) for bandwidth-light gathers.
#define GBM 128
#define GBNT 128
#define GBK 32
#define ASTR 40
__global__ __launch_bounds__(256) void gemm_split_kernel(const float* __restrict__ A,
                                                         const unsigned short* __restrict__ Bt_hi,
                                                         const unsigned short* __restrict__ Bt_lo,
                                                         float* __restrict__ Cm,
                                                         unsigned short* __restrict__ Ch16,
                                                         int M, int K, int Nc, int Kpad) {
    __shared__ short AsH[GBM * ASTR];
    __shared__ short AsL[GBM * ASTR];
    __shared__ short BsH[GBNT * ASTR];
    __shared__ short BsL[GBNT * ASTR];
    int tid = threadIdx.x;
    int wave = tid >> 6, lane = tid & 63;
    int q = lane >> 4, r = lane & 15;
    int m0 = blockIdx.y * GBM, n0 = blockIdx.x * GBNT;
    int wm = (wave & 1) * 64, wn = (wave >> 1) * 64;
    f32x4 acc[4][4];
#pragma unroll
    for (int i = 0; i < 4; i++)
#pragma unroll
        for (int j = 0; j < 4; j++) acc[i][j] = (f32x4)(0.f);

    // scalar-staging indices (fallback when K % 4 != 0)
    int arow = tid >> 3;
    int alk  = tid & 7;
    // vector-staging indices (K % 4 == 0): each thread covers 16 consecutive k
    int arow2 = tid >> 1;          // 0..127
    int acol2 = (tid & 1) * 16;    // 0 or 16
    int brow = tid >> 2;
    int bcol = (tid & 3) * 8;
    bool vecA = ((K & 3) == 0);

    int ksteps = (K + GBK - 1) / GBK;
    for (int ks = 0; ks < ksteps; ks++) {
        int k0 = ks * GBK;
        if (vecA) {
            int m = m0 + arow2;
            float v[16];
            if (m < M && (k0 + acol2 + 16) <= K) {
                const float* Ap = A + (size_t)m * K + k0 + acol2;
                float4 f0 = *(const float4*)(Ap);
                float4 f1 = *(const float4*)(Ap + 4);
                float4 f2 = *(const float4*)(Ap + 8);
                float4 f3 = *(const float4*)(Ap + 12);
                v[0]=f0.x; v[1]=f0.y; v[2]=f0.z; v[3]=f0.w;
                v[4]=f1.x; v[5]=f1.y; v[6]=f1.z; v[7]=f1.w;
                v[8]=f2.x; v[9]=f2.y; v[10]=f2.z; v[11]=f2.w;
                v[12]=f3.x; v[13]=f3.y; v[14]=f3.z; v[15]=f3.w;
            } else {
                const float* Ap = A + (size_t)m * K + k0 + acol2;
#pragma unroll
                for (int i = 0; i < 16; i++)
                    v[i] = (m < M && (k0 + acol2 + i) < K) ? Ap[i] : 0.f;
            }
#pragma unroll
            for (int i = 0; i < 16; i++) {
                unsigned short hi = f2bf(v[i]);
                unsigned short lo = f2bf(v[i] - bf2f(hi));
                AsH[arow2 * ASTR + acol2 + i] = (short)hi;
                AsL[arow2 * ASTR + acol2 + i] = (short)lo;
            }
        } else {
#pragma unroll
            for (int p = 0; p < 4; p++) {
                int row = p * 32 + arow;
                int m = m0 + row;
#pragma unroll
                for (int i = 0; i < 4; i++) {
                    int k = alk + 8 * i;
                    float v = 0.f;
                    if (m < M && (k0 + k) < K) v = A[(size_t)m * K + k0 + k];
                    unsigned short hi = f2bf(v);
                    unsigned short lo = f2bf(v - bf2f(hi));
                    AsH[row * ASTR + k] = (short)hi;
                    AsL[row * ASTR + k] = (short)lo;
                }
            }
        }
#pragma unroll
        for (int p = 0; p < 2; p++) {
            int row = p * 64 + brow;
            size_t gidx = (size_t)(n0 + row) * Kpad + k0 + bcol;
            *((uint4*)(BsH + row * ASTR + bcol)) = *((const uint4*)(Bt_hi + gidx));
            *((uint4*)(BsL + row * ASTR + bcol)) = *((const uint4*)(Bt_lo + gidx));
        }
        __syncthreads();
        short8 ah[4], al[4], bh[4], bl[4];
#pragma unroll
        for (int i = 0; i < 4; i++) {
            ah[i] = *((const short8*)(AsH + (wm + i * 16 + r) * ASTR + q * 8));
            al[i] = *((const short8*)(AsL + (wm + i * 16 + r) * ASTR + q * 8));
        }
#pragma unroll
        for (int j = 0; j < 4; j++) {
            bh[j] = *((const short8*)(BsH + (wn + j * 16 + r) * ASTR + q * 8));
            bl[j] = *((const short8*)(BsL + (wn + j * 16 + r) * ASTR + q * 8));
        }
#pragma unroll
        for (int i = 0; i < 4; i++)
#pragma unroll
            for (int j = 0; j < 4; j++) {
                acc[i][j] = __builtin_amdgcn_mfma_f32_16x16x32_bf16(ah[i], bh[j], acc[i][j], 0, 0, 0);
                acc[i][j] = __builtin_amdgcn_mfma_f32_16x16x32_bf16(ah[i], bl[j], acc[i][j], 0, 0, 0);
                acc[i][j] = __builtin_amdgcn_mfma_f32_16x16x32_bf16(al[i], bh[j], acc[i][j], 0, 0, 0);
            }
        __syncthreads();
    }
#pragma unroll
    for (int i = 0; i < 4; i++) {
#pragma unroll
        for (int j = 0; j < 4; j++) {
#pragma unroll
            for (int reg = 0; reg < 4; reg++) {
                int mrow = m0 + wm + i * 16 + q * 4 + reg;
                int ncol = n0 + wn + j * 16 + r;
                if (mrow < M && ncol < Nc) {
                    float val = acc[i][j][reg];
                    Cm[(size_t)mrow * Nc + ncol] = val;
                    if (Ch16) Ch16[(size_t)mrow * Nc + ncol] = f2bf(val);
                }
            }
        }
    }
}

// al_src/al_dst[n*H+h] = sum_c h[n, h*C+c] * a_{s,d}[h*C+c]
__global__ void al_kernel(const float* __restrict__ h, const float* __restrict__ a_s,
                          const float* __restrict__ a_d, float* __restrict__ al_src,
                          float* __restrict__ al_dst, int H, int C, int NH) {
    int t = blockIdx.x * blockDim.x + threadIdx.x;
    if (t >= NH) return;
    int n = t / H, hd = t % H;
    const float* hp = h + (size_t)n * H * C + hd * C;
    float s1 = 0.f, s2 = 0.f;
    for (int c = 0; c < C; c++) {
        float v = hp[c];
        s1 += v * a_s[hd * C + c];
        s2 += v * a_d[hd * C + c];
    }
    al_src[t] = s1;
    al_dst[t] = s2;
}

// fused logit + segment softmax; alpha_t[hd*ET + p]
__global__ void attn_kernel(const float* __restrict__ al_src,
                            const float* __restrict__ al_dst,
                            const int* __restrict__ csr_src,
                            const float* __restrict__ csr_ea,
                            const float* __restrict__ we_dot,
                            const int* __restrict__ off,
                            float* __restrict__ alpha_t, int H, int NH) {
    int t = blockIdx.x * blockDim.x + threadIdx.x;
    if (t >= NH) return;
    int n = t / H, hd = t - n * H;
    int s = off[n], e = off[n + 1];
    float ad = al_dst[(size_t)n * H + hd];
    float wd = we_dot[hd];
    float* arow = alpha_t + (size_t)hd * ET;
    float m = -INFINITY;
    int p = s;
    for (; p + 3 < e; p += 4) {
        int s0 = csr_src[p], s1 = csr_src[p + 1], s2 = csr_src[p + 2], s3 = csr_src[p + 3];
        float w0 = csr_ea[p], w1 = csr_ea[p + 1], w2 = csr_ea[p + 2], w3 = csr_ea[p + 3];
        float l0 = al_src[(size_t)s0 * H + hd] + ad + w0 * wd;
        float l1 = al_src[(size_t)s1 * H + hd] + ad + w1 * wd;
        float l2 = al_src[(size_t)s2 * H + hd] + ad + w2 * wd;
        float l3 = al_src[(size_t)s3 * H + hd] + ad + w3 * wd;
        l0 = (l0 >= 0.f) ? l0 : NEG_SLOPE * l0;
        l1 = (l1 >= 0.f) ? l1 : NEG_SLOPE * l1;
        l2 = (l2 >= 0.f) ? l2 : NEG_SLOPE * l2;
        l3 = (l3 >= 0.f) ? l3 : NEG_SLOPE * l3;
        arow[p] = l0; arow[p + 1] = l1; arow[p + 2] = l2; arow[p + 3] = l3;
        m = fmaxf(m, fmaxf(fmaxf(l0, l1), fmaxf(l2, l3)));
    }
    for (; p < e; p++) {
        float lg = al_src[(size_t)csr_src[p] * H + hd] + ad + csr_ea[p] * wd;
        lg = (lg >= 0.f) ? lg : NEG_SLOPE * lg;
        arow[p] = lg;
        m = fmaxf(m, lg);
    }
    float l = 0.f;
    for (p = s; p < e; p++) {
        float ev = __expf(arow[p] - m);
        arow[p] = ev;
        l += ev;
    }
    float inv = 1.f / fmaxf(l, 1e-16f);
    for (p = s; p < e; p++) arow[p] *= inv;
}

// bf16 gather aggregate, 4 cols/thread (4|C) — layers with big h
__global__ void aggregate_v4h_kernel(const unsigned short* __restrict__ h16,
                                     const float* __restrict__ alpha_t,
                                     const int* __restrict__ off,
                                     const int* __restrict__ csr_src,
                                     const float* __restrict__ bias,
                                     float* __restrict__ out,
                                     int C, int HC, int HC4, int total4) {
    int t = blockIdx.x * blockDim.x + threadIdx.x;
    if (t >= total4) return;
    int n = t / HC4, j4 = t - n * HC4;
    int j = j4 * 4;
    int hd = j / C;
    const float* arow = alpha_t + (size_t)hd * ET;
    int s = off[n], e = off[n + 1];
    float4 acc = make_float4(0.f, 0.f, 0.f, 0.f);
    int p = s;
    for (; p + 3 < e; p += 4) {
        int idx[4]; float a[4];
#pragma unroll
        for (int u = 0; u < 4; u++) { idx[u] = csr_src[p + u]; a[u] = arow[p + u]; }
#pragma unroll
        for (int u = 0; u < 4; u++) {
            ushort4 uv = *(const ushort4*)(h16 + (size_t)idx[u] * HC + j);
            acc.x += a[u] * bf2f(uv.x);
            acc.y += a[u] * bf2f(uv.y);
            acc.z += a[u] * bf2f(uv.z);
            acc.w += a[u] * bf2f(uv.w);
        }
    }
    for (; p < e; p++) {
        int s0 = csr_src[p];
        float a0 = arow[p];
        ushort4 uv = *(const ushort4*)(h16 + (size_t)s0 * HC + j);
        acc.x += a0 * bf2f(uv.x);
        acc.y += a0 * bf2f(uv.y);
        acc.z += a0 * bf2f(uv.z);
        acc.w += a0 * bf2f(uv.w);
    }
    float4 bi = *(const float4*)(bias + j);
    float4 rr = make_float4(acc.x + bi.x, acc.y + bi.y, acc.z + bi.z, acc.w + bi.w);
    *(float4*)(out + (size_t)n * HC + j) = rr;
}

// bf16 gather aggregate, 2 cols/thread (2|C) — C=50
__global__ void aggregate_v2h_kernel(const unsigned short* __restrict__ h16,
                                     const float* __restrict__ alpha_t,
                                     const int* __restrict__ off,
                                     const int* __restrict__ csr_src,
                                     const float* __restrict__ bias,
                                     float* __restrict__ out,
                                     int C, int HC, int HC2, int total2) {
    int t = blockIdx.x * blockDim.x + threadIdx.x;
    if (t >= total2) return;
    int n = t / HC2, j2 = t - n * HC2;
    int j = j2 * 2;
    int hd = j / C;
    const float* arow = alpha_t + (size_t)hd * ET;
    int s = off[n], e = off[n + 1];
    float2 acc = make_float2(0.f, 0.f);
    int p = s;
    for (; p + 3 < e; p += 4) {
        int idx[4]; float a[4];
#pragma unroll
        for (int u = 0; u < 4; u++) { idx[u] = csr_src[p + u]; a[u] = arow[p + u]; }
#pragma unroll
        for (int u = 0; u < 4; u++) {
            ushort2 uv = *(const ushort2*)(h16 + (size_t)idx[u] * HC + j);
            acc.x += a[u] * bf2f(uv.x);
            acc.y += a[u] * bf2f(uv.y);
        }
    }
    for (; p < e; p++) {
        int s0 = csr_src[p];
        float a0 = arow[p];
        ushort2 uv = *(const ushort2*)(h16 + (size_t)s0 * HC + j);
        acc.x += a0 * bf2f(uv.x);
        acc.y += a0 * bf2f(uv.y);
    }
    float2 bi = *(const float2*)(bias + j);
    *(float2*)(out + (size_t)n * HC + j) = make_float2(acc.x + bi.x, acc.y + bi.y);
}

// f32 float4 aggregate (small layers); optional fused relu
__global__ void aggregate_v4_kernel(const float* __restrict__ hfeat,
                                    const float* __restrict__ alpha_t,
                                    const int* __restrict__ off,
                                    const int* __restrict__ csr_src,
                                    const float* __restrict__ bias,
                                    float* __restrict__ out,
                                    int C, int HC, int HC4, int total4, int relu) {
    int t = blockIdx.x * blockDim.x + threadIdx.x;
    if (t >= total4) return;
    int n = t / HC4, j4 = t - n * HC4;
    int j = j4 * 4;
    int hd = j / C;
    const float* arow = alpha_t + (size_t)hd * ET;
    int s = off[n], e = off[n + 1];
    float4 acc = make_float4(0.f, 0.f, 0.f, 0.f);
    int p = s;
    for (; p + 3 < e; p += 4) {
        int idx[4]; float a[4];
#pragma unroll
        for (int u = 0; u < 4; u++) { idx[u] = csr_src[p + u]; a[u] = arow[p + u]; }
#pragma unroll
        for (int u = 0; u < 4; u++) {
            float4 f = *(const float4*)(hfeat + (size_t)idx[u] * HC + j);
            acc.x += a[u] * f.x; acc.y += a[u] * f.y; acc.z += a[u] * f.z; acc.w += a[u] * f.w;
        }
    }
    for (; p < e; p++) {
        int s0 = csr_src[p];
        float a0 = arow[p];
        float4 f0 = *(const float4*)(hfeat + (size_t)s0 * HC + j);
        acc.x += a0 * f0.x; acc.y += a0 * f0.y; acc.z += a0 * f0.z; acc.w += a0 * f0.w;
    }
    float4 bi = *(const float4*)(bias + j);
    float4 rr = make_float4(acc.x + bi.x, acc.y + bi.y, acc.z + bi.z, acc.w + bi.w);
    if (relu) {
        rr.x = fmaxf(rr.x, 0.f); rr.y = fmaxf(rr.y, 0.f);
        rr.z = fmaxf(rr.z, 0.f); rr.w = fmaxf(rr.w, 0.f);
    }
    *(float4*)(out + (size_t)n * HC + j) = rr;
}

// scalar fallback (layer 5, HC==1)
__global__ void aggregate_kernel(const float* __restrict__ hfeat,
                                 const float* __restrict__ alpha_t,
                                 const int* __restrict__ off, const int* __restrict__ csr_src,
                                 const float* __restrict__ bias, float* __restrict__ out,
                                 int total) {
    int t = blockIdx.x * blockDim.x + threadIdx.x;
    if (t >= total) return;
    int n = t;
    int s = off[n], e = off[n + 1];
    float acc = 0.f;
    int p = s;
    for (; p + 3 < e; p += 4) {
        acc += alpha_t[p] * hfeat[csr_src[p]]
             + alpha_t[p + 1] * hfeat[csr_src[p + 1]]
             + alpha_t[p + 2] * hfeat[csr_src[p + 2]]
             + alpha_t[p + 3] * hfeat[csr_src[p + 3]];
    }
    for (; p < e; p++) acc += alpha_t[p] * hfeat[csr_src[p]];
    out[n] = acc + bias[0];
}

// ---------------- BN / activations ----------------

__global__ void bn_stats_kernel(const float* __restrict__ x, float* __restrict__ colsum,
                                float* __restrict__ colsumsq, int D) {
    int rows_per_block = (NN + gridDim.x - 1) / gridDim.x;
    int r0 = blockIdx.x * rows_per_block;
    int r1 = min(NN, r0 + rows_per_block);
    int c0 = threadIdx.x;
    int c1 = threadIdx.x + 256;
    float s0 = 0.f, q0 = 0.f, s1 = 0.f, q1 = 0.f;
    for (int r = r0; r < r1; r++) {
        const float* row = x + (size_t)r * D;
        if (c0 < D) { float v = row[c0]; s0 += v; q0 += v * v; }
        if (c1 < D) { float v = row[c1]; s1 += v; q1 += v * v; }
    }
    if (c0 < D) { atomicAdd(&colsum[c0], s0); atomicAdd(&colsumsq[c0], q0); }
    if (c1 < D) { atomicAdd(&colsum[c1], s1); atomicAdd(&colsumsq[c1], q1); }
}

// fused BN+ReLU, float4 path (4|D)
__global__ void bn_relu_v4_kernel(float* __restrict__ x,
                                  const float* __restrict__ colsum,
                                  const float* __restrict__ colsumsq,
                                  const float* __restrict__ g, const float* __restrict__ beta,
                                  int total4, int D) {
    __shared__ float sscale[512];
    __shared__ float sshift[512];
    for (int c = threadIdx.x; c < D; c += blockDim.x) {
        float mu = colsum[c] * (1.0f / (float)NN);
        float var = colsumsq[c] * (1.0f / (float)NN) - mu * mu;
        float sc = g[c] * rsqrtf(var + BN_EPS);
        sscale[c] = sc;
        sshift[c] = beta[c] - mu * sc;
    }
    __syncthreads();
    int D4 = D >> 2;
    for (int i = blockIdx.x * blockDim.x + threadIdx.x; i < total4; i += gridDim.x * blockDim.x) {
        int c4 = (i % D4) * 4;
        float4 v = *(float4*)(x + (size_t)i * 4);
        v.x = fmaxf(v.x * sscale[c4]     + sshift[c4],     0.f);
        v.y = fmaxf(v.y * sscale[c4 + 1] + sshift[c4 + 1], 0.f);
        v.z = fmaxf(v.z * sscale[c4 + 2] + sshift[c4 + 2], 0.f);
        v.w = fmaxf(v.w * sscale[c4 + 3] + sshift[c4 + 3], 0.f);
        *(float4*)(x + (size_t)i * 4) = v;
    }
}

// fused BN+ReLU, float2 path (2|D; D=250)
__global__ void bn_relu_v2_kernel(float* __restrict__ x,
                                  const float* __restrict__ colsum,
                                  const float* __restrict__ colsumsq,
                                  const float* __restrict__ g, const float* __restrict__ beta,
                                  int total2, int D) {
    __shared__ float sscale[512];
    __shared__ float sshift[512];
    for (int c = threadIdx.x; c < D; c += blockDim.x) {
        float mu = colsum[c] * (1.0f / (float)NN);
        float var = colsumsq[c] * (1.0f / (float)NN) - mu * mu;
        float sc = g[c] * rsqrtf(var + BN_EPS);
        sscale[c] = sc;
        sshift[c] = beta[c] - mu * sc;
    }
    __syncthreads();
    int D2 = D >> 1;
    for (int i = blockIdx.x * blockDim.x + threadIdx.x; i < total2; i += gridDim.x * blockDim.x) {
        int c2 = (i % D2) * 2;
        float2 v = *(float2*)(x + (size_t)i * 2);
        v.x = fmaxf(v.x * sscale[c2]     + sshift[c2],     0.f);
        v.y = fmaxf(v.y * sscale[c2 + 1] + sshift[c2 + 1], 0.f);
        *(float2*)(x + (size_t)i * 2) = v;
    }
}

// ---------------- host orchestration ----------------

static inline size_t align_up(size_t v, size_t a) { return (v + a - 1) / a * a; }

extern "C" void kernel_launch(void* const* d_in, const int* in_sizes, int n_in,
                              void* d_out, int out_size, void* d_ws, size_t ws_size,
                              hipStream_t stream) {
    const float* x_in = (const float*)d_in[0];
    const int* ei     = (const int*)d_in[1];
    const float* ew   = (const float*)d_in[2];

    char* pws = (char*)d_ws;
    size_t off_b = 0;
    auto alloc = [&](size_t bytes) -> void* {
        void* rp = pws + off_b;
        off_b = align_up(off_b + bytes, 256);
        return rp;
    };
    float* B0      = (float*)alloc((size_t)NN * 500 * 4);
    float* B1      = (float*)alloc((size_t)NN * 500 * 4);
    unsigned short* H16 = (unsigned short*)alloc((size_t)NN * 500 * 2);  // bf16 copy of h (layers 1-2)
    float* alpha_t = (float*)alloc((size_t)ET * 5 * 4);
    unsigned short* Wt_hi = (unsigned short*)alloc((size_t)512 * 512 * 2);
    unsigned short* Wt_lo = (unsigned short*)alloc((size_t)512 * 512 * 2);
    float* al_src  = (float*)alloc((size_t)NN * 5 * 4);
    float* al_dst  = (float*)alloc((size_t)NN * 5 * 4);
    float* ea      = (float*)alloc((size_t)ET * 4);
    float* csr_ea  = (float*)alloc((size_t)ET * 4);
    int* srcv      = (int*)alloc((size_t)ET * 4);
    int* dstv      = (int*)alloc((size_t)ET * 4);
    int* csr_src   = (int*)alloc((size_t)ET * 4);
    int* offarr    = (int*)alloc((size_t)(NN + 1) * 4);
    int* wptr      = (int*)alloc((size_t)NN * 4);
    int* cnt       = (int*)alloc((size_t)NN * 4);
    float* esum    = (float*)alloc(4);
    float* we_dot  = (float*)alloc(40 * 4);
    float* colsum  = (float*)alloc(512 * 4);
    float* colsumsq= (float*)alloc(512 * 4);
    (void)ws_size; (void)n_in; (void)in_sizes; (void)out_size;

    int Kp[5], Np[5];
    size_t wtoff[5];
    size_t acc_off = 0;
    for (int l = 0; l < 5; l++) {
        int K = g_cfg[l].cin, HC = g_cfg[l].C * g_cfg[l].H;
        Kp[l] = (K + 31) / 32 * 32;
        Np[l] = (HC + 127) / 128 * 128;
        wtoff[l] = acc_off;
        acc_off += (size_t)Kp[l] * Np[l];
    }

    PrepArgs pa;
    for (int l = 0; l < 5; l++) {
        pa.W[l]  = (const float*)d_in[3 + l * 6 + 0];
        pa.We[l] = (const float*)d_in[3 + l * 6 + 3];
        pa.ae[l] = (const float*)d_in[3 + l * 6 + 4];
        pa.bh[l] = Wt_hi + wtoff[l];
        pa.bl[l] = Wt_lo + wtoff[l];
        pa.K[l] = g_cfg[l].cin;
        pa.N[l] = g_cfg[l].C * g_cfg[l].H;
        pa.Kp[l] = Kp[l];
        pa.Np[l] = Np[l];
        pa.C[l] = g_cfg[l].C;
        pa.H[l] = g_cfg[l].H;
    }
    pa.wedot = we_dot;

    // graph & CSR build
    hipMemsetAsync(esum, 0, 4, stream);
    hipMemsetAsync(cnt, 0, (size_t)NN * 4, stream);
    ewsum_kernel<<<256, 256, 0, stream>>>(ew, esum, EE);
    int ebl = (ET + 255) / 256;
    build_edges_kernel<<<ebl, 256, 0, stream>>>(ei, ew, esum, srcv, dstv, ea, cnt);
    scan_kernel<<<1, 1024, 0, stream>>>(cnt, offarr, wptr);
    fill_kernel<<<ebl, 256, 0, stream>>>(dstv, srcv, ea, wptr, csr_src, csr_ea);

    // all-layer weight prep
    wedot_all_kernel<<<1, 64, 0, stream>>>(pa);
    transpose_all_kernel<<<dim3(16, 16, 5), dim3(32, 8), 0, stream>>>(pa);

    int bn_idx = 0;
    for (int l = 0; l < 5; l++) {
        const LayerCfg& cf = g_cfg[l];
        int H = cf.H, C = cf.C, K = cf.cin;
        int HC = H * C;
        const float* a_s = (const float*)d_in[3 + l * 6 + 1];
        const float* a_d = (const float*)d_in[3 + l * 6 + 2];
        const float* b   = (const float*)d_in[3 + l * 6 + 5];

        const float* X = (l == 0) ? x_in : B1;
        float* hbuf = B0;
        float* outbuf = (l == 4) ? (float*)d_out : B1;
        bool big = (l < 2);   // layers 1-2: bf16 gather path

        dim3 ggrid(Np[l] / GBNT, (NN + GBM - 1) / GBM);
        gemm_split_kernel<<<ggrid, 256, 0, stream>>>(X, Wt_hi + wtoff[l], Wt_lo + wtoff[l],
                                                     hbuf, big ? H16 : nullptr, NN, K, HC, Kp[l]);

        int NH = NN * H;
        al_kernel<<<(NH + 255) / 256, 256, 0, stream>>>(hbuf, a_s, a_d, al_src, al_dst, H, C, NH);
        attn_kernel<<<(NH + 255) / 256, 256, 0, stream>>>(al_src, al_dst, csr_src, csr_ea,
                                                          we_dot + l * 8, offarr, alpha_t, H, NH);

        int do_relu = (l == 3) ? 1 : 0;
        if (big && (C & 3) == 0) {
            int HC4 = HC / 4;
            int total4 = NN * HC4;
            aggregate_v4h_kernel<<<(total4 + 255) / 256, 256, 0, stream>>>(
                H16, alpha_t, offarr, csr_src, b, outbuf, C, HC, HC4, total4);
        } else if (big) {
            int HC2 = HC / 2;
            int total2 = NN * HC2;
            aggregate_v2h_kernel<<<(total2 + 255) / 256, 256, 0, stream>>>(
                H16, alpha_t, offarr, csr_src, b, outbuf, C, HC, HC2, total2);
        } else if ((C & 3) == 0) {
            int HC4 = HC / 4;
            int total4 = NN * HC4;
            aggregate_v4_kernel<<<(total4 + 255) / 256, 256, 0, stream>>>(
                hbuf, alpha_t, offarr, csr_src, b, outbuf, C, HC, HC4, total4, do_relu);
        } else {
            aggregate_kernel<<<(NN + 255) / 256, 256, 0, stream>>>(
                hbuf, alpha_t, offarr, csr_src, b, outbuf, NN);
        }

        int total = NN * HC;
        if (l < 3) {
            int D = HC;
            const float* g    = (const float*)d_in[33 + bn_idx * 2 + 0];
            const float* beta = (const float*)d_in[33 + bn_idx * 2 + 1];
            hipMemsetAsync(colsum, 0, 2 * 512 * 4, stream);
            bn_stats_kernel<<<256, 256, 0, stream>>>(outbuf, colsum, colsumsq, D);
            if ((D & 3) == 0) {
                bn_relu_v4_kernel<<<2048, 256, 0, stream>>>(outbuf, colsum, colsumsq, g, beta, total / 4, D);
            } else {
                bn_relu_v2_kernel<<<2048, 256, 0, stream>>>(outbuf, colsum, colsumsq, g, beta, total / 2, D);
            }
            bn_idx++;
        }
    }
}

// Round 9
// 1054.820 us; speedup vs baseline: 2.0449x; 1.0683x over previous
//
#include <hip/hip_runtime.h>
#include <hip/hip_bf16.h>
#include <math.h>

// ---------------- problem constants ----------------
#define NN 30000
#define EE 480000
#define ET (EE + NN)   // edges + self loops = 510000
#define NEG_SLOPE 0.2f
#define BN_EPS 1e-5f

struct LayerCfg { int cin, C, H; };
static const LayerCfg g_cfg[5] = {
    {128, 100, 5}, {500, 50, 5}, {250, 32, 4}, {128, 8, 4}, {32, 1, 1}
};

typedef short short8 __attribute__((ext_vector_type(8)));
typedef float f32x4 __attribute__((ext_vector_type(4)));

__device__ __forceinline__ unsigned short f2bf(float f) {
    unsigned int u = __builtin_bit_cast(unsigned int, f);
    u = (u + 0x7FFFu + ((u >> 16) & 1u)) >> 16;
    return (unsigned short)u;
}
__device__ __forceinline__ float bf2f(unsigned short h) {
    unsigned int u = ((unsigned int)h) << 16;
    return __builtin_bit_cast(float, u);
}

// ---------------- graph / CSR kernels ----------------

__global__ void ewsum_kernel(const float* __restrict__ ew, float* __restrict__ out, int E) {
    __shared__ float sdata[256];
    int tid = threadIdx.x;
    float s = 0.f;
    for (int i = blockIdx.x * blockDim.x + tid; i < E; i += gridDim.x * blockDim.x)
        s += ew[i];
    sdata[tid] = s;
    __syncthreads();
    for (int off = 128; off > 0; off >>= 1) {
        if (tid < off) sdata[tid] += sdata[tid + off];
        __syncthreads();
    }
    if (tid == 0) atomicAdd(out, sdata[0]);
}

__global__ void build_edges_kernel(const int* __restrict__ ei, const float* __restrict__ ew,
                                   const float* __restrict__ sum,
                                   int* __restrict__ srcv, int* __restrict__ dstv,
                                   float* __restrict__ ea, int* __restrict__ cnt) {
    int e = blockIdx.x * blockDim.x + threadIdx.x;
    if (e >= ET) return;
    int d;
    if (e < EE) {
        srcv[e] = ei[e];
        d = ei[EE + e];
        dstv[e] = d;
        ea[e]   = ew[e];
    } else {
        int n = e - EE;
        srcv[e] = n;
        d = n;
        dstv[e] = n;
        ea[e]   = sum[0] * (1.0f / (float)EE);
    }
    atomicAdd(&cnt[d], 1);
}

__global__ void scan_kernel(const int* __restrict__ cnt, int* __restrict__ off,
                            int* __restrict__ wptr) {
    __shared__ int lsum[1024];
    __shared__ int loff[1024];
    const int T = 1024;
    int t = threadIdx.x;
    int chunk = (NN + T - 1) / T;
    int base = t * chunk;
    int end = min(NN, base + chunk);
    int s = 0;
    for (int i = base; i < end; i++) s += cnt[i];
    lsum[t] = s;
    __syncthreads();
    if (t == 0) {
        int run = 0;
        for (int i = 0; i < T; i++) { loff[i] = run; run += lsum[i]; }
    }
    __syncthreads();
    int run = loff[t];
    for (int i = base; i < end; i++) {
        off[i] = run;
        wptr[i] = run;
        run += cnt[i];
    }
    if (t == 0) off[NN] = ET;
}

__global__ void fill_kernel(const int* __restrict__ dstv, const int* __restrict__ srcv,
                            const float* __restrict__ ea,
                            int* __restrict__ wptr, int* __restrict__ csr_src,
                            float* __restrict__ csr_ea) {
    int e = blockIdx.x * blockDim.x + threadIdx.x;
    if (e >= ET) return;
    int p = atomicAdd(&wptr[dstv[e]], 1);
    csr_src[p] = srcv[e];
    csr_ea[p]  = ea[e];
}

// ---------------- all-layer weight prep ----------------

struct PrepArgs {
    const float* W[5];
    const float* We[5];
    const float* ae[5];
    unsigned short* bh[5];
    unsigned short* bl[5];
    float* wedot;            // out: [5][8]
    int K[5], N[5], Kp[5], Np[5], C[5], H[5];
};

__global__ void wedot_all_kernel(PrepArgs a) {
    int tid = threadIdx.x;   // 64
    int l = tid >> 3, hd = tid & 7;
    if (l < 5 && hd < a.H[l]) {
        int C = a.C[l];
        const float* We = a.We[l] + hd * C;
        const float* ae = a.ae[l] + hd * C;
        float s = 0.f;
        for (int c = 0; c < C; c++) s += We[c] * ae[c];
        a.wedot[l * 8 + hd] = s;
    }
}

__global__ void transpose_all_kernel(PrepArgs a) {
    int l = blockIdx.z;
    int Kp = a.Kp[l], Np = a.Np[l], K = a.K[l], N = a.N[l];
    int kb = blockIdx.x * 32, nb = blockIdx.y * 32;
    if (kb >= Kp || nb >= Np) return;
    const float* B = a.W[l];
    unsigned short* Bth = a.bh[l];
    unsigned short* Btl = a.bl[l];
    __shared__ float tile[32][33];
    int tx = threadIdx.x, ty = threadIdx.y;   // 32 x 8
#pragma unroll
    for (int i = 0; i < 4; i++) {
        int k = kb + ty + i * 8, n = nb + tx;
        tile[ty + i * 8][tx] = (k < K && n < N) ? B[(size_t)k * N + n] : 0.f;
    }
    __syncthreads();
#pragma unroll
    for (int i = 0; i < 4; i++) {
        int n = nb + ty + i * 8, k = kb + tx;
        if (n < Np && k < Kp) {
            float v = tile[tx][ty + i * 8];
            unsigned short hi = f2bf(v);
            unsigned short lo = f2bf(v - bf2f(hi));
            size_t idx = (size_t)n * Kp + k;
            Bth[idx] = hi;
            Btl[idx] = lo;
        }
    }
}

// ---------------- split-bf16 MFMA GEMM ----------------
#define GBM 128
#define GBNT 128
#define GBK 32
#define ASTR 40
__global__ __launch_bounds__(256) void gemm_split_kernel(const float* __restrict__ A,
                                                         const unsigned short* __restrict__ Bt_hi,
                                                         const unsigned short* __restrict__ Bt_lo,
                                                         float* __restrict__ Cm,
                                                         unsigned short* __restrict__ Ch16,
                                                         int M, int K, int Nc, int Kpad) {
    __shared__ short AsH[GBM * ASTR];
    __shared__ short AsL[GBM * ASTR];
    __shared__ short BsH[GBNT * ASTR];
    __shared__ short BsL[GBNT * ASTR];
    int tid = threadIdx.x;
    int wave = tid >> 6, lane = tid & 63;
    int q = lane >> 4, r = lane & 15;
    int m0 = blockIdx.y * GBM, n0 = blockIdx.x * GBNT;
    int wm = (wave & 1) * 64, wn = (wave >> 1) * 64;
    f32x4 acc[4][4];
#pragma unroll
    for (int i = 0; i < 4; i++)
#pragma unroll
        for (int j = 0; j < 4; j++) acc[i][j] = (f32x4)(0.f);

    int arow = tid >> 3;
    int alk  = tid & 7;
    int arow2 = tid >> 1;
    int acol2 = (tid & 1) * 16;
    int brow = tid >> 2;
    int bcol = (tid & 3) * 8;
    bool vecA = ((K & 3) == 0);

    int ksteps = (K + GBK - 1) / GBK;
    for (int ks = 0; ks < ksteps; ks++) {
        int k0 = ks * GBK;
        if (vecA) {
            int m = m0 + arow2;
            float v[16];
            if (m < M && (k0 + acol2 + 16) <= K) {
                const float* Ap = A + (size_t)m * K + k0 + acol2;
                float4 f0 = *(const float4*)(Ap);
                float4 f1 = *(const float4*)(Ap + 4);
                float4 f2 = *(const float4*)(Ap + 8);
                float4 f3 = *(const float4*)(Ap + 12);
                v[0]=f0.x; v[1]=f0.y; v[2]=f0.z; v[3]=f0.w;
                v[4]=f1.x; v[5]=f1.y; v[6]=f1.z; v[7]=f1.w;
                v[8]=f2.x; v[9]=f2.y; v[10]=f2.z; v[11]=f2.w;
                v[12]=f3.x; v[13]=f3.y; v[14]=f3.z; v[15]=f3.w;
            } else {
                const float* Ap = A + (size_t)m * K + k0 + acol2;
#pragma unroll
                for (int i = 0; i < 16; i++)
                    v[i] = (m < M && (k0 + acol2 + i) < K) ? Ap[i] : 0.f;
            }
#pragma unroll
            for (int i = 0; i < 16; i++) {
                unsigned short hi = f2bf(v[i]);
                unsigned short lo = f2bf(v[i] - bf2f(hi));
                AsH[arow2 * ASTR + acol2 + i] = (short)hi;
                AsL[arow2 * ASTR + acol2 + i] = (short)lo;
            }
        } else {
#pragma unroll
            for (int p = 0; p < 4; p++) {
                int row = p * 32 + arow;
                int m = m0 + row;
#pragma unroll
                for (int i = 0; i < 4; i++) {
                    int k = alk + 8 * i;
                    float v = 0.f;
                    if (m < M && (k0 + k) < K) v = A[(size_t)m * K + k0 + k];
                    unsigned short hi = f2bf(v);
                    unsigned short lo = f2bf(v - bf2f(hi));
                    AsH[row * ASTR + k] = (short)hi;
                    AsL[row * ASTR + k] = (short)lo;
                }
            }
        }
#pragma unroll
        for (int p = 0; p < 2; p++) {
            int row = p * 64 + brow;
            size_t gidx = (size_t)(n0 + row) * Kpad + k0 + bcol;
            *((uint4*)(BsH + row * ASTR + bcol)) = *((const uint4*)(Bt_hi + gidx));
            *((uint4*)(BsL + row * ASTR + bcol)) = *((const uint4*)(Bt_lo + gidx));
        }
        __syncthreads();
        short8 ah[4], al[4], bh[4], bl[4];
#pragma unroll
        for (int i = 0; i < 4; i++) {
            ah[i] = *((const short8*)(AsH + (wm + i * 16 + r) * ASTR + q * 8));
            al[i] = *((const short8*)(AsL + (wm + i * 16 + r) * ASTR + q * 8));
        }
#pragma unroll
        for (int j = 0; j < 4; j++) {
            bh[j] = *((const short8*)(BsH + (wn + j * 16 + r) * ASTR + q * 8));
            bl[j] = *((const short8*)(BsL + (wn + j * 16 + r) * ASTR + q * 8));
        }
#pragma unroll
        for (int i = 0; i < 4; i++)
#pragma unroll
            for (int j = 0; j < 4; j++) {
                acc[i][j] = __builtin_amdgcn_mfma_f32_16x16x32_bf16(ah[i], bh[j], acc[i][j], 0, 0, 0);
                acc[i][j] = __builtin_amdgcn_mfma_f32_16x16x32_bf16(ah[i], bl[j], acc[i][j], 0, 0, 0);
                acc[i][j] = __builtin_amdgcn_mfma_f32_16x16x32_bf16(al[i], bh[j], acc[i][j], 0, 0, 0);
            }
        __syncthreads();
    }
#pragma unroll
    for (int i = 0; i < 4; i++) {
#pragma unroll
        for (int j = 0; j < 4; j++) {
#pragma unroll
            for (int reg = 0; reg < 4; reg++) {
                int mrow = m0 + wm + i * 16 + q * 4 + reg;
                int ncol = n0 + wn + j * 16 + r;
                if (mrow < M && ncol < Nc) {
                    float val = acc[i][j][reg];
                    Cm[(size_t)mrow * Nc + ncol] = val;
                    if (Ch16) Ch16[(size_t)mrow * Nc + ncol] = f2bf(val);
                }
            }
        }
    }
}

// wave-per-node attention dots: coalesced row read, per-head register acc,
// butterfly reduce. Unrolled head loop keeps register indices compile-time.
__global__ void al_wave_kernel(const float* __restrict__ h, const float* __restrict__ a_s,
                               const float* __restrict__ a_d, float* __restrict__ al_src,
                               float* __restrict__ al_dst, int H, int C, int HC) {
    int w = (blockIdx.x * blockDim.x + threadIdx.x) >> 6;
    int lane = threadIdx.x & 63;
    if (w >= NN) return;
    const float* row = h + (size_t)w * HC;
    float s1[5] = {0.f, 0.f, 0.f, 0.f, 0.f};
    float s2[5] = {0.f, 0.f, 0.f, 0.f, 0.f};
#pragma unroll
    for (int hd = 0; hd < 5; hd++) {
        if (hd >= H) break;
        int base = hd * C;
        for (int c = lane; c < C; c += 64) {
            float v = row[base + c];
            s1[hd] += v * a_s[base + c];
            s2[hd] += v * a_d[base + c];
        }
    }
#pragma unroll
    for (int hd = 0; hd < 5; hd++) {
        if (hd >= H) break;
#pragma unroll
        for (int off = 32; off > 0; off >>= 1) {
            s1[hd] += __shfl_xor(s1[hd], off, 64);
            s2[hd] += __shfl_xor(s2[hd], off, 64);
        }
    }
    if (lane == 0) {
#pragma unroll
        for (int hd = 0; hd < 5; hd++) {
            if (hd >= H) break;
            al_src[(size_t)w * H + hd] = s1[hd];
            al_dst[(size_t)w * H + hd] = s2[hd];
        }
    }
}

// fused logit + segment softmax; alpha_t[hd*ET + p]
__global__ void attn_kernel(const float* __restrict__ al_src,
                            const float* __restrict__ al_dst,
                            const int* __restrict__ csr_src,
                            const float* __restrict__ csr_ea,
                            const float* __restrict__ we_dot,
                            const int* __restrict__ off,
                            float* __restrict__ alpha_t, int H, int NH) {
    int t = blockIdx.x * blockDim.x + threadIdx.x;
    if (t >= NH) return;
    int n = t / H, hd = t - n * H;
    int s = off[n], e = off[n + 1];
    float ad = al_dst[(size_t)n * H + hd];
    float wd = we_dot[hd];
    float* arow = alpha_t + (size_t)hd * ET;
    float m = -INFINITY;
    int p = s;
    for (; p + 3 < e; p += 4) {
        int s0 = csr_src[p], s1 = csr_src[p + 1], s2 = csr_src[p + 2], s3 = csr_src[p + 3];
        float w0 = csr_ea[p], w1 = csr_ea[p + 1], w2 = csr_ea[p + 2], w3 = csr_ea[p + 3];
        float l0 = al_src[(size_t)s0 * H + hd] + ad + w0 * wd;
        float l1 = al_src[(size_t)s1 * H + hd] + ad + w1 * wd;
        float l2 = al_src[(size_t)s2 * H + hd] + ad + w2 * wd;
        float l3 = al_src[(size_t)s3 * H + hd] + ad + w3 * wd;
        l0 = (l0 >= 0.f) ? l0 : NEG_SLOPE * l0;
        l1 = (l1 >= 0.f) ? l1 : NEG_SLOPE * l1;
        l2 = (l2 >= 0.f) ? l2 : NEG_SLOPE * l2;
        l3 = (l3 >= 0.f) ? l3 : NEG_SLOPE * l3;
        arow[p] = l0; arow[p + 1] = l1; arow[p + 2] = l2; arow[p + 3] = l3;
        m = fmaxf(m, fmaxf(fmaxf(l0, l1), fmaxf(l2, l3)));
    }
    for (; p < e; p++) {
        float lg = al_src[(size_t)csr_src[p] * H + hd] + ad + csr_ea[p] * wd;
        lg = (lg >= 0.f) ? lg : NEG_SLOPE * lg;
        arow[p] = lg;
        m = fmaxf(m, lg);
    }
    float l = 0.f;
    for (p = s; p < e; p++) {
        float ev = __expf(arow[p] - m);
        arow[p] = ev;
        l += ev;
    }
    float inv = 1.f / fmaxf(l, 1e-16f);
    for (p = s; p < e; p++) arow[p] *= inv;
}

// bf16 gather aggregate, 4 cols/thread (4|C)
__global__ void aggregate_v4h_kernel(const unsigned short* __restrict__ h16,
                                     const float* __restrict__ alpha_t,
                                     const int* __restrict__ off,
                                     const int* __restrict__ csr_src,
                                     const float* __restrict__ bias,
                                     float* __restrict__ out,
                                     int C, int HC, int HC4, int total4) {
    int t = blockIdx.x * blockDim.x + threadIdx.x;
    if (t >= total4) return;
    int n = t / HC4, j4 = t - n * HC4;
    int j = j4 * 4;
    int hd = j / C;
    const float* arow = alpha_t + (size_t)hd * ET;
    int s = off[n], e = off[n + 1];
    float4 acc = make_float4(0.f, 0.f, 0.f, 0.f);
    int p = s;
    for (; p + 3 < e; p += 4) {
        int idx[4]; float a[4];
#pragma unroll
        for (int u = 0; u < 4; u++) { idx[u] = csr_src[p + u]; a[u] = arow[p + u]; }
#pragma unroll
        for (int u = 0; u < 4; u++) {
            ushort4 uv = *(const ushort4*)(h16 + (size_t)idx[u] * HC + j);
            acc.x += a[u] * bf2f(uv.x);
            acc.y += a[u] * bf2f(uv.y);
            acc.z += a[u] * bf2f(uv.z);
            acc.w += a[u] * bf2f(uv.w);
        }
    }
    for (; p < e; p++) {
        int s0 = csr_src[p];
        float a0 = arow[p];
        ushort4 uv = *(const ushort4*)(h16 + (size_t)s0 * HC + j);
        acc.x += a0 * bf2f(uv.x);
        acc.y += a0 * bf2f(uv.y);
        acc.z += a0 * bf2f(uv.z);
        acc.w += a0 * bf2f(uv.w);
    }
    float4 bi = *(const float4*)(bias + j);
    float4 rr = make_float4(acc.x + bi.x, acc.y + bi.y, acc.z + bi.z, acc.w + bi.w);
    *(float4*)(out + (size_t)n * HC + j) = rr;
}

// bf16 gather aggregate, 2 cols/thread (2|C) — C=50
__global__ void aggregate_v2h_kernel(const unsigned short* __restrict__ h16,
                                     const float* __restrict__ alpha_t,
                                     const int* __restrict__ off,
                                     const int* __restrict__ csr_src,
                                     const float* __restrict__ bias,
                                     float* __restrict__ out,
                                     int C, int HC, int HC2, int total2) {
    int t = blockIdx.x * blockDim.x + threadIdx.x;
    if (t >= total2) return;
    int n = t / HC2, j2 = t - n * HC2;
    int j = j2 * 2;
    int hd = j / C;
    const float* arow = alpha_t + (size_t)hd * ET;
    int s = off[n], e = off[n + 1];
    float2 acc = make_float2(0.f, 0.f);
    int p = s;
    for (; p + 3 < e; p += 4) {
        int idx[4]; float a[4];
#pragma unroll
        for (int u = 0; u < 4; u++) { idx[u] = csr_src[p + u]; a[u] = arow[p + u]; }
#pragma unroll
        for (int u = 0; u < 4; u++) {
            ushort2 uv = *(const ushort2*)(h16 + (size_t)idx[u] * HC + j);
            acc.x += a[u] * bf2f(uv.x);
            acc.y += a[u] * bf2f(uv.y);
        }
    }
    for (; p < e; p++) {
        int s0 = csr_src[p];
        float a0 = arow[p];
        ushort2 uv = *(const ushort2*)(h16 + (size_t)s0 * HC + j);
        acc.x += a0 * bf2f(uv.x);
        acc.y += a0 * bf2f(uv.y);
    }
    float2 bi = *(const float2*)(bias + j);
    *(float2*)(out + (size_t)n * HC + j) = make_float2(acc.x + bi.x, acc.y + bi.y);
}

// f32 float4 aggregate (small layers); optional fused relu
__global__ void aggregate_v4_kernel(const float* __restrict__ hfeat,
                                    const float* __restrict__ alpha_t,
                                    const int* __restrict__ off,
                                    const int* __restrict__ csr_src,
                                    const float* __restrict__ bias,
                                    float* __restrict__ out,
                                    int C, int HC, int HC4, int total4, int relu) {
    int t = blockIdx.x * blockDim.x + threadIdx.x;
    if (t >= total4) return;
    int n = t / HC4, j4 = t - n * HC4;
    int j = j4 * 4;
    int hd = j / C;
    const float* arow = alpha_t + (size_t)hd * ET;
    int s = off[n], e = off[n + 1];
    float4 acc = make_float4(0.f, 0.f, 0.f, 0.f);
    int p = s;
    for (; p + 3 < e; p += 4) {
        int idx[4]; float a[4];
#pragma unroll
        for (int u = 0; u < 4; u++) { idx[u] = csr_src[p + u]; a[u] = arow[p + u]; }
#pragma unroll
        for (int u = 0; u < 4; u++) {
            float4 f = *(const float4*)(hfeat + (size_t)idx[u] * HC + j);
            acc.x += a[u] * f.x; acc.y += a[u] * f.y; acc.z += a[u] * f.z; acc.w += a[u] * f.w;
        }
    }
    for (; p < e; p++) {
        int s0 = csr_src[p];
        float a0 = arow[p];
        float4 f0 = *(const float4*)(hfeat + (size_t)s0 * HC + j);
        acc.x += a0 * f0.x; acc.y += a0 * f0.y; acc.z += a0 * f0.z; acc.w += a0 * f0.w;
    }
    float4 bi = *(const float4*)(bias + j);
    float4 rr = make_float4(acc.x + bi.x, acc.y + bi.y, acc.z + bi.z, acc.w + bi.w);
    if (relu) {
        rr.x = fmaxf(rr.x, 0.f); rr.y = fmaxf(rr.y, 0.f);
        rr.z = fmaxf(rr.z, 0.f); rr.w = fmaxf(rr.w, 0.f);
    }
    *(float4*)(out + (size_t)n * HC + j) = rr;
}

// scalar fallback (layer 5, HC==1)
__global__ void aggregate_kernel(const float* __restrict__ hfeat,
                                 const float* __restrict__ alpha_t,
                                 const int* __restrict__ off, const int* __restrict__ csr_src,
                                 const float* __restrict__ bias, float* __restrict__ out,
                                 int total) {
    int t = blockIdx.x * blockDim.x + threadIdx.x;
    if (t >= total) return;
    int n = t;
    int s = off[n], e = off[n + 1];
    float acc = 0.f;
    int p = s;
    for (; p + 3 < e; p += 4) {
        acc += alpha_t[p] * hfeat[csr_src[p]]
             + alpha_t[p + 1] * hfeat[csr_src[p + 1]]
             + alpha_t[p + 2] * hfeat[csr_src[p + 2]]
             + alpha_t[p + 3] * hfeat[csr_src[p + 3]];
    }
    for (; p < e; p++) acc += alpha_t[p] * hfeat[csr_src[p]];
    out[n] = acc + bias[0];
}

// ---------------- BN / activations ----------------

__global__ void bn_stats_kernel(const float* __restrict__ x, float* __restrict__ colsum,
                                float* __restrict__ colsumsq, int D) {
    int rows_per_block = (NN + gridDim.x - 1) / gridDim.x;
    int r0 = blockIdx.x * rows_per_block;
    int r1 = min(NN, r0 + rows_per_block);
    int c0 = threadIdx.x;
    int c1 = threadIdx.x + 256;
    float s0 = 0.f, q0 = 0.f, s1 = 0.f, q1 = 0.f;
    for (int r = r0; r < r1; r++) {
        const float* row = x + (size_t)r * D;
        if (c0 < D) { float v = row[c0]; s0 += v; q0 += v * v; }
        if (c1 < D) { float v = row[c1]; s1 += v; q1 += v * v; }
    }
    if (c0 < D) { atomicAdd(&colsum[c0], s0); atomicAdd(&colsumsq[c0], q0); }
    if (c1 < D) { atomicAdd(&colsum[c1], s1); atomicAdd(&colsumsq[c1], q1); }
}

// fused BN+ReLU, float4 path (4|D)
__global__ void bn_relu_v4_kernel(float* __restrict__ x,
                                  const float* __restrict__ colsum,
                                  const float* __restrict__ colsumsq,
                                  const float* __restrict__ g, const float* __restrict__ beta,
                                  int total4, int D) {
    __shared__ float sscale[512];
    __shared__ float sshift[512];
    for (int c = threadIdx.x; c < D; c += blockDim.x) {
        float mu = colsum[c] * (1.0f / (float)NN);
        float var = colsumsq[c] * (1.0f / (float)NN) - mu * mu;
        float sc = g[c] * rsqrtf(var + BN_EPS);
        sscale[c] = sc;
        sshift[c] = beta[c] - mu * sc;
    }
    __syncthreads();
    int D4 = D >> 2;
    for (int i = blockIdx.x * blockDim.x + threadIdx.x; i < total4; i += gridDim.x * blockDim.x) {
        int c4 = (i % D4) * 4;
        float4 v = *(float4*)(x + (size_t)i * 4);
        v.x = fmaxf(v.x * sscale[c4]     + sshift[c4],     0.f);
        v.y = fmaxf(v.y * sscale[c4 + 1] + sshift[c4 + 1], 0.f);
        v.z = fmaxf(v.z * sscale[c4 + 2] + sshift[c4 + 2], 0.f);
        v.w = fmaxf(v.w * sscale[c4 + 3] + sshift[c4 + 3], 0.f);
        *(float4*)(x + (size_t)i * 4) = v;
    }
}

// fused BN+ReLU, float2 path (2|D; D=250)
__global__ void bn_relu_v2_kernel(float* __restrict__ x,
                                  const float* __restrict__ colsum,
                                  const float* __restrict__ colsumsq,
                                  const float* __restrict__ g, const float* __restrict__ beta,
                                  int total2, int D) {
    __shared__ float sscale[512];
    __shared__ float sshift[512];
    for (int c = threadIdx.x; c < D; c += blockDim.x) {
        float mu = colsum[c] * (1.0f / (float)NN);
        float var = colsumsq[c] * (1.0f / (float)NN) - mu * mu;
        float sc = g[c] * rsqrtf(var + BN_EPS);
        sscale[c] = sc;
        sshift[c] = beta[c] - mu * sc;
    }
    __syncthreads();
    int D2 = D >> 1;
    for (int i = blockIdx.x * blockDim.x + threadIdx.x; i < total2; i += gridDim.x * blockDim.x) {
        int c2 = (i % D2) * 2;
        float2 v = *(float2*)(x + (size_t)i * 2);
        v.x = fmaxf(v.x * sscale[c2]     + sshift[c2],     0.f);
        v.y = fmaxf(v.y * sscale[c2 + 1] + sshift[c2 + 1], 0.f);
        *(float2*)(x + (size_t)i * 2) = v;
    }
}

// ---------------- host orchestration ----------------

static inline size_t align_up(size_t v, size_t a) { return (v + a - 1) / a * a; }

extern "C" void kernel_launch(void* const* d_in, const int* in_sizes, int n_in,
                              void* d_out, int out_size, void* d_ws, size_t ws_size,
                              hipStream_t stream) {
    const float* x_in = (const float*)d_in[0];
    const int* ei     = (const int*)d_in[1];
    const float* ew   = (const float*)d_in[2];

    char* pws = (char*)d_ws;
    size_t off_b = 0;
    auto alloc = [&](size_t bytes) -> void* {
        void* rp = pws + off_b;
        off_b = align_up(off_b + bytes, 256);
        return rp;
    };
    float* B0      = (float*)alloc((size_t)NN * 500 * 4);
    float* B1      = (float*)alloc((size_t)NN * 500 * 4);
    unsigned short* H16 = (unsigned short*)alloc((size_t)NN * 500 * 2);
    float* alpha_t = (float*)alloc((size_t)ET * 5 * 4);
    unsigned short* Wt_hi = (unsigned short*)alloc((size_t)512 * 512 * 2);
    unsigned short* Wt_lo = (unsigned short*)alloc((size_t)512 * 512 * 2);
    float* al_src  = (float*)alloc((size_t)NN * 5 * 4);
    float* al_dst  = (float*)alloc((size_t)NN * 5 * 4);
    float* ea      = (float*)alloc((size_t)ET * 4);
    float* csr_ea  = (float*)alloc((size_t)ET * 4);
    int* srcv      = (int*)alloc((size_t)ET * 4);
    int* dstv      = (int*)alloc((size_t)ET * 4);
    int* csr_src   = (int*)alloc((size_t)ET * 4);
    int* offarr    = (int*)alloc((size_t)(NN + 1) * 4);
    int* wptr      = (int*)alloc((size_t)NN * 4);
    int* cnt       = (int*)alloc((size_t)NN * 4);
    float* esum    = (float*)alloc(4);
    float* we_dot  = (float*)alloc(40 * 4);
    float* colsum  = (float*)alloc(512 * 4);
    float* colsumsq= (float*)alloc(512 * 4);
    (void)ws_size; (void)n_in; (void)in_sizes; (void)out_size;

    int Kp[5], Np[5];
    size_t wtoff[5];
    size_t acc_off = 0;
    for (int l = 0; l < 5; l++) {
        int K = g_cfg[l].cin, HC = g_cfg[l].C * g_cfg[l].H;
        Kp[l] = (K + 31) / 32 * 32;
        Np[l] = (HC + 127) / 128 * 128;
        wtoff[l] = acc_off;
        acc_off += (size_t)Kp[l] * Np[l];
    }

    PrepArgs pa;
    for (int l = 0; l < 5; l++) {
        pa.W[l]  = (const float*)d_in[3 + l * 6 + 0];
        pa.We[l] = (const float*)d_in[3 + l * 6 + 3];
        pa.ae[l] = (const float*)d_in[3 + l * 6 + 4];
        pa.bh[l] = Wt_hi + wtoff[l];
        pa.bl[l] = Wt_lo + wtoff[l];
        pa.K[l] = g_cfg[l].cin;
        pa.N[l] = g_cfg[l].C * g_cfg[l].H;
        pa.Kp[l] = Kp[l];
        pa.Np[l] = Np[l];
        pa.C[l] = g_cfg[l].C;
        pa.H[l] = g_cfg[l].H;
    }
    pa.wedot = we_dot;

    // graph & CSR build
    hipMemsetAsync(esum, 0, 4, stream);
    hipMemsetAsync(cnt, 0, (size_t)NN * 4, stream);
    ewsum_kernel<<<256, 256, 0, stream>>>(ew, esum, EE);
    int ebl = (ET + 255) / 256;
    build_edges_kernel<<<ebl, 256, 0, stream>>>(ei, ew, esum, srcv, dstv, ea, cnt);
    scan_kernel<<<1, 1024, 0, stream>>>(cnt, offarr, wptr);
    fill_kernel<<<ebl, 256, 0, stream>>>(dstv, srcv, ea, wptr, csr_src, csr_ea);

    // all-layer weight prep
    wedot_all_kernel<<<1, 64, 0, stream>>>(pa);
    transpose_all_kernel<<<dim3(16, 16, 5), dim3(32, 8), 0, stream>>>(pa);

    int bn_idx = 0;
    for (int l = 0; l < 5; l++) {
        const LayerCfg& cf = g_cfg[l];
        int H = cf.H, C = cf.C, K = cf.cin;
        int HC = H * C;
        const float* a_s = (const float*)d_in[3 + l * 6 + 1];
        const float* a_d = (const float*)d_in[3 + l * 6 + 2];
        const float* b   = (const float*)d_in[3 + l * 6 + 5];

        const float* X = (l == 0) ? x_in : B1;
        float* hbuf = B0;
        float* outbuf = (l == 4) ? (float*)d_out : B1;
        bool big = (l < 2);

        dim3 ggrid(Np[l] / GBNT, (NN + GBM - 1) / GBM);
        gemm_split_kernel<<<ggrid, 256, 0, stream>>>(X, Wt_hi + wtoff[l], Wt_lo + wtoff[l],
                                                     hbuf, big ? H16 : nullptr, NN, K, HC, Kp[l]);

        int NH = NN * H;
        int alblocks = (NN * 64 + 255) / 256;
        al_wave_kernel<<<alblocks, 256, 0, stream>>>(hbuf, a_s, a_d, al_src, al_dst, H, C, HC);
        attn_kernel<<<(NH + 255) / 256, 256, 0, stream>>>(al_src, al_dst, csr_src, csr_ea,
                                                          we_dot + l * 8, offarr, alpha_t, H, NH);

        int do_relu = (l == 3) ? 1 : 0;
        if (big && (C & 3) == 0) {
            int HC4 = HC / 4;
            int total4 = NN * HC4;
            aggregate_v4h_kernel<<<(total4 + 255) / 256, 256, 0, stream>>>(
                H16, alpha_t, offarr, csr_src, b, outbuf, C, HC, HC4, total4);
        } else if (big) {
            int HC2 = HC / 2;
            int total2 = NN * HC2;
            aggregate_v2h_kernel<<<(total2 + 255) / 256, 256, 0, stream>>>(
                H16, alpha_t, offarr, csr_src, b, outbuf, C, HC, HC2, total2);
        } else if ((C & 3) == 0) {
            int HC4 = HC / 4;
            int total4 = NN * HC4;
            aggregate_v4_kernel<<<(total4 + 255) / 256, 256, 0, stream>>>(
                hbuf, alpha_t, offarr, csr_src, b, outbuf, C, HC, HC4, total4, do_relu);
        } else {
            aggregate_kernel<<<(NN + 255) / 256, 256, 0, stream>>>(
                hbuf, alpha_t, offarr, csr_src, b, outbuf, NN);
        }

        int total = NN * HC;
        if (l < 3) {
            int D = HC;
            const float* g    = (const float*)d_in[33 + bn_idx * 2 + 0];
            const float* beta = (const float*)d_in[33 + bn_idx * 2 + 1];
            hipMemsetAsync(colsum, 0, 2 * 512 * 4, stream);
            bn_stats_kernel<<<256, 256, 0, stream>>>(outbuf, colsum, colsumsq, D);
            if ((D & 3) == 0) {
                bn_relu_v4_kernel<<<2048, 256, 0, stream>>>(outbuf, colsum, colsumsq, g, beta, total / 4, D);
            } else {
                bn_relu_v2_kernel<<<2048, 256, 0, stream>>>(outbuf, colsum, colsumsq, g, beta, total / 2, D);
            }
            bn_idx++;
        }
    }
}

// Round 10
// 1006.344 us; speedup vs baseline: 2.1434x; 1.0482x over previous
//
#include <hip/hip_runtime.h>
#include <hip/hip_bf16.h>
#include <math.h>

// ---------------- problem constants ----------------
#define NN 30000
#define EE 480000
#define ET (EE + NN)   // edges + self loops = 510000
#define NEG_SLOPE 0.2f
#define BN_EPS 1e-5f

struct LayerCfg { int cin, C, H; };
static const LayerCfg g_cfg[5] = {
    {128, 100, 5}, {500, 50, 5}, {250, 32, 4}, {128, 8, 4}, {32, 1, 1}
};

typedef short short8 __attribute__((ext_vector_type(8)));
typedef float f32x4 __attribute__((ext_vector_type(4)));

__device__ __forceinline__ unsigned short f2bf(float f) {
    unsigned int u = __builtin_bit_cast(unsigned int, f);
    u = (u + 0x7FFFu + ((u >> 16) & 1u)) >> 16;
    return (unsigned short)u;
}
__device__ __forceinline__ float bf2f(unsigned short h) {
    unsigned int u = ((unsigned int)h) << 16;
    return __builtin_bit_cast(float, u);
}

// ---------------- graph / CSR kernels ----------------

__global__ void ewsum_kernel(const float* __restrict__ ew, float* __restrict__ out, int E) {
    __shared__ float sdata[256];
    int tid = threadIdx.x;
    float s = 0.f;
    for (int i = blockIdx.x * blockDim.x + tid; i < E; i += gridDim.x * blockDim.x)
        s += ew[i];
    sdata[tid] = s;
    __syncthreads();
    for (int off = 128; off > 0; off >>= 1) {
        if (tid < off) sdata[tid] += sdata[tid + off];
        __syncthreads();
    }
    if (tid == 0) atomicAdd(out, sdata[0]);
}

__global__ void build_edges_kernel(const int* __restrict__ ei, const float* __restrict__ ew,
                                   const float* __restrict__ sum,
                                   int* __restrict__ srcv, int* __restrict__ dstv,
                                   float* __restrict__ ea, int* __restrict__ cnt) {
    int e = blockIdx.x * blockDim.x + threadIdx.x;
    if (e >= ET) return;
    int d;
    if (e < EE) {
        srcv[e] = ei[e];
        d = ei[EE + e];
        dstv[e] = d;
        ea[e]   = ew[e];
    } else {
        int n = e - EE;
        srcv[e] = n;
        d = n;
        dstv[e] = n;
        ea[e]   = sum[0] * (1.0f / (float)EE);
    }
    atomicAdd(&cnt[d], 1);
}

__global__ void scan_kernel(const int* __restrict__ cnt, int* __restrict__ off,
                            int* __restrict__ wptr) {
    __shared__ int lsum[1024];
    __shared__ int loff[1024];
    const int T = 1024;
    int t = threadIdx.x;
    int chunk = (NN + T - 1) / T;
    int base = t * chunk;
    int end = min(NN, base + chunk);
    int s = 0;
    for (int i = base; i < end; i++) s += cnt[i];
    lsum[t] = s;
    __syncthreads();
    if (t == 0) {
        int run = 0;
        for (int i = 0; i < T; i++) { loff[i] = run; run += lsum[i]; }
    }
    __syncthreads();
    int run = loff[t];
    for (int i = base; i < end; i++) {
        off[i] = run;
        wptr[i] = run;
        run += cnt[i];
    }
    if (t == 0) off[NN] = ET;
}

__global__ void fill_kernel(const int* __restrict__ dstv, const int* __restrict__ srcv,
                            const float* __restrict__ ea,
                            int* __restrict__ wptr, int* __restrict__ csr_src,
                            float* __restrict__ csr_ea) {
    int e = blockIdx.x * blockDim.x + threadIdx.x;
    if (e >= ET) return;
    int p = atomicAdd(&wptr[dstv[e]], 1);
    csr_src[p] = srcv[e];
    csr_ea[p]  = ea[e];
}

// ---------------- all-layer weight prep ----------------

struct PrepArgs {
    const float* W[5];
    const float* We[5];
    const float* ae[5];
    unsigned short* bh[5];
    unsigned short* bl[5];
    float* wedot;            // out: [5][8]
    int K[5], N[5], Kp[5], Np[5], C[5], H[5];
};

__global__ void wedot_all_kernel(PrepArgs a) {
    int tid = threadIdx.x;   // 64
    int l = tid >> 3, hd = tid & 7;
    if (l < 5 && hd < a.H[l]) {
        int C = a.C[l];
        const float* We = a.We[l] + hd * C;
        const float* ae = a.ae[l] + hd * C;
        float s = 0.f;
        for (int c = 0; c < C; c++) s += We[c] * ae[c];
        a.wedot[l * 8 + hd] = s;
    }
}

__global__ void transpose_all_kernel(PrepArgs a) {
    int l = blockIdx.z;
    int Kp = a.Kp[l], Np = a.Np[l], K = a.K[l], N = a.N[l];
    int kb = blockIdx.x * 32, nb = blockIdx.y * 32;
    if (kb >= Kp || nb >= Np) return;
    const float* B = a.W[l];
    unsigned short* Bth = a.bh[l];
    unsigned short* Btl = a.bl[l];
    __shared__ float tile[32][33];
    int tx = threadIdx.x, ty = threadIdx.y;   // 32 x 8
#pragma unroll
    for (int i = 0; i < 4; i++) {
        int k = kb + ty + i * 8, n = nb + tx;
        tile[ty + i * 8][tx] = (k < K && n < N) ? B[(size_t)k * N + n] : 0.f;
    }
    __syncthreads();
#pragma unroll
    for (int i = 0; i < 4; i++) {
        int n = nb + ty + i * 8, k = kb + tx;
        if (n < Np && k < Kp) {
            float v = tile[tx][ty + i * 8];
            unsigned short hi = f2bf(v);
            unsigned short lo = f2bf(v - bf2f(hi));
            size_t idx = (size_t)n * Kp + k;
            Bth[idx] = hi;
            Btl[idx] = lo;
        }
    }
}

// ---------------- split-bf16 MFMA GEMM ----------------
#define GBM 128
#define GBNT 128
#define GBK 32
#define ASTR 40
__global__ __launch_bounds__(256) void gemm_split_kernel(const float* __restrict__ A,
                                                         const unsigned short* __restrict__ Bt_hi,
                                                         const unsigned short* __restrict__ Bt_lo,
                                                         float* __restrict__ Cm,
                                                         unsigned short* __restrict__ Ch16,
                                                         int M, int K, int Nc, int Kpad) {
    __shared__ short AsH[GBM * ASTR];
    __shared__ short AsL[GBM * ASTR];
    __shared__ short BsH[GBNT * ASTR];
    __shared__ short BsL[GBNT * ASTR];
    int tid = threadIdx.x;
    int wave = tid >> 6, lane = tid & 63;
    int q = lane >> 4, r = lane & 15;
    int m0 = blockIdx.y * GBM, n0 = blockIdx.x * GBNT;
    int wm = (wave & 1) * 64, wn = (wave >> 1) * 64;
    f32x4 acc[4][4];
#pragma unroll
    for (int i = 0; i < 4; i++)
#pragma unroll
        for (int j = 0; j < 4; j++) acc[i][j] = (f32x4)(0.f);

    int arow = tid >> 3;
    int alk  = tid & 7;
    int arow2 = tid >> 1;
    int acol2 = (tid & 1) * 16;
    int brow = tid >> 2;
    int bcol = (tid & 3) * 8;
    bool vecA = ((K & 3) == 0);

    int ksteps = (K + GBK - 1) / GBK;
    for (int ks = 0; ks < ksteps; ks++) {
        int k0 = ks * GBK;
        if (vecA) {
            int m = m0 + arow2;
            float v[16];
            if (m < M && (k0 + acol2 + 16) <= K) {
                const float* Ap = A + (size_t)m * K + k0 + acol2;
                float4 f0 = *(const float4*)(Ap);
                float4 f1 = *(const float4*)(Ap + 4);
                float4 f2 = *(const float4*)(Ap + 8);
                float4 f3 = *(const float4*)(Ap + 12);
                v[0]=f0.x; v[1]=f0.y; v[2]=f0.z; v[3]=f0.w;
                v[4]=f1.x; v[5]=f1.y; v[6]=f1.z; v[7]=f1.w;
                v[8]=f2.x; v[9]=f2.y; v[10]=f2.z; v[11]=f2.w;
                v[12]=f3.x; v[13]=f3.y; v[14]=f3.z; v[15]=f3.w;
            } else {
                const float* Ap = A + (size_t)m * K + k0 + acol2;
#pragma unroll
                for (int i = 0; i < 16; i++)
                    v[i] = (m < M && (k0 + acol2 + i) < K) ? Ap[i] : 0.f;
            }
#pragma unroll
            for (int i = 0; i < 16; i++) {
                unsigned short hi = f2bf(v[i]);
                unsigned short lo = f2bf(v[i] - bf2f(hi));
                AsH[arow2 * ASTR + acol2 + i] = (short)hi;
                AsL[arow2 * ASTR + acol2 + i] = (short)lo;
            }
        } else {
#pragma unroll
            for (int p = 0; p < 4; p++) {
                int row = p * 32 + arow;
                int m = m0 + row;
#pragma unroll
                for (int i = 0; i < 4; i++) {
                    int k = alk + 8 * i;
                    float v = 0.f;
                    if (m < M && (k0 + k) < K) v = A[(size_t)m * K + k0 + k];
                    unsigned short hi = f2bf(v);
                    unsigned short lo = f2bf(v - bf2f(hi));
                    AsH[row * ASTR + k] = (short)hi;
                    AsL[row * ASTR + k] = (short)lo;
                }
            }
        }
#pragma unroll
        for (int p = 0; p < 2; p++) {
            int row = p * 64 + brow;
            size_t gidx = (size_t)(n0 + row) * Kpad + k0 + bcol;
            *((uint4*)(BsH + row * ASTR + bcol)) = *((const uint4*)(Bt_hi + gidx));
            *((uint4*)(BsL + row * ASTR + bcol)) = *((const uint4*)(Bt_lo + gidx));
        }
        __syncthreads();
        short8 ah[4], al[4], bh[4], bl[4];
#pragma unroll
        for (int i = 0; i < 4; i++) {
            ah[i] = *((const short8*)(AsH + (wm + i * 16 + r) * ASTR + q * 8));
            al[i] = *((const short8*)(AsL + (wm + i * 16 + r) * ASTR + q * 8));
        }
#pragma unroll
        for (int j = 0; j < 4; j++) {
            bh[j] = *((const short8*)(BsH + (wn + j * 16 + r) * ASTR + q * 8));
            bl[j] = *((const short8*)(BsL + (wn + j * 16 + r) * ASTR + q * 8));
        }
#pragma unroll
        for (int i = 0; i < 4; i++)
#pragma unroll
            for (int j = 0; j < 4; j++) {
                acc[i][j] = __builtin_amdgcn_mfma_f32_16x16x32_bf16(ah[i], bh[j], acc[i][j], 0, 0, 0);
                acc[i][j] = __builtin_amdgcn_mfma_f32_16x16x32_bf16(ah[i], bl[j], acc[i][j], 0, 0, 0);
                acc[i][j] = __builtin_amdgcn_mfma_f32_16x16x32_bf16(al[i], bh[j], acc[i][j], 0, 0, 0);
            }
        __syncthreads();
    }
#pragma unroll
    for (int i = 0; i < 4; i++) {
#pragma unroll
        for (int j = 0; j < 4; j++) {
#pragma unroll
            for (int reg = 0; reg < 4; reg++) {
                int mrow = m0 + wm + i * 16 + q * 4 + reg;
                int ncol = n0 + wn + j * 16 + r;
                if (mrow < M && ncol < Nc) {
                    float val = acc[i][j][reg];
                    Cm[(size_t)mrow * Nc + ncol] = val;
                    if (Ch16) Ch16[(size_t)mrow * Nc + ncol] = f2bf(val);
                }
            }
        }
    }
}

// wave-per-node attention dots
__global__ void al_wave_kernel(const float* __restrict__ h, const float* __restrict__ a_s,
                               const float* __restrict__ a_d, float* __restrict__ al_src,
                               float* __restrict__ al_dst, int H, int C, int HC) {
    int w = (blockIdx.x * blockDim.x + threadIdx.x) >> 6;
    int lane = threadIdx.x & 63;
    if (w >= NN) return;
    const float* row = h + (size_t)w * HC;
    float s1[5] = {0.f, 0.f, 0.f, 0.f, 0.f};
    float s2[5] = {0.f, 0.f, 0.f, 0.f, 0.f};
#pragma unroll
    for (int hd = 0; hd < 5; hd++) {
        if (hd >= H) break;
        int base = hd * C;
        for (int c = lane; c < C; c += 64) {
            float v = row[base + c];
            s1[hd] += v * a_s[base + c];
            s2[hd] += v * a_d[base + c];
        }
    }
#pragma unroll
    for (int hd = 0; hd < 5; hd++) {
        if (hd >= H) break;
#pragma unroll
        for (int off = 32; off > 0; off >>= 1) {
            s1[hd] += __shfl_xor(s1[hd], off, 64);
            s2[hd] += __shfl_xor(s2[hd], off, 64);
        }
    }
    if (lane == 0) {
#pragma unroll
        for (int hd = 0; hd < 5; hd++) {
            if (hd >= H) break;
            al_src[(size_t)w * H + hd] = s1[hd];
            al_dst[(size_t)w * H + hd] = s2[hd];
        }
    }
}

// fused logit + ONLINE segment softmax (2 passes over own slice):
//  pass1: gather, write raw logit, track online (m, l)
//  pass2: alpha = exp(lg - m) * inv
__global__ void attn_kernel(const float* __restrict__ al_src,
                            const float* __restrict__ al_dst,
                            const int* __restrict__ csr_src,
                            const float* __restrict__ csr_ea,
                            const float* __restrict__ we_dot,
                            const int* __restrict__ off,
                            float* __restrict__ alpha_t, int H, int NH) {
    int t = blockIdx.x * blockDim.x + threadIdx.x;
    if (t >= NH) return;
    int n = t / H, hd = t - n * H;
    int s = off[n], e = off[n + 1];
    float ad = al_dst[(size_t)n * H + hd];
    float wd = we_dot[hd];
    float* arow = alpha_t + (size_t)hd * ET;
    float m = -INFINITY, l = 0.f;
    int p = s;
    for (; p + 3 < e; p += 4) {
        int s0 = csr_src[p], s1 = csr_src[p + 1], s2 = csr_src[p + 2], s3 = csr_src[p + 3];
        float w0 = csr_ea[p], w1 = csr_ea[p + 1], w2 = csr_ea[p + 2], w3 = csr_ea[p + 3];
        float l0 = al_src[(size_t)s0 * H + hd] + ad + w0 * wd;
        float l1 = al_src[(size_t)s1 * H + hd] + ad + w1 * wd;
        float l2 = al_src[(size_t)s2 * H + hd] + ad + w2 * wd;
        float l3 = al_src[(size_t)s3 * H + hd] + ad + w3 * wd;
        l0 = (l0 >= 0.f) ? l0 : NEG_SLOPE * l0;
        l1 = (l1 >= 0.f) ? l1 : NEG_SLOPE * l1;
        l2 = (l2 >= 0.f) ? l2 : NEG_SLOPE * l2;
        l3 = (l3 >= 0.f) ? l3 : NEG_SLOPE * l3;
        arow[p] = l0; arow[p + 1] = l1; arow[p + 2] = l2; arow[p + 3] = l3;
        float mq = fmaxf(fmaxf(l0, l1), fmaxf(l2, l3));
        float nm = fmaxf(m, mq);
        l = l * __expf(m - nm)
          + __expf(l0 - nm) + __expf(l1 - nm) + __expf(l2 - nm) + __expf(l3 - nm);
        m = nm;
    }
    for (; p < e; p++) {
        float lg = al_src[(size_t)csr_src[p] * H + hd] + ad + csr_ea[p] * wd;
        lg = (lg >= 0.f) ? lg : NEG_SLOPE * lg;
        arow[p] = lg;
        float nm = fmaxf(m, lg);
        l = l * __expf(m - nm) + __expf(lg - nm);
        m = nm;
    }
    float inv = 1.f / fmaxf(l, 1e-16f);
    for (p = s; p < e; p++) arow[p] = __expf(arow[p] - m) * inv;
}

// bf16 gather aggregate, 4 cols/thread (4|C); optional fused relu
__global__ void aggregate_v4h_kernel(const unsigned short* __restrict__ h16,
                                     const float* __restrict__ alpha_t,
                                     const int* __restrict__ off,
                                     const int* __restrict__ csr_src,
                                     const float* __restrict__ bias,
                                     float* __restrict__ out,
                                     int C, int HC, int HC4, int total4, int relu) {
    int t = blockIdx.x * blockDim.x + threadIdx.x;
    if (t >= total4) return;
    int n = t / HC4, j4 = t - n * HC4;
    int j = j4 * 4;
    int hd = j / C;
    const float* arow = alpha_t + (size_t)hd * ET;
    int s = off[n], e = off[n + 1];
    float4 acc = make_float4(0.f, 0.f, 0.f, 0.f);
    int p = s;
    for (; p + 3 < e; p += 4) {
        int idx[4]; float a[4];
#pragma unroll
        for (int u = 0; u < 4; u++) { idx[u] = csr_src[p + u]; a[u] = arow[p + u]; }
#pragma unroll
        for (int u = 0; u < 4; u++) {
            ushort4 uv = *(const ushort4*)(h16 + (size_t)idx[u] * HC + j);
            acc.x += a[u] * bf2f(uv.x);
            acc.y += a[u] * bf2f(uv.y);
            acc.z += a[u] * bf2f(uv.z);
            acc.w += a[u] * bf2f(uv.w);
        }
    }
    for (; p < e; p++) {
        int s0 = csr_src[p];
        float a0 = arow[p];
        ushort4 uv = *(const ushort4*)(h16 + (size_t)s0 * HC + j);
        acc.x += a0 * bf2f(uv.x);
        acc.y += a0 * bf2f(uv.y);
        acc.z += a0 * bf2f(uv.z);
        acc.w += a0 * bf2f(uv.w);
    }
    float4 bi = *(const float4*)(bias + j);
    float4 rr = make_float4(acc.x + bi.x, acc.y + bi.y, acc.z + bi.z, acc.w + bi.w);
    if (relu) {
        rr.x = fmaxf(rr.x, 0.f); rr.y = fmaxf(rr.y, 0.f);
        rr.z = fmaxf(rr.z, 0.f); rr.w = fmaxf(rr.w, 0.f);
    }
    *(float4*)(out + (size_t)n * HC + j) = rr;
}

// bf16 gather aggregate, 2 cols/thread (2|C) — C=50
__global__ void aggregate_v2h_kernel(const unsigned short* __restrict__ h16,
                                     const float* __restrict__ alpha_t,
                                     const int* __restrict__ off,
                                     const int* __restrict__ csr_src,
                                     const float* __restrict__ bias,
                                     float* __restrict__ out,
                                     int C, int HC, int HC2, int total2) {
    int t = blockIdx.x * blockDim.x + threadIdx.x;
    if (t >= total2) return;
    int n = t / HC2, j2 = t - n * HC2;
    int j = j2 * 2;
    int hd = j / C;
    const float* arow = alpha_t + (size_t)hd * ET;
    int s = off[n], e = off[n + 1];
    float2 acc = make_float2(0.f, 0.f);
    int p = s;
    for (; p + 3 < e; p += 4) {
        int idx[4]; float a[4];
#pragma unroll
        for (int u = 0; u < 4; u++) { idx[u] = csr_src[p + u]; a[u] = arow[p + u]; }
#pragma unroll
        for (int u = 0; u < 4; u++) {
            ushort2 uv = *(const ushort2*)(h16 + (size_t)idx[u] * HC + j);
            acc.x += a[u] * bf2f(uv.x);
            acc.y += a[u] * bf2f(uv.y);
        }
    }
    for (; p < e; p++) {
        int s0 = csr_src[p];
        float a0 = arow[p];
        ushort2 uv = *(const ushort2*)(h16 + (size_t)s0 * HC + j);
        acc.x += a0 * bf2f(uv.x);
        acc.y += a0 * bf2f(uv.y);
    }
    float2 bi = *(const float2*)(bias + j);
    *(float2*)(out + (size_t)n * HC + j) = make_float2(acc.x + bi.x, acc.y + bi.y);
}

// f32 float4 aggregate (small layers); optional fused relu
__global__ void aggregate_v4_kernel(const float* __restrict__ hfeat,
                                    const float* __restrict__ alpha_t,
                                    const int* __restrict__ off,
                                    const int* __restrict__ csr_src,
                                    const float* __restrict__ bias,
                                    float* __restrict__ out,
                                    int C, int HC, int HC4, int total4, int relu) {
    int t = blockIdx.x * blockDim.x + threadIdx.x;
    if (t >= total4) return;
    int n = t / HC4, j4 = t - n * HC4;
    int j = j4 * 4;
    int hd = j / C;
    const float* arow = alpha_t + (size_t)hd * ET;
    int s = off[n], e = off[n + 1];
    float4 acc = make_float4(0.f, 0.f, 0.f, 0.f);
    int p = s;
    for (; p + 3 < e; p += 4) {
        int idx[4]; float a[4];
#pragma unroll
        for (int u = 0; u < 4; u++) { idx[u] = csr_src[p + u]; a[u] = arow[p + u]; }
#pragma unroll
        for (int u = 0; u < 4; u++) {
            float4 f = *(const float4*)(hfeat + (size_t)idx[u] * HC + j);
            acc.x += a[u] * f.x; acc.y += a[u] * f.y; acc.z += a[u] * f.z; acc.w += a[u] * f.w;
        }
    }
    for (; p < e; p++) {
        int s0 = csr_src[p];
        float a0 = arow[p];
        float4 f0 = *(const float4*)(hfeat + (size_t)s0 * HC + j);
        acc.x += a0 * f0.x; acc.y += a0 * f0.y; acc.z += a0 * f0.z; acc.w += a0 * f0.w;
    }
    float4 bi = *(const float4*)(bias + j);
    float4 rr = make_float4(acc.x + bi.x, acc.y + bi.y, acc.z + bi.z, acc.w + bi.w);
    if (relu) {
        rr.x = fmaxf(rr.x, 0.f); rr.y = fmaxf(rr.y, 0.f);
        rr.z = fmaxf(rr.z, 0.f); rr.w = fmaxf(rr.w, 0.f);
    }
    *(float4*)(out + (size_t)n * HC + j) = rr;
}

// scalar fallback (layer 5, HC==1)
__global__ void aggregate_kernel(const float* __restrict__ hfeat,
                                 const float* __restrict__ alpha_t,
                                 const int* __restrict__ off, const int* __restrict__ csr_src,
                                 const float* __restrict__ bias, float* __restrict__ out,
                                 int total) {
    int t = blockIdx.x * blockDim.x + threadIdx.x;
    if (t >= total) return;
    int n = t;
    int s = off[n], e = off[n + 1];
    float acc = 0.f;
    int p = s;
    for (; p + 3 < e; p += 4) {
        acc += alpha_t[p] * hfeat[csr_src[p]]
             + alpha_t[p + 1] * hfeat[csr_src[p + 1]]
             + alpha_t[p + 2] * hfeat[csr_src[p + 2]]
             + alpha_t[p + 3] * hfeat[csr_src[p + 3]];
    }
    for (; p < e; p++) acc += alpha_t[p] * hfeat[csr_src[p]];
    out[n] = acc + bias[0];
}

// ---------------- BN / activations ----------------

__global__ void bn_stats_kernel(const float* __restrict__ x, float* __restrict__ colsum,
                                float* __restrict__ colsumsq, int D) {
    int rows_per_block = (NN + gridDim.x - 1) / gridDim.x;
    int r0 = blockIdx.x * rows_per_block;
    int r1 = min(NN, r0 + rows_per_block);
    int c0 = threadIdx.x;
    int c1 = threadIdx.x + 256;
    float s0 = 0.f, q0 = 0.f, s1 = 0.f, q1 = 0.f;
    for (int r = r0; r < r1; r++) {
        const float* row = x + (size_t)r * D;
        if (c0 < D) { float v = row[c0]; s0 += v; q0 += v * v; }
        if (c1 < D) { float v = row[c1]; s1 += v; q1 += v * v; }
    }
    if (c0 < D) { atomicAdd(&colsum[c0], s0); atomicAdd(&colsumsq[c0], q0); }
    if (c1 < D) { atomicAdd(&colsum[c1], s1); atomicAdd(&colsumsq[c1], q1); }
}

// fused BN+ReLU, float4 path (4|D)
__global__ void bn_relu_v4_kernel(float* __restrict__ x,
                                  const float* __restrict__ colsum,
                                  const float* __restrict__ colsumsq,
                                  const float* __restrict__ g, const float* __restrict__ beta,
                                  int total4, int D) {
    __shared__ float sscale[512];
    __shared__ float sshift[512];
    for (int c = threadIdx.x; c < D; c += blockDim.x) {
        float mu = colsum[c] * (1.0f / (float)NN);
        float var = colsumsq[c] * (1.0f / (float)NN) - mu * mu;
        float sc = g[c] * rsqrtf(var + BN_EPS);
        sscale[c] = sc;
        sshift[c] = beta[c] - mu * sc;
    }
    __syncthreads();
    int D4 = D >> 2;
    for (int i = blockIdx.x * blockDim.x + threadIdx.x; i < total4; i += gridDim.x * blockDim.x) {
        int c4 = (i % D4) * 4;
        float4 v = *(float4*)(x + (size_t)i * 4);
        v.x = fmaxf(v.x * sscale[c4]     + sshift[c4],     0.f);
        v.y = fmaxf(v.y * sscale[c4 + 1] + sshift[c4 + 1], 0.f);
        v.z = fmaxf(v.z * sscale[c4 + 2] + sshift[c4 + 2], 0.f);
        v.w = fmaxf(v.w * sscale[c4 + 3] + sshift[c4 + 3], 0.f);
        *(float4*)(x + (size_t)i * 4) = v;
    }
}

// fused BN+ReLU, float2 path (2|D; D=250)
__global__ void bn_relu_v2_kernel(float* __restrict__ x,
                                  const float* __restrict__ colsum,
                                  const float* __restrict__ colsumsq,
                                  const float* __restrict__ g, const float* __restrict__ beta,
                                  int total2, int D) {
    __shared__ float sscale[512];
    __shared__ float sshift[512];
    for (int c = threadIdx.x; c < D; c += blockDim.x) {
        float mu = colsum[c] * (1.0f / (float)NN);
        float var = colsumsq[c] * (1.0f / (float)NN) - mu * mu;
        float sc = g[c] * rsqrtf(var + BN_EPS);
        sscale[c] = sc;
        sshift[c] = beta[c] - mu * sc;
    }
    __syncthreads();
    int D2 = D >> 1;
    for (int i = blockIdx.x * blockDim.x + threadIdx.x; i < total2; i += gridDim.x * blockDim.x) {
        int c2 = (i % D2) * 2;
        float2 v = *(float2*)(x + (size_t)i * 2);
        v.x = fmaxf(v.x * sscale[c2]     + sshift[c2],     0.f);
        v.y = fmaxf(v.y * sscale[c2 + 1] + sshift[c2 + 1], 0.f);
        *(float2*)(x + (size_t)i * 2) = v;
    }
}

// ---------------- host orchestration ----------------

static inline size_t align_up(size_t v, size_t a) { return (v + a - 1) / a * a; }

extern "C" void kernel_launch(void* const* d_in, const int* in_sizes, int n_in,
                              void* d_out, int out_size, void* d_ws, size_t ws_size,
                              hipStream_t stream) {
    const float* x_in = (const float*)d_in[0];
    const int* ei     = (const int*)d_in[1];
    const float* ew   = (const float*)d_in[2];

    char* pws = (char*)d_ws;
    size_t off_b = 0;
    auto alloc = [&](size_t bytes) -> void* {
        void* rp = pws + off_b;
        off_b = align_up(off_b + bytes, 256);
        return rp;
    };
    float* B0      = (float*)alloc((size_t)NN * 500 * 4);
    float* B1      = (float*)alloc((size_t)NN * 500 * 4);
    unsigned short* H16 = (unsigned short*)alloc((size_t)NN * 500 * 2);
    float* alpha_t = (float*)alloc((size_t)ET * 5 * 4);
    unsigned short* Wt_hi = (unsigned short*)alloc((size_t)512 * 512 * 2);
    unsigned short* Wt_lo = (unsigned short*)alloc((size_t)512 * 512 * 2);
    float* al_src  = (float*)alloc((size_t)NN * 5 * 4);
    float* al_dst  = (float*)alloc((size_t)NN * 5 * 4);
    float* ea      = (float*)alloc((size_t)ET * 4);
    float* csr_ea  = (float*)alloc((size_t)ET * 4);
    int* srcv      = (int*)alloc((size_t)ET * 4);
    int* dstv      = (int*)alloc((size_t)ET * 4);
    int* csr_src   = (int*)alloc((size_t)ET * 4);
    int* offarr    = (int*)alloc((size_t)(NN + 1) * 4);
    int* wptr      = (int*)alloc((size_t)NN * 4);
    int* cnt       = (int*)alloc((size_t)NN * 4);
    float* esum    = (float*)alloc(4);
    float* we_dot  = (float*)alloc(40 * 4);
    float* colsum  = (float*)alloc(512 * 4);
    float* colsumsq= (float*)alloc(512 * 4);
    (void)ws_size; (void)n_in; (void)in_sizes; (void)out_size;

    int Kp[5], Np[5];
    size_t wtoff[5];
    size_t acc_off = 0;
    for (int l = 0; l < 5; l++) {
        int K = g_cfg[l].cin, HC = g_cfg[l].C * g_cfg[l].H;
        Kp[l] = (K + 31) / 32 * 32;
        Np[l] = (HC + 127) / 128 * 128;
        wtoff[l] = acc_off;
        acc_off += (size_t)Kp[l] * Np[l];
    }

    PrepArgs pa;
    for (int l = 0; l < 5; l++) {
        pa.W[l]  = (const float*)d_in[3 + l * 6 + 0];
        pa.We[l] = (const float*)d_in[3 + l * 6 + 3];
        pa.ae[l] = (const float*)d_in[3 + l * 6 + 4];
        pa.bh[l] = Wt_hi + wtoff[l];
        pa.bl[l] = Wt_lo + wtoff[l];
        pa.K[l] = g_cfg[l].cin;
        pa.N[l] = g_cfg[l].C * g_cfg[l].H;
        pa.Kp[l] = Kp[l];
        pa.Np[l] = Np[l];
        pa.C[l] = g_cfg[l].C;
        pa.H[l] = g_cfg[l].H;
    }
    pa.wedot = we_dot;

    // graph & CSR build
    hipMemsetAsync(esum, 0, 4, stream);
    hipMemsetAsync(cnt, 0, (size_t)NN * 4, stream);
    ewsum_kernel<<<256, 256, 0, stream>>>(ew, esum, EE);
    int ebl = (ET + 255) / 256;
    build_edges_kernel<<<ebl, 256, 0, stream>>>(ei, ew, esum, srcv, dstv, ea, cnt);
    scan_kernel<<<1, 1024, 0, stream>>>(cnt, offarr, wptr);
    fill_kernel<<<ebl, 256, 0, stream>>>(dstv, srcv, ea, wptr, csr_src, csr_ea);

    // all-layer weight prep
    wedot_all_kernel<<<1, 64, 0, stream>>>(pa);
    transpose_all_kernel<<<dim3(16, 16, 5), dim3(32, 8), 0, stream>>>(pa);

    int bn_idx = 0;
    for (int l = 0; l < 5; l++) {
        const LayerCfg& cf = g_cfg[l];
        int H = cf.H, C = cf.C, K = cf.cin;
        int HC = H * C;
        const float* a_s = (const float*)d_in[3 + l * 6 + 1];
        const float* a_d = (const float*)d_in[3 + l * 6 + 2];
        const float* b   = (const float*)d_in[3 + l * 6 + 5];

        const float* X = (l == 0) ? x_in : B1;
        float* hbuf = B0;
        float* outbuf = (l == 4) ? (float*)d_out : B1;
        bool big = (l < 3);   // layers 1-3: bf16 gather path

        dim3 ggrid(Np[l] / GBNT, (NN + GBM - 1) / GBM);
        gemm_split_kernel<<<ggrid, 256, 0, stream>>>(X, Wt_hi + wtoff[l], Wt_lo + wtoff[l],
                                                     hbuf, big ? H16 : nullptr, NN, K, HC, Kp[l]);

        int NH = NN * H;
        int alblocks = (NN * 64 + 255) / 256;
        al_wave_kernel<<<alblocks, 256, 0, stream>>>(hbuf, a_s, a_d, al_src, al_dst, H, C, HC);
        attn_kernel<<<(NH + 255) / 256, 256, 0, stream>>>(al_src, al_dst, csr_src, csr_ea,
                                                          we_dot + l * 8, offarr, alpha_t, H, NH);

        int do_relu = (l == 3) ? 1 : 0;
        if (big && (C & 3) == 0) {
            int HC4 = HC / 4;
            int total4 = NN * HC4;
            aggregate_v4h_kernel<<<(total4 + 255) / 256, 256, 0, stream>>>(
                H16, alpha_t, offarr, csr_src, b, outbuf, C, HC, HC4, total4, 0);
        } else if (big) {
            int HC2 = HC / 2;
            int total2 = NN * HC2;
            aggregate_v2h_kernel<<<(total2 + 255) / 256, 256, 0, stream>>>(
                H16, alpha_t, offarr, csr_src, b, outbuf, C, HC, HC2, total2);
        } else if ((C & 3) == 0) {
            int HC4 = HC / 4;
            int total4 = NN * HC4;
            aggregate_v4_kernel<<<(total4 + 255) / 256, 256, 0, stream>>>(
                hbuf, alpha_t, offarr, csr_src, b, outbuf, C, HC, HC4, total4, do_relu);
        } else {
            aggregate_kernel<<<(NN + 255) / 256, 256, 0, stream>>>(
                hbuf, alpha_t, offarr, csr_src, b, outbuf, NN);
        }

        int total = NN * HC;
        if (l < 3) {
            int D = HC;
            const float* g    = (const float*)d_in[33 + bn_idx * 2 + 0];
            const float* beta = (const float*)d_in[33 + bn_idx * 2 + 1];
            hipMemsetAsync(colsum, 0, 2 * 512 * 4, stream);
            bn_stats_kernel<<<256, 256, 0, stream>>>(outbuf, colsum, colsumsq, D);
            if ((D & 3) == 0) {
                bn_relu_v4_kernel<<<2048, 256, 0, stream>>>(outbuf, colsum, colsumsq, g, beta, total / 4, D);
            } else {
                bn_relu_v2_kernel<<<2048, 256, 0, stream>>>(outbuf, colsum, colsumsq, g, beta, total / 2, D);
            }
            bn_idx++;
        }
    }
}

// Round 11
// 938.634 us; speedup vs baseline: 2.2981x; 1.0721x over previous
//
#include <hip/hip_runtime.h>
#include <hip/hip_bf16.h>
#include <math.h>

// ---------------- problem constants ----------------
#define NN 30000
#define EE 480000
#define ET (EE + NN)   // edges + self loops = 510000
#define NEG_SLOPE 0.2f
#define BN_EPS 1e-5f

struct LayerCfg { int cin, C, H; };
static const LayerCfg g_cfg[5] = {
    {128, 100, 5}, {500, 50, 5}, {250, 32, 4}, {128, 8, 4}, {32, 1, 1}
};

typedef short short8 __attribute__((ext_vector_type(8)));
typedef float f32x4 __attribute__((ext_vector_type(4)));

__device__ __forceinline__ unsigned short f2bf(float f) {
    unsigned int u = __builtin_bit_cast(unsigned int, f);
    u = (u + 0x7FFFu + ((u >> 16) & 1u)) >> 16;
    return (unsigned short)u;
}
__device__ __forceinline__ float bf2f(unsigned short h) {
    unsigned int u = ((unsigned int)h) << 16;
    return __builtin_bit_cast(float, u);
}

// ---------------- graph / CSR kernels ----------------

__global__ void ewsum_kernel(const float* __restrict__ ew, float* __restrict__ out, int E) {
    __shared__ float sdata[256];
    int tid = threadIdx.x;
    float s = 0.f;
    for (int i = blockIdx.x * blockDim.x + tid; i < E; i += gridDim.x * blockDim.x)
        s += ew[i];
    sdata[tid] = s;
    __syncthreads();
    for (int off = 128; off > 0; off >>= 1) {
        if (tid < off) sdata[tid] += sdata[tid + off];
        __syncthreads();
    }
    if (tid == 0) atomicAdd(out, sdata[0]);
}

__global__ void build_edges_kernel(const int* __restrict__ ei, const float* __restrict__ ew,
                                   const float* __restrict__ sum,
                                   int* __restrict__ srcv, int* __restrict__ dstv,
                                   float* __restrict__ ea, int* __restrict__ cnt) {
    int e = blockIdx.x * blockDim.x + threadIdx.x;
    if (e >= ET) return;
    int d;
    if (e < EE) {
        srcv[e] = ei[e];
        d = ei[EE + e];
        dstv[e] = d;
        ea[e]   = ew[e];
    } else {
        int n = e - EE;
        srcv[e] = n;
        d = n;
        dstv[e] = n;
        ea[e]   = sum[0] * (1.0f / (float)EE);
    }
    atomicAdd(&cnt[d], 1);
}

__global__ void scan_kernel(const int* __restrict__ cnt, int* __restrict__ off,
                            int* __restrict__ wptr) {
    __shared__ int lsum[1024];
    __shared__ int loff[1024];
    const int T = 1024;
    int t = threadIdx.x;
    int chunk = (NN + T - 1) / T;
    int base = t * chunk;
    int end = min(NN, base + chunk);
    int s = 0;
    for (int i = base; i < end; i++) s += cnt[i];
    lsum[t] = s;
    __syncthreads();
    if (t == 0) {
        int run = 0;
        for (int i = 0; i < T; i++) { loff[i] = run; run += lsum[i]; }
    }
    __syncthreads();
    int run = loff[t];
    for (int i = base; i < end; i++) {
        off[i] = run;
        wptr[i] = run;
        run += cnt[i];
    }
    if (t == 0) off[NN] = ET;
}

__global__ void fill_kernel(const int* __restrict__ dstv, const int* __restrict__ srcv,
                            const float* __restrict__ ea,
                            int* __restrict__ wptr, int* __restrict__ csr_src,
                            float* __restrict__ csr_ea) {
    int e = blockIdx.x * blockDim.x + threadIdx.x;
    if (e >= ET) return;
    int p = atomicAdd(&wptr[dstv[e]], 1);
    csr_src[p] = srcv[e];
    csr_ea[p]  = ea[e];
}

// ---------------- all-layer weight prep ----------------

struct PrepArgs {
    const float* W[5];
    const float* We[5];
    const float* ae[5];
    unsigned short* bh[5];
    unsigned short* bl[5];
    float* wedot;            // out: [5][8]
    int K[5], N[5], Kp[5], Np[5], C[5], H[5];
};

__global__ void wedot_all_kernel(PrepArgs a) {
    int tid = threadIdx.x;   // 64
    int l = tid >> 3, hd = tid & 7;
    if (l < 5 && hd < a.H[l]) {
        int C = a.C[l];
        const float* We = a.We[l] + hd * C;
        const float* ae = a.ae[l] + hd * C;
        float s = 0.f;
        for (int c = 0; c < C; c++) s += We[c] * ae[c];
        a.wedot[l * 8 + hd] = s;
    }
}

__global__ void transpose_all_kernel(PrepArgs a) {
    int l = blockIdx.z;
    int Kp = a.Kp[l], Np = a.Np[l], K = a.K[l], N = a.N[l];
    int kb = blockIdx.x * 32, nb = blockIdx.y * 32;
    if (kb >= Kp || nb >= Np) return;
    const float* B = a.W[l];
    unsigned short* Bth = a.bh[l];
    unsigned short* Btl = a.bl[l];
    __shared__ float tile[32][33];
    int tx = threadIdx.x, ty = threadIdx.y;   // 32 x 8
#pragma unroll
    for (int i = 0; i < 4; i++) {
        int k = kb + ty + i * 8, n = nb + tx;
        tile[ty + i * 8][tx] = (k < K && n < N) ? B[(size_t)k * N + n] : 0.f;
    }
    __syncthreads();
#pragma unroll
    for (int i = 0; i < 4; i++) {
        int n = nb + ty + i * 8, k = kb + tx;
        if (n < Np && k < Kp) {
            float v = tile[tx][ty + i * 8];
            unsigned short hi = f2bf(v);
            unsigned short lo = f2bf(v - bf2f(hi));
            size_t idx = (size_t)n * Kp + k;
            Bth[idx] = hi;
            Btl[idx] = lo;
        }
    }
}

// zero the pad columns of a pitched activation buffer
__global__ void padzero_kernel(float* __restrict__ x, int pitch, int D, int padc) {
    int t = blockIdx.x * blockDim.x + threadIdx.x;
    int total = NN * padc;
    if (t >= total) return;
    int r = t / padc, c = t - r * padc;
    x[(size_t)r * pitch + D + c] = 0.f;
}

// ---------------- split-bf16 MFMA GEMM ----------------
// A is pitched (Apitch, multiple of 32) and zero-padded to Kp columns.
// K here is ALWAYS the padded Kp -> unconditional vector staging, no k-bounds.
#define GBM 128
#define GBNT 128
#define GBK 32
#define ASTR 40
__global__ __launch_bounds__(256) void gemm_split_kernel(const float* __restrict__ A,
                                                         const unsigned short* __restrict__ Bt_hi,
                                                         const unsigned short* __restrict__ Bt_lo,
                                                         float* __restrict__ Cm,
                                                         unsigned short* __restrict__ Ch16,
                                                         int M, int Kp, int Nc, int Apitch) {
    __shared__ short AsH[GBM * ASTR];
    __shared__ short AsL[GBM * ASTR];
    __shared__ short BsH[GBNT * ASTR];
    __shared__ short BsL[GBNT * ASTR];
    int tid = threadIdx.x;
    int wave = tid >> 6, lane = tid & 63;
    int q = lane >> 4, r = lane & 15;
    int m0 = blockIdx.y * GBM, n0 = blockIdx.x * GBNT;
    int wm = (wave & 1) * 64, wn = (wave >> 1) * 64;
    f32x4 acc[4][4];
#pragma unroll
    for (int i = 0; i < 4; i++)
#pragma unroll
        for (int j = 0; j < 4; j++) acc[i][j] = (f32x4)(0.f);

    int arow2 = tid >> 1;          // 0..127
    int acol2 = (tid & 1) * 16;    // 0 or 16
    int brow = tid >> 2;
    int bcol = (tid & 3) * 8;

    int ksteps = Kp / GBK;
    for (int ks = 0; ks < ksteps; ks++) {
        int k0 = ks * GBK;
        {
            int m = m0 + arow2;
            float v[16];
            if (m < M) {
                const float* Ap = A + (size_t)m * Apitch + k0 + acol2;
                float4 f0 = *(const float4*)(Ap);
                float4 f1 = *(const float4*)(Ap + 4);
                float4 f2 = *(const float4*)(Ap + 8);
                float4 f3 = *(const float4*)(Ap + 12);
                v[0]=f0.x; v[1]=f0.y; v[2]=f0.z; v[3]=f0.w;
                v[4]=f1.x; v[5]=f1.y; v[6]=f1.z; v[7]=f1.w;
                v[8]=f2.x; v[9]=f2.y; v[10]=f2.z; v[11]=f2.w;
                v[12]=f3.x; v[13]=f3.y; v[14]=f3.z; v[15]=f3.w;
            } else {
#pragma unroll
                for (int i = 0; i < 16; i++) v[i] = 0.f;
            }
#pragma unroll
            for (int i = 0; i < 16; i++) {
                unsigned short hi = f2bf(v[i]);
                unsigned short lo = f2bf(v[i] - bf2f(hi));
                AsH[arow2 * ASTR + acol2 + i] = (short)hi;
                AsL[arow2 * ASTR + acol2 + i] = (short)lo;
            }
        }
#pragma unroll
        for (int p = 0; p < 2; p++) {
            int row = p * 64 + brow;
            size_t gidx = (size_t)(n0 + row) * Kp + k0 + bcol;
            *((uint4*)(BsH + row * ASTR + bcol)) = *((const uint4*)(Bt_hi + gidx));
            *((uint4*)(BsL + row * ASTR + bcol)) = *((const uint4*)(Bt_lo + gidx));
        }
        __syncthreads();
        short8 ah[4], al[4], bh[4], bl[4];
#pragma unroll
        for (int i = 0; i < 4; i++) {
            ah[i] = *((const short8*)(AsH + (wm + i * 16 + r) * ASTR + q * 8));
            al[i] = *((const short8*)(AsL + (wm + i * 16 + r) * ASTR + q * 8));
        }
#pragma unroll
        for (int j = 0; j < 4; j++) {
            bh[j] = *((const short8*)(BsH + (wn + j * 16 + r) * ASTR + q * 8));
            bl[j] = *((const short8*)(BsL + (wn + j * 16 + r) * ASTR + q * 8));
        }
#pragma unroll
        for (int i = 0; i < 4; i++)
#pragma unroll
            for (int j = 0; j < 4; j++) {
                acc[i][j] = __builtin_amdgcn_mfma_f32_16x16x32_bf16(ah[i], bh[j], acc[i][j], 0, 0, 0);
                acc[i][j] = __builtin_amdgcn_mfma_f32_16x16x32_bf16(ah[i], bl[j], acc[i][j], 0, 0, 0);
                acc[i][j] = __builtin_amdgcn_mfma_f32_16x16x32_bf16(al[i], bh[j], acc[i][j], 0, 0, 0);
            }
        __syncthreads();
    }
#pragma unroll
    for (int i = 0; i < 4; i++) {
#pragma unroll
        for (int j = 0; j < 4; j++) {
#pragma unroll
            for (int reg = 0; reg < 4; reg++) {
                int mrow = m0 + wm + i * 16 + q * 4 + reg;
                int ncol = n0 + wn + j * 16 + r;
                if (mrow < M && ncol < Nc) {
                    float val = acc[i][j][reg];
                    Cm[(size_t)mrow * Nc + ncol] = val;
                    if (Ch16) Ch16[(size_t)mrow * Nc + ncol] = f2bf(val);
                }
            }
        }
    }
}

// layer-5 fused GEMV: h = X @ w (K=32, Nc=1) + al_src/al_dst scalars
__global__ void gemv_l5_kernel(const float* __restrict__ X, const float* __restrict__ W,
                               const float* __restrict__ a_s, const float* __restrict__ a_d,
                               float* __restrict__ h, float* __restrict__ al_src,
                               float* __restrict__ al_dst) {
    __shared__ float w[32];
    if (threadIdx.x < 32) w[threadIdx.x] = W[threadIdx.x];
    __syncthreads();
    int n = blockIdx.x * blockDim.x + threadIdx.x;
    if (n >= NN) return;
    const float* row = X + (size_t)n * 32;
    float s = 0.f;
#pragma unroll
    for (int i = 0; i < 8; i++) {
        float4 f = *(const float4*)(row + i * 4);
        s += f.x * w[i * 4] + f.y * w[i * 4 + 1] + f.z * w[i * 4 + 2] + f.w * w[i * 4 + 3];
    }
    h[n] = s;
    al_src[n] = s * a_s[0];
    al_dst[n] = s * a_d[0];
}

// wave-per-node attention dots (h unpitched [NN,HC])
__global__ void al_wave_kernel(const float* __restrict__ h, const float* __restrict__ a_s,
                               const float* __restrict__ a_d, float* __restrict__ al_src,
                               float* __restrict__ al_dst, int H, int C, int HC) {
    int w = (blockIdx.x * blockDim.x + threadIdx.x) >> 6;
    int lane = threadIdx.x & 63;
    if (w >= NN) return;
    const float* row = h + (size_t)w * HC;
    float s1[5] = {0.f, 0.f, 0.f, 0.f, 0.f};
    float s2[5] = {0.f, 0.f, 0.f, 0.f, 0.f};
#pragma unroll
    for (int hd = 0; hd < 5; hd++) {
        if (hd >= H) break;
        int base = hd * C;
        for (int c = lane; c < C; c += 64) {
            float v = row[base + c];
            s1[hd] += v * a_s[base + c];
            s2[hd] += v * a_d[base + c];
        }
    }
#pragma unroll
    for (int hd = 0; hd < 5; hd++) {
        if (hd >= H) break;
#pragma unroll
        for (int off = 32; off > 0; off >>= 1) {
            s1[hd] += __shfl_xor(s1[hd], off, 64);
            s2[hd] += __shfl_xor(s2[hd], off, 64);
        }
    }
    if (lane == 0) {
#pragma unroll
        for (int hd = 0; hd < 5; hd++) {
            if (hd >= H) break;
            al_src[(size_t)w * H + hd] = s1[hd];
            al_dst[(size_t)w * H + hd] = s2[hd];
        }
    }
}

// fused logit + ONLINE segment softmax
__global__ void attn_kernel(const float* __restrict__ al_src,
                            const float* __restrict__ al_dst,
                            const int* __restrict__ csr_src,
                            const float* __restrict__ csr_ea,
                            const float* __restrict__ we_dot,
                            const int* __restrict__ off,
                            float* __restrict__ alpha_t, int H, int NH) {
    int t = blockIdx.x * blockDim.x + threadIdx.x;
    if (t >= NH) return;
    int n = t / H, hd = t - n * H;
    int s = off[n], e = off[n + 1];
    float ad = al_dst[(size_t)n * H + hd];
    float wd = we_dot[hd];
    float* arow = alpha_t + (size_t)hd * ET;
    float m = -INFINITY, l = 0.f;
    int p = s;
    for (; p + 3 < e; p += 4) {
        int s0 = csr_src[p], s1 = csr_src[p + 1], s2 = csr_src[p + 2], s3 = csr_src[p + 3];
        float w0 = csr_ea[p], w1 = csr_ea[p + 1], w2 = csr_ea[p + 2], w3 = csr_ea[p + 3];
        float l0 = al_src[(size_t)s0 * H + hd] + ad + w0 * wd;
        float l1 = al_src[(size_t)s1 * H + hd] + ad + w1 * wd;
        float l2 = al_src[(size_t)s2 * H + hd] + ad + w2 * wd;
        float l3 = al_src[(size_t)s3 * H + hd] + ad + w3 * wd;
        l0 = (l0 >= 0.f) ? l0 : NEG_SLOPE * l0;
        l1 = (l1 >= 0.f) ? l1 : NEG_SLOPE * l1;
        l2 = (l2 >= 0.f) ? l2 : NEG_SLOPE * l2;
        l3 = (l3 >= 0.f) ? l3 : NEG_SLOPE * l3;
        arow[p] = l0; arow[p + 1] = l1; arow[p + 2] = l2; arow[p + 3] = l3;
        float mq = fmaxf(fmaxf(l0, l1), fmaxf(l2, l3));
        float nm = fmaxf(m, mq);
        l = l * __expf(m - nm)
          + __expf(l0 - nm) + __expf(l1 - nm) + __expf(l2 - nm) + __expf(l3 - nm);
        m = nm;
    }
    for (; p < e; p++) {
        float lg = al_src[(size_t)csr_src[p] * H + hd] + ad + csr_ea[p] * wd;
        lg = (lg >= 0.f) ? lg : NEG_SLOPE * lg;
        arow[p] = lg;
        float nm = fmaxf(m, lg);
        l = l * __expf(m - nm) + __expf(lg - nm);
        m = nm;
    }
    float inv = 1.f / fmaxf(l, 1e-16f);
    for (p = s; p < e; p++) arow[p] = __expf(arow[p] - m) * inv;
}

// bf16 gather aggregate, 4 cols/thread (4|C); pitched output
__global__ void aggregate_v4h_kernel(const unsigned short* __restrict__ h16,
                                     const float* __restrict__ alpha_t,
                                     const int* __restrict__ off,
                                     const int* __restrict__ csr_src,
                                     const float* __restrict__ bias,
                                     float* __restrict__ out,
                                     int C, int HC, int HC4, int total4, int opitch) {
    int t = blockIdx.x * blockDim.x + threadIdx.x;
    if (t >= total4) return;
    int n = t / HC4, j4 = t - n * HC4;
    int j = j4 * 4;
    int hd = j / C;
    const float* arow = alpha_t + (size_t)hd * ET;
    int s = off[n], e = off[n + 1];
    float4 acc = make_float4(0.f, 0.f, 0.f, 0.f);
    int p = s;
    for (; p + 3 < e; p += 4) {
        int idx[4]; float a[4];
#pragma unroll
        for (int u = 0; u < 4; u++) { idx[u] = csr_src[p + u]; a[u] = arow[p + u]; }
#pragma unroll
        for (int u = 0; u < 4; u++) {
            ushort4 uv = *(const ushort4*)(h16 + (size_t)idx[u] * HC + j);
            acc.x += a[u] * bf2f(uv.x);
            acc.y += a[u] * bf2f(uv.y);
            acc.z += a[u] * bf2f(uv.z);
            acc.w += a[u] * bf2f(uv.w);
        }
    }
    for (; p < e; p++) {
        int s0 = csr_src[p];
        float a0 = arow[p];
        ushort4 uv = *(const ushort4*)(h16 + (size_t)s0 * HC + j);
        acc.x += a0 * bf2f(uv.x);
        acc.y += a0 * bf2f(uv.y);
        acc.z += a0 * bf2f(uv.z);
        acc.w += a0 * bf2f(uv.w);
    }
    float4 bi = *(const float4*)(bias + j);
    float4 rr = make_float4(acc.x + bi.x, acc.y + bi.y, acc.z + bi.z, acc.w + bi.w);
    *(float4*)(out + (size_t)n * opitch + j) = rr;
}

// bf16 gather aggregate, 2 cols/thread (2|C) — C=50; pitched output
__global__ void aggregate_v2h_kernel(const unsigned short* __restrict__ h16,
                                     const float* __restrict__ alpha_t,
                                     const int* __restrict__ off,
                                     const int* __restrict__ csr_src,
                                     const float* __restrict__ bias,
                                     float* __restrict__ out,
                                     int C, int HC, int HC2, int total2, int opitch) {
    int t = blockIdx.x * blockDim.x + threadIdx.x;
    if (t >= total2) return;
    int n = t / HC2, j2 = t - n * HC2;
    int j = j2 * 2;
    int hd = j / C;
    const float* arow = alpha_t + (size_t)hd * ET;
    int s = off[n], e = off[n + 1];
    float2 acc = make_float2(0.f, 0.f);
    int p = s;
    for (; p + 3 < e; p += 4) {
        int idx[4]; float a[4];
#pragma unroll
        for (int u = 0; u < 4; u++) { idx[u] = csr_src[p + u]; a[u] = arow[p + u]; }
#pragma unroll
        for (int u = 0; u < 4; u++) {
            ushort2 uv = *(const ushort2*)(h16 + (size_t)idx[u] * HC + j);
            acc.x += a[u] * bf2f(uv.x);
            acc.y += a[u] * bf2f(uv.y);
        }
    }
    for (; p < e; p++) {
        int s0 = csr_src[p];
        float a0 = arow[p];
        ushort2 uv = *(const ushort2*)(h16 + (size_t)s0 * HC + j);
        acc.x += a0 * bf2f(uv.x);
        acc.y += a0 * bf2f(uv.y);
    }
    float2 bi = *(const float2*)(bias + j);
    *(float2*)(out + (size_t)n * opitch + j) = make_float2(acc.x + bi.x, acc.y + bi.y);
}

// f32 float4 aggregate (layer 4); optional fused relu; pitched output
__global__ void aggregate_v4_kernel(const float* __restrict__ hfeat,
                                    const float* __restrict__ alpha_t,
                                    const int* __restrict__ off,
                                    const int* __restrict__ csr_src,
                                    const float* __restrict__ bias,
                                    float* __restrict__ out,
                                    int C, int HC, int HC4, int total4, int relu, int opitch) {
    int t = blockIdx.x * blockDim.x + threadIdx.x;
    if (t >= total4) return;
    int n = t / HC4, j4 = t - n * HC4;
    int j = j4 * 4;
    int hd = j / C;
    const float* arow = alpha_t + (size_t)hd * ET;
    int s = off[n], e = off[n + 1];
    float4 acc = make_float4(0.f, 0.f, 0.f, 0.f);
    int p = s;
    for (; p + 3 < e; p += 4) {
        int idx[4]; float a[4];
#pragma unroll
        for (int u = 0; u < 4; u++) { idx[u] = csr_src[p + u]; a[u] = arow[p + u]; }
#pragma unroll
        for (int u = 0; u < 4; u++) {
            float4 f = *(const float4*)(hfeat + (size_t)idx[u] * HC + j);
            acc.x += a[u] * f.x; acc.y += a[u] * f.y; acc.z += a[u] * f.z; acc.w += a[u] * f.w;
        }
    }
    for (; p < e; p++) {
        int s0 = csr_src[p];
        float a0 = arow[p];
        float4 f0 = *(const float4*)(hfeat + (size_t)s0 * HC + j);
        acc.x += a0 * f0.x; acc.y += a0 * f0.y; acc.z += a0 * f0.z; acc.w += a0 * f0.w;
    }
    float4 bi = *(const float4*)(bias + j);
    float4 rr = make_float4(acc.x + bi.x, acc.y + bi.y, acc.z + bi.z, acc.w + bi.w);
    if (relu) {
        rr.x = fmaxf(rr.x, 0.f); rr.y = fmaxf(rr.y, 0.f);
        rr.z = fmaxf(rr.z, 0.f); rr.w = fmaxf(rr.w, 0.f);
    }
    *(float4*)(out + (size_t)n * opitch + j) = rr;
}

// scalar fallback (layer 5, HC==1)
__global__ void aggregate_kernel(const float* __restrict__ hfeat,
                                 const float* __restrict__ alpha_t,
                                 const int* __restrict__ off, const int* __restrict__ csr_src,
                                 const float* __restrict__ bias, float* __restrict__ out,
                                 int total) {
    int t = blockIdx.x * blockDim.x + threadIdx.x;
    if (t >= total) return;
    int n = t;
    int s = off[n], e = off[n + 1];
    float acc = 0.f;
    int p = s;
    for (; p + 3 < e; p += 4) {
        acc += alpha_t[p] * hfeat[csr_src[p]]
             + alpha_t[p + 1] * hfeat[csr_src[p + 1]]
             + alpha_t[p + 2] * hfeat[csr_src[p + 2]]
             + alpha_t[p + 3] * hfeat[csr_src[p + 3]];
    }
    for (; p < e; p++) acc += alpha_t[p] * hfeat[csr_src[p]];
    out[n] = acc + bias[0];
}

// ---------------- BN / activations (pitched) ----------------

__global__ void bn_stats_kernel(const float* __restrict__ x, float* __restrict__ colsum,
                                float* __restrict__ colsumsq, int D, int pitch) {
    int rows_per_block = (NN + gridDim.x - 1) / gridDim.x;
    int r0 = blockIdx.x * rows_per_block;
    int r1 = min(NN, r0 + rows_per_block);
    int c0 = threadIdx.x;
    int c1 = threadIdx.x + 256;
    float s0 = 0.f, q0 = 0.f, s1 = 0.f, q1 = 0.f;
    for (int r = r0; r < r1; r++) {
        const float* row = x + (size_t)r * pitch;
        if (c0 < D) { float v = row[c0]; s0 += v; q0 += v * v; }
        if (c1 < D) { float v = row[c1]; s1 += v; q1 += v * v; }
    }
    if (c0 < D) { atomicAdd(&colsum[c0], s0); atomicAdd(&colsumsq[c0], q0); }
    if (c1 < D) { atomicAdd(&colsum[c1], s1); atomicAdd(&colsumsq[c1], q1); }
}

__global__ void bn_relu_v4_kernel(float* __restrict__ x,
                                  const float* __restrict__ colsum,
                                  const float* __restrict__ colsumsq,
                                  const float* __restrict__ g, const float* __restrict__ beta,
                                  int total4, int D, int pitch) {
    __shared__ float sscale[512];
    __shared__ float sshift[512];
    for (int c = threadIdx.x; c < D; c += blockDim.x) {
        float mu = colsum[c] * (1.0f / (float)NN);
        float var = colsumsq[c] * (1.0f / (float)NN) - mu * mu;
        float sc = g[c] * rsqrtf(var + BN_EPS);
        sscale[c] = sc;
        sshift[c] = beta[c] - mu * sc;
    }
    __syncthreads();
    int D4 = D >> 2;
    for (int i = blockIdx.x * blockDim.x + threadIdx.x; i < total4; i += gridDim.x * blockDim.x) {
        int row = i / D4;
        int c4 = (i - row * D4) * 4;
        float* px = x + (size_t)row * pitch + c4;
        float4 v = *(float4*)px;
        v.x = fmaxf(v.x * sscale[c4]     + sshift[c4],     0.f);
        v.y = fmaxf(v.y * sscale[c4 + 1] + sshift[c4 + 1], 0.f);
        v.z = fmaxf(v.z * sscale[c4 + 2] + sshift[c4 + 2], 0.f);
        v.w = fmaxf(v.w * sscale[c4 + 3] + sshift[c4 + 3], 0.f);
        *(float4*)px = v;
    }
}

__global__ void bn_relu_v2_kernel(float* __restrict__ x,
                                  const float* __restrict__ colsum,
                                  const float* __restrict__ colsumsq,
                                  const float* __restrict__ g, const float* __restrict__ beta,
                                  int total2, int D, int pitch) {
    __shared__ float sscale[512];
    __shared__ float sshift[512];
    for (int c = threadIdx.x; c < D; c += blockDim.x) {
        float mu = colsum[c] * (1.0f / (float)NN);
        float var = colsumsq[c] * (1.0f / (float)NN) - mu * mu;
        float sc = g[c] * rsqrtf(var + BN_EPS);
        sscale[c] = sc;
        sshift[c] = beta[c] - mu * sc;
    }
    __syncthreads();
    int D2 = D >> 1;
    for (int i = blockIdx.x * blockDim.x + threadIdx.x; i < total2; i += gridDim.x * blockDim.x) {
        int row = i / D2;
        int c2 = (i - row * D2) * 2;
        float* px = x + (size_t)row * pitch + c2;
        float2 v = *(float2*)px;
        v.x = fmaxf(v.x * sscale[c2]     + sshift[c2],     0.f);
        v.y = fmaxf(v.y * sscale[c2 + 1] + sshift[c2 + 1], 0.f);
        *(float2*)px = v;
    }
}

// ---------------- host orchestration ----------------

static inline size_t align_up(size_t v, size_t a) { return (v + a - 1) / a * a; }

extern "C" void kernel_launch(void* const* d_in, const int* in_sizes, int n_in,
                              void* d_out, int out_size, void* d_ws, size_t ws_size,
                              hipStream_t stream) {
    const float* x_in = (const float*)d_in[0];
    const int* ei     = (const int*)d_in[1];
    const float* ew   = (const float*)d_in[2];

    char* pws = (char*)d_ws;
    size_t off_b = 0;
    auto alloc = [&](size_t bytes) -> void* {
        void* rp = pws + off_b;
        off_b = align_up(off_b + bytes, 256);
        return rp;
    };
    float* B0      = (float*)alloc((size_t)NN * 500 * 4);      // GEMM f32 out (pitch HC)
    float* B1      = (float*)alloc((size_t)NN * 512 * 4);      // activations (pitched to Kp_next)
    unsigned short* H16 = (unsigned short*)alloc((size_t)NN * 500 * 2);
    float* alpha_t = (float*)alloc((size_t)ET * 5 * 4);
    unsigned short* Wt_hi = (unsigned short*)alloc((size_t)600 * 512 * 2);
    unsigned short* Wt_lo = (unsigned short*)alloc((size_t)600 * 512 * 2);
    float* al_src  = (float*)alloc((size_t)NN * 5 * 4);
    float* al_dst  = (float*)alloc((size_t)NN * 5 * 4);
    float* ea      = (float*)alloc((size_t)ET * 4);
    float* csr_ea  = (float*)alloc((size_t)ET * 4);
    int* srcv      = (int*)alloc((size_t)ET * 4);
    int* dstv      = (int*)alloc((size_t)ET * 4);
    int* csr_src   = (int*)alloc((size_t)ET * 4);
    int* offarr    = (int*)alloc((size_t)(NN + 1) * 4);
    int* wptr      = (int*)alloc((size_t)NN * 4);
    int* cnt       = (int*)alloc((size_t)NN * 4);
    float* esum    = (float*)alloc(4);
    float* we_dot  = (float*)alloc(40 * 4);
    float* colsum  = (float*)alloc(512 * 4);
    float* colsumsq= (float*)alloc(512 * 4);
    (void)ws_size; (void)n_in; (void)in_sizes; (void)out_size;

    int Kp[5], Np[5];
    size_t wtoff[5];
    size_t acc_off = 0;
    for (int l = 0; l < 5; l++) {
        int K = g_cfg[l].cin, HC = g_cfg[l].C * g_cfg[l].H;
        Kp[l] = (K + 31) / 32 * 32;
        Np[l] = (HC + 127) / 128 * 128;
        wtoff[l] = acc_off;
        acc_off += (size_t)Kp[l] * Np[l];
    }

    PrepArgs pa;
    for (int l = 0; l < 5; l++) {
        pa.W[l]  = (const float*)d_in[3 + l * 6 + 0];
        pa.We[l] = (const float*)d_in[3 + l * 6 + 3];
        pa.ae[l] = (const float*)d_in[3 + l * 6 + 4];
        pa.bh[l] = Wt_hi + wtoff[l];
        pa.bl[l] = Wt_lo + wtoff[l];
        pa.K[l] = g_cfg[l].cin;
        pa.N[l] = g_cfg[l].C * g_cfg[l].H;
        pa.Kp[l] = Kp[l];
        pa.Np[l] = Np[l];
        pa.C[l] = g_cfg[l].C;
        pa.H[l] = g_cfg[l].H;
    }
    pa.wedot = we_dot;

    // graph & CSR build
    hipMemsetAsync(esum, 0, 4, stream);
    hipMemsetAsync(cnt, 0, (size_t)NN * 4, stream);
    ewsum_kernel<<<256, 256, 0, stream>>>(ew, esum, EE);
    int ebl = (ET + 255) / 256;
    build_edges_kernel<<<ebl, 256, 0, stream>>>(ei, ew, esum, srcv, dstv, ea, cnt);
    scan_kernel<<<1, 1024, 0, stream>>>(cnt, offarr, wptr);
    fill_kernel<<<ebl, 256, 0, stream>>>(dstv, srcv, ea, wptr, csr_src, csr_ea);

    // all-layer weight prep
    wedot_all_kernel<<<1, 64, 0, stream>>>(pa);
    transpose_all_kernel<<<dim3(16, 16, 5), dim3(32, 8), 0, stream>>>(pa);

    int bn_idx = 0;
    for (int l = 0; l < 5; l++) {
        const LayerCfg& cf = g_cfg[l];
        int H = cf.H, C = cf.C;
        int HC = H * C;
        const float* a_s = (const float*)d_in[3 + l * 6 + 1];
        const float* a_d = (const float*)d_in[3 + l * 6 + 2];
        const float* b   = (const float*)d_in[3 + l * 6 + 5];

        const float* X = (l == 0) ? x_in : B1;
        float* hbuf = B0;
        float* outbuf = (l == 4) ? (float*)d_out : B1;
        bool big = (l < 3);                       // layers 1-3: bf16 gather path
        int opitch = (l == 4) ? 1 : ((l < 4) ? Kp[l + 1] : HC);  // out pitch = next layer's Kp
        int NH = NN * H;

        if (l == 4) {
            // fused GEMV + al for HC==1
            gemv_l5_kernel<<<(NN + 255) / 256, 256, 0, stream>>>(
                X, pa.W[4], a_s, a_d, hbuf, al_src, al_dst);
        } else {
            dim3 ggrid(Np[l] / GBNT, (NN + GBM - 1) / GBM);
            gemm_split_kernel<<<ggrid, 256, 0, stream>>>(X, Wt_hi + wtoff[l], Wt_lo + wtoff[l],
                                                         hbuf, big ? H16 : nullptr,
                                                         NN, Kp[l], HC, Kp[l]);
            int alblocks = (NN * 64 + 255) / 256;
            al_wave_kernel<<<alblocks, 256, 0, stream>>>(hbuf, a_s, a_d, al_src, al_dst, H, C, HC);
        }

        attn_kernel<<<(NH + 255) / 256, 256, 0, stream>>>(al_src, al_dst, csr_src, csr_ea,
                                                          we_dot + l * 8, offarr, alpha_t, H, NH);

        if (big && (C & 3) == 0) {
            int HC4 = HC / 4;
            int total4 = NN * HC4;
            aggregate_v4h_kernel<<<(total4 + 255) / 256, 256, 0, stream>>>(
                H16, alpha_t, offarr, csr_src, b, outbuf, C, HC, HC4, total4, opitch);
        } else if (big) {
            int HC2 = HC / 2;
            int total2 = NN * HC2;
            aggregate_v2h_kernel<<<(total2 + 255) / 256, 256, 0, stream>>>(
                H16, alpha_t, offarr, csr_src, b, outbuf, C, HC, HC2, total2, opitch);
        } else if (l == 3) {
            int HC4 = HC / 4;
            int total4 = NN * HC4;
            aggregate_v4_kernel<<<(total4 + 255) / 256, 256, 0, stream>>>(
                hbuf, alpha_t, offarr, csr_src, b, outbuf, C, HC, HC4, total4, 1, opitch);
        } else {
            aggregate_kernel<<<(NN + 255) / 256, 256, 0, stream>>>(
                hbuf, alpha_t, offarr, csr_src, b, outbuf, NN);
        }

        // zero pad columns of the pitched activation (needed before next GEMM)
        if (l < 4 && opitch > HC) {
            int padc = opitch - HC;
            int ptot = NN * padc;
            padzero_kernel<<<(ptot + 255) / 256, 256, 0, stream>>>(outbuf, opitch, HC, padc);
        }

        if (l < 3) {
            int D = HC;
            int total = NN * HC;
            const float* g    = (const float*)d_in[33 + bn_idx * 2 + 0];
            const float* beta = (const float*)d_in[33 + bn_idx * 2 + 1];
            hipMemsetAsync(colsum, 0, 2 * 512 * 4, stream);
            bn_stats_kernel<<<512, 256, 0, stream>>>(outbuf, colsum, colsumsq, D, opitch);
            if ((D & 3) == 0) {
                bn_relu_v4_kernel<<<2048, 256, 0, stream>>>(outbuf, colsum, colsumsq, g, beta,
                                                            total / 4, D, opitch);
            } else {
                bn_relu_v2_kernel<<<2048, 256, 0, stream>>>(outbuf, colsum, colsumsq, g, beta,
                                                            total / 2, D, opitch);
            }
            bn_idx++;
        }
    }
}

// Round 12
// 890.579 us; speedup vs baseline: 2.4221x; 1.0540x over previous
//
#include <hip/hip_runtime.h>
#include <hip/hip_bf16.h>
#include <math.h>

// ---------------- problem constants ----------------
#define NN 30000
#define EE 480000
#define ET (EE + NN)   // edges + self loops = 510000
#define NEG_SLOPE 0.2f
#define BN_EPS 1e-5f

struct LayerCfg { int cin, C, H; };
static const LayerCfg g_cfg[5] = {
    {128, 100, 5}, {500, 50, 5}, {250, 32, 4}, {128, 8, 4}, {32, 1, 1}
};

typedef short short8 __attribute__((ext_vector_type(8)));
typedef float f32x4 __attribute__((ext_vector_type(4)));

__device__ __forceinline__ unsigned short f2bf(float f) {
    unsigned int u = __builtin_bit_cast(unsigned int, f);
    u = (u + 0x7FFFu + ((u >> 16) & 1u)) >> 16;
    return (unsigned short)u;
}
__device__ __forceinline__ float bf2f(unsigned short h) {
    unsigned int u = ((unsigned int)h) << 16;
    return __builtin_bit_cast(float, u);
}

// ---------------- graph / CSR kernels ----------------

__global__ void ewsum_kernel(const float* __restrict__ ew, float* __restrict__ out, int E) {
    __shared__ float sdata[256];
    int tid = threadIdx.x;
    float s = 0.f;
    for (int i = blockIdx.x * blockDim.x + tid; i < E; i += gridDim.x * blockDim.x)
        s += ew[i];
    sdata[tid] = s;
    __syncthreads();
    for (int off = 128; off > 0; off >>= 1) {
        if (tid < off) sdata[tid] += sdata[tid + off];
        __syncthreads();
    }
    if (tid == 0) atomicAdd(out, sdata[0]);
}

__global__ void build_edges_kernel(const int* __restrict__ ei, const float* __restrict__ ew,
                                   const float* __restrict__ sum,
                                   int* __restrict__ srcv, int* __restrict__ dstv,
                                   float* __restrict__ ea, int* __restrict__ cnt) {
    int e = blockIdx.x * blockDim.x + threadIdx.x;
    if (e >= ET) return;
    int d;
    if (e < EE) {
        srcv[e] = ei[e];
        d = ei[EE + e];
        dstv[e] = d;
        ea[e]   = ew[e];
    } else {
        int n = e - EE;
        srcv[e] = n;
        d = n;
        dstv[e] = n;
        ea[e]   = sum[0] * (1.0f / (float)EE);
    }
    atomicAdd(&cnt[d], 1);
}

__global__ void scan_kernel(const int* __restrict__ cnt, int* __restrict__ off,
                            int* __restrict__ wptr) {
    __shared__ int lsum[1024];
    __shared__ int loff[1024];
    const int T = 1024;
    int t = threadIdx.x;
    int chunk = (NN + T - 1) / T;
    int base = t * chunk;
    int end = min(NN, base + chunk);
    int s = 0;
    for (int i = base; i < end; i++) s += cnt[i];
    lsum[t] = s;
    __syncthreads();
    if (t == 0) {
        int run = 0;
        for (int i = 0; i < T; i++) { loff[i] = run; run += lsum[i]; }
    }
    __syncthreads();
    int run = loff[t];
    for (int i = base; i < end; i++) {
        off[i] = run;
        wptr[i] = run;
        run += cnt[i];
    }
    if (t == 0) off[NN] = ET;
}

__global__ void fill_kernel(const int* __restrict__ dstv, const int* __restrict__ srcv,
                            const float* __restrict__ ea,
                            int* __restrict__ wptr, int* __restrict__ csr_src,
                            float* __restrict__ csr_ea) {
    int e = blockIdx.x * blockDim.x + threadIdx.x;
    if (e >= ET) return;
    int p = atomicAdd(&wptr[dstv[e]], 1);
    csr_src[p] = srcv[e];
    csr_ea[p]  = ea[e];
}

// ---------------- all-layer weight prep ----------------

struct PrepArgs {
    const float* W[5];
    const float* We[5];
    const float* ae[5];
    unsigned short* bh[5];
    unsigned short* bl[5];
    float* wedot;            // out: [5][8]
    int K[5], N[5], Kp[5], Np[5], C[5], H[5];
};

__global__ void wedot_all_kernel(PrepArgs a) {
    int tid = threadIdx.x;   // 64
    int l = tid >> 3, hd = tid & 7;
    if (l < 5 && hd < a.H[l]) {
        int C = a.C[l];
        const float* We = a.We[l] + hd * C;
        const float* ae = a.ae[l] + hd * C;
        float s = 0.f;
        for (int c = 0; c < C; c++) s += We[c] * ae[c];
        a.wedot[l * 8 + hd] = s;
    }
}

__global__ void transpose_all_kernel(PrepArgs a) {
    int l = blockIdx.z;
    int Kp = a.Kp[l], Np = a.Np[l], K = a.K[l], N = a.N[l];
    int kb = blockIdx.x * 32, nb = blockIdx.y * 32;
    if (kb >= Kp || nb >= Np) return;
    const float* B = a.W[l];
    unsigned short* Bth = a.bh[l];
    unsigned short* Btl = a.bl[l];
    __shared__ float tile[32][33];
    int tx = threadIdx.x, ty = threadIdx.y;   // 32 x 8
#pragma unroll
    for (int i = 0; i < 4; i++) {
        int k = kb + ty + i * 8, n = nb + tx;
        tile[ty + i * 8][tx] = (k < K && n < N) ? B[(size_t)k * N + n] : 0.f;
    }
    __syncthreads();
#pragma unroll
    for (int i = 0; i < 4; i++) {
        int n = nb + ty + i * 8, k = kb + tx;
        if (n < Np && k < Kp) {
            float v = tile[tx][ty + i * 8];
            unsigned short hi = f2bf(v);
            unsigned short lo = f2bf(v - bf2f(hi));
            size_t idx = (size_t)n * Kp + k;
            Bth[idx] = hi;
            Btl[idx] = lo;
        }
    }
}

// ---------------- split-bf16 MFMA GEMM with optional fused BN+ReLU on A ----------------
// A pitched (Apitch=Kp), zero/any-padded to Kp cols. If colsum!=null, staging
// applies v = max(v*scale[c]+shift[c], 0) with scale/shift derived in LDS
// (pad cols c>=D get scale=shift=0 -> staged 0 regardless of pad contents).
#define GBM 128
#define GBNT 128
#define GBK 32
#define ASTR 36   // 32 data + 4 pad shorts; total LDS = 4*128*36*2 + 4KB = 40KB
__global__ __launch_bounds__(256) void gemm_split_kernel(const float* __restrict__ A,
                                                         const unsigned short* __restrict__ Bt_hi,
                                                         const unsigned short* __restrict__ Bt_lo,
                                                         float* __restrict__ Cm,
                                                         unsigned short* __restrict__ Ch16,
                                                         int M, int Kp, int Nc,
                                                         const float* __restrict__ colsum,
                                                         const float* __restrict__ colsumsq,
                                                         const float* __restrict__ g,
                                                         const float* __restrict__ beta,
                                                         int D) {
    __shared__ short AsH[GBM * ASTR];
    __shared__ short AsL[GBM * ASTR];
    __shared__ short BsH[GBNT * ASTR];
    __shared__ short BsL[GBNT * ASTR];
    __shared__ float sscale[512];
    __shared__ float sshift[512];
    int tid = threadIdx.x;
    bool bn = (colsum != nullptr);
    if (bn) {
        for (int c = tid; c < Kp; c += 256) {
            float sc = 0.f, sh = 0.f;
            if (c < D) {
                float mu = colsum[c] * (1.0f / (float)NN);
                float var = colsumsq[c] * (1.0f / (float)NN) - mu * mu;
                sc = g[c] * rsqrtf(var + BN_EPS);
                sh = beta[c] - mu * sc;
            }
            sscale[c] = sc;
            sshift[c] = sh;
        }
        __syncthreads();
    }
    int wave = tid >> 6, lane = tid & 63;
    int q = lane >> 4, r = lane & 15;
    int m0 = blockIdx.y * GBM, n0 = blockIdx.x * GBNT;
    int wm = (wave & 1) * 64, wn = (wave >> 1) * 64;
    f32x4 acc[4][4];
#pragma unroll
    for (int i = 0; i < 4; i++)
#pragma unroll
        for (int j = 0; j < 4; j++) acc[i][j] = (f32x4)(0.f);

    int arow2 = tid >> 1;          // 0..127
    int acol2 = (tid & 1) * 16;    // 0 or 16
    int brow = tid >> 2;
    int bcol = (tid & 3) * 8;

    int ksteps = Kp / GBK;
    for (int ks = 0; ks < ksteps; ks++) {
        int k0 = ks * GBK;
        {
            int m = m0 + arow2;
            float v[16];
            if (m < M) {
                const float* Ap = A + (size_t)m * Kp + k0 + acol2;
                float4 f0 = *(const float4*)(Ap);
                float4 f1 = *(const float4*)(Ap + 4);
                float4 f2 = *(const float4*)(Ap + 8);
                float4 f3 = *(const float4*)(Ap + 12);
                v[0]=f0.x; v[1]=f0.y; v[2]=f0.z; v[3]=f0.w;
                v[4]=f1.x; v[5]=f1.y; v[6]=f1.z; v[7]=f1.w;
                v[8]=f2.x; v[9]=f2.y; v[10]=f2.z; v[11]=f2.w;
                v[12]=f3.x; v[13]=f3.y; v[14]=f3.z; v[15]=f3.w;
                if (bn) {
                    int cb = k0 + acol2;
#pragma unroll
                    for (int i = 0; i < 16; i++)
                        v[i] = fmaxf(v[i] * sscale[cb + i] + sshift[cb + i], 0.f);
                }
            } else {
#pragma unroll
                for (int i = 0; i < 16; i++) v[i] = 0.f;
            }
#pragma unroll
            for (int i = 0; i < 16; i++) {
                unsigned short hi = f2bf(v[i]);
                unsigned short lo = f2bf(v[i] - bf2f(hi));
                AsH[arow2 * ASTR + acol2 + i] = (short)hi;
                AsL[arow2 * ASTR + acol2 + i] = (short)lo;
            }
        }
#pragma unroll
        for (int p = 0; p < 2; p++) {
            int row = p * 64 + brow;
            size_t gidx = (size_t)(n0 + row) * Kp + k0 + bcol;
            *((uint4*)(BsH + row * ASTR + bcol)) = *((const uint4*)(Bt_hi + gidx));
            *((uint4*)(BsL + row * ASTR + bcol)) = *((const uint4*)(Bt_lo + gidx));
        }
        __syncthreads();
        short8 ah[4], al[4], bh[4], bl[4];
#pragma unroll
        for (int i = 0; i < 4; i++) {
            ah[i] = *((const short8*)(AsH + (wm + i * 16 + r) * ASTR + q * 8));
            al[i] = *((const short8*)(AsL + (wm + i * 16 + r) * ASTR + q * 8));
        }
#pragma unroll
        for (int j = 0; j < 4; j++) {
            bh[j] = *((const short8*)(BsH + (wn + j * 16 + r) * ASTR + q * 8));
            bl[j] = *((const short8*)(BsL + (wn + j * 16 + r) * ASTR + q * 8));
        }
#pragma unroll
        for (int i = 0; i < 4; i++)
#pragma unroll
            for (int j = 0; j < 4; j++) {
                acc[i][j] = __builtin_amdgcn_mfma_f32_16x16x32_bf16(ah[i], bh[j], acc[i][j], 0, 0, 0);
                acc[i][j] = __builtin_amdgcn_mfma_f32_16x16x32_bf16(ah[i], bl[j], acc[i][j], 0, 0, 0);
                acc[i][j] = __builtin_amdgcn_mfma_f32_16x16x32_bf16(al[i], bh[j], acc[i][j], 0, 0, 0);
            }
        __syncthreads();
    }
#pragma unroll
    for (int i = 0; i < 4; i++) {
#pragma unroll
        for (int j = 0; j < 4; j++) {
#pragma unroll
            for (int reg = 0; reg < 4; reg++) {
                int mrow = m0 + wm + i * 16 + q * 4 + reg;
                int ncol = n0 + wn + j * 16 + r;
                if (mrow < M && ncol < Nc) {
                    float val = acc[i][j][reg];
                    Cm[(size_t)mrow * Nc + ncol] = val;
                    if (Ch16) Ch16[(size_t)mrow * Nc + ncol] = f2bf(val);
                }
            }
        }
    }
}

// layer-5 fused GEMV: h = X @ w (K=32, Nc=1) + al_src/al_dst scalars
__global__ void gemv_l5_kernel(const float* __restrict__ X, const float* __restrict__ W,
                               const float* __restrict__ a_s, const float* __restrict__ a_d,
                               float* __restrict__ h, float* __restrict__ al_src,
                               float* __restrict__ al_dst) {
    __shared__ float w[32];
    if (threadIdx.x < 32) w[threadIdx.x] = W[threadIdx.x];
    __syncthreads();
    int n = blockIdx.x * blockDim.x + threadIdx.x;
    if (n >= NN) return;
    const float* row = X + (size_t)n * 32;
    float s = 0.f;
#pragma unroll
    for (int i = 0; i < 8; i++) {
        float4 f = *(const float4*)(row + i * 4);
        s += f.x * w[i * 4] + f.y * w[i * 4 + 1] + f.z * w[i * 4 + 2] + f.w * w[i * 4 + 3];
    }
    h[n] = s;
    al_src[n] = s * a_s[0];
    al_dst[n] = s * a_d[0];
}

// wave-per-node attention dots (h unpitched [NN,HC])
__global__ void al_wave_kernel(const float* __restrict__ h, const float* __restrict__ a_s,
                               const float* __restrict__ a_d, float* __restrict__ al_src,
                               float* __restrict__ al_dst, int H, int C, int HC) {
    int w = (blockIdx.x * blockDim.x + threadIdx.x) >> 6;
    int lane = threadIdx.x & 63;
    if (w >= NN) return;
    const float* row = h + (size_t)w * HC;
    float s1[5] = {0.f, 0.f, 0.f, 0.f, 0.f};
    float s2[5] = {0.f, 0.f, 0.f, 0.f, 0.f};
#pragma unroll
    for (int hd = 0; hd < 5; hd++) {
        if (hd >= H) break;
        int base = hd * C;
        for (int c = lane; c < C; c += 64) {
            float v = row[base + c];
            s1[hd] += v * a_s[base + c];
            s2[hd] += v * a_d[base + c];
        }
    }
#pragma unroll
    for (int hd = 0; hd < 5; hd++) {
        if (hd >= H) break;
#pragma unroll
        for (int off = 32; off > 0; off >>= 1) {
            s1[hd] += __shfl_xor(s1[hd], off, 64);
            s2[hd] += __shfl_xor(s2[hd], off, 64);
        }
    }
    if (lane == 0) {
#pragma unroll
        for (int hd = 0; hd < 5; hd++) {
            if (hd >= H) break;
            al_src[(size_t)w * H + hd] = s1[hd];
            al_dst[(size_t)w * H + hd] = s2[hd];
        }
    }
}

// fused logit + ONLINE segment softmax
__global__ void attn_kernel(const float* __restrict__ al_src,
                            const float* __restrict__ al_dst,
                            const int* __restrict__ csr_src,
                            const float* __restrict__ csr_ea,
                            const float* __restrict__ we_dot,
                            const int* __restrict__ off,
                            float* __restrict__ alpha_t, int H, int NH) {
    int t = blockIdx.x * blockDim.x + threadIdx.x;
    if (t >= NH) return;
    int n = t / H, hd = t - n * H;
    int s = off[n], e = off[n + 1];
    float ad = al_dst[(size_t)n * H + hd];
    float wd = we_dot[hd];
    float* arow = alpha_t + (size_t)hd * ET;
    float m = -INFINITY, l = 0.f;
    int p = s;
    for (; p + 3 < e; p += 4) {
        int s0 = csr_src[p], s1 = csr_src[p + 1], s2 = csr_src[p + 2], s3 = csr_src[p + 3];
        float w0 = csr_ea[p], w1 = csr_ea[p + 1], w2 = csr_ea[p + 2], w3 = csr_ea[p + 3];
        float l0 = al_src[(size_t)s0 * H + hd] + ad + w0 * wd;
        float l1 = al_src[(size_t)s1 * H + hd] + ad + w1 * wd;
        float l2 = al_src[(size_t)s2 * H + hd] + ad + w2 * wd;
        float l3 = al_src[(size_t)s3 * H + hd] + ad + w3 * wd;
        l0 = (l0 >= 0.f) ? l0 : NEG_SLOPE * l0;
        l1 = (l1 >= 0.f) ? l1 : NEG_SLOPE * l1;
        l2 = (l2 >= 0.f) ? l2 : NEG_SLOPE * l2;
        l3 = (l3 >= 0.f) ? l3 : NEG_SLOPE * l3;
        arow[p] = l0; arow[p + 1] = l1; arow[p + 2] = l2; arow[p + 3] = l3;
        float mq = fmaxf(fmaxf(l0, l1), fmaxf(l2, l3));
        float nm = fmaxf(m, mq);
        l = l * __expf(m - nm)
          + __expf(l0 - nm) + __expf(l1 - nm) + __expf(l2 - nm) + __expf(l3 - nm);
        m = nm;
    }
    for (; p < e; p++) {
        float lg = al_src[(size_t)csr_src[p] * H + hd] + ad + csr_ea[p] * wd;
        lg = (lg >= 0.f) ? lg : NEG_SLOPE * lg;
        arow[p] = lg;
        float nm = fmaxf(m, lg);
        l = l * __expf(m - nm) + __expf(lg - nm);
        m = nm;
    }
    float inv = 1.f / fmaxf(l, 1e-16f);
    for (p = s; p < e; p++) arow[p] = __expf(arow[p] - m) * inv;
}

// bf16 gather aggregate, 4 cols/thread (4|C); pitched output
__global__ void aggregate_v4h_kernel(const unsigned short* __restrict__ h16,
                                     const float* __restrict__ alpha_t,
                                     const int* __restrict__ off,
                                     const int* __restrict__ csr_src,
                                     const float* __restrict__ bias,
                                     float* __restrict__ out,
                                     int C, int HC, int HC4, int total4, int opitch) {
    int t = blockIdx.x * blockDim.x + threadIdx.x;
    if (t >= total4) return;
    int n = t / HC4, j4 = t - n * HC4;
    int j = j4 * 4;
    int hd = j / C;
    const float* arow = alpha_t + (size_t)hd * ET;
    int s = off[n], e = off[n + 1];
    float4 acc = make_float4(0.f, 0.f, 0.f, 0.f);
    int p = s;
    for (; p + 3 < e; p += 4) {
        int idx[4]; float a[4];
#pragma unroll
        for (int u = 0; u < 4; u++) { idx[u] = csr_src[p + u]; a[u] = arow[p + u]; }
#pragma unroll
        for (int u = 0; u < 4; u++) {
            ushort4 uv = *(const ushort4*)(h16 + (size_t)idx[u] * HC + j);
            acc.x += a[u] * bf2f(uv.x);
            acc.y += a[u] * bf2f(uv.y);
            acc.z += a[u] * bf2f(uv.z);
            acc.w += a[u] * bf2f(uv.w);
        }
    }
    for (; p < e; p++) {
        int s0 = csr_src[p];
        float a0 = arow[p];
        ushort4 uv = *(const ushort4*)(h16 + (size_t)s0 * HC + j);
        acc.x += a0 * bf2f(uv.x);
        acc.y += a0 * bf2f(uv.y);
        acc.z += a0 * bf2f(uv.z);
        acc.w += a0 * bf2f(uv.w);
    }
    float4 bi = *(const float4*)(bias + j);
    float4 rr = make_float4(acc.x + bi.x, acc.y + bi.y, acc.z + bi.z, acc.w + bi.w);
    *(float4*)(out + (size_t)n * opitch + j) = rr;
}

// bf16 gather aggregate, 2 cols/thread (2|C) — C=50; pitched output
__global__ void aggregate_v2h_kernel(const unsigned short* __restrict__ h16,
                                     const float* __restrict__ alpha_t,
                                     const int* __restrict__ off,
                                     const int* __restrict__ csr_src,
                                     const float* __restrict__ bias,
                                     float* __restrict__ out,
                                     int C, int HC, int HC2, int total2, int opitch) {
    int t = blockIdx.x * blockDim.x + threadIdx.x;
    if (t >= total2) return;
    int n = t / HC2, j2 = t - n * HC2;
    int j = j2 * 2;
    int hd = j / C;
    const float* arow = alpha_t + (size_t)hd * ET;
    int s = off[n], e = off[n + 1];
    float2 acc = make_float2(0.f, 0.f);
    int p = s;
    for (; p + 3 < e; p += 4) {
        int idx[4]; float a[4];
#pragma unroll
        for (int u = 0; u < 4; u++) { idx[u] = csr_src[p + u]; a[u] = arow[p + u]; }
#pragma unroll
        for (int u = 0; u < 4; u++) {
            ushort2 uv = *(const ushort2*)(h16 + (size_t)idx[u] * HC + j);
            acc.x += a[u] * bf2f(uv.x);
            acc.y += a[u] * bf2f(uv.y);
        }
    }
    for (; p < e; p++) {
        int s0 = csr_src[p];
        float a0 = arow[p];
        ushort2 uv = *(const ushort2*)(h16 + (size_t)s0 * HC + j);
        acc.x += a0 * bf2f(uv.x);
        acc.y += a0 * bf2f(uv.y);
    }
    float2 bi = *(const float2*)(bias + j);
    *(float2*)(out + (size_t)n * opitch + j) = make_float2(acc.x + bi.x, acc.y + bi.y);
}

// f32 float4 aggregate (layer 4); optional fused relu; pitched output
__global__ void aggregate_v4_kernel(const float* __restrict__ hfeat,
                                    const float* __restrict__ alpha_t,
                                    const int* __restrict__ off,
                                    const int* __restrict__ csr_src,
                                    const float* __restrict__ bias,
                                    float* __restrict__ out,
                                    int C, int HC, int HC4, int total4, int relu, int opitch) {
    int t = blockIdx.x * blockDim.x + threadIdx.x;
    if (t >= total4) return;
    int n = t / HC4, j4 = t - n * HC4;
    int j = j4 * 4;
    int hd = j / C;
    const float* arow = alpha_t + (size_t)hd * ET;
    int s = off[n], e = off[n + 1];
    float4 acc = make_float4(0.f, 0.f, 0.f, 0.f);
    int p = s;
    for (; p + 3 < e; p += 4) {
        int idx[4]; float a[4];
#pragma unroll
        for (int u = 0; u < 4; u++) { idx[u] = csr_src[p + u]; a[u] = arow[p + u]; }
#pragma unroll
        for (int u = 0; u < 4; u++) {
            float4 f = *(const float4*)(hfeat + (size_t)idx[u] * HC + j);
            acc.x += a[u] * f.x; acc.y += a[u] * f.y; acc.z += a[u] * f.z; acc.w += a[u] * f.w;
        }
    }
    for (; p < e; p++) {
        int s0 = csr_src[p];
        float a0 = arow[p];
        float4 f0 = *(const float4*)(hfeat + (size_t)s0 * HC + j);
        acc.x += a0 * f0.x; acc.y += a0 * f0.y; acc.z += a0 * f0.z; acc.w += a0 * f0.w;
    }
    float4 bi = *(const float4*)(bias + j);
    float4 rr = make_float4(acc.x + bi.x, acc.y + bi.y, acc.z + bi.z, acc.w + bi.w);
    if (relu) {
        rr.x = fmaxf(rr.x, 0.f); rr.y = fmaxf(rr.y, 0.f);
        rr.z = fmaxf(rr.z, 0.f); rr.w = fmaxf(rr.w, 0.f);
    }
    *(float4*)(out + (size_t)n * opitch + j) = rr;
}

// scalar fallback (layer 5, HC==1)
__global__ void aggregate_kernel(const float* __restrict__ hfeat,
                                 const float* __restrict__ alpha_t,
                                 const int* __restrict__ off, const int* __restrict__ csr_src,
                                 const float* __restrict__ bias, float* __restrict__ out,
                                 int total) {
    int t = blockIdx.x * blockDim.x + threadIdx.x;
    if (t >= total) return;
    int n = t;
    int s = off[n], e = off[n + 1];
    float acc = 0.f;
    int p = s;
    for (; p + 3 < e; p += 4) {
        acc += alpha_t[p] * hfeat[csr_src[p]]
             + alpha_t[p + 1] * hfeat[csr_src[p + 1]]
             + alpha_t[p + 2] * hfeat[csr_src[p + 2]]
             + alpha_t[p + 3] * hfeat[csr_src[p + 3]];
    }
    for (; p < e; p++) acc += alpha_t[p] * hfeat[csr_src[p]];
    out[n] = acc + bias[0];
}

// ---------------- BN stats (pitched) ----------------

__global__ void bn_stats_kernel(const float* __restrict__ x, float* __restrict__ colsum,
                                float* __restrict__ colsumsq, int D, int pitch) {
    int rows_per_block = (NN + gridDim.x - 1) / gridDim.x;
    int r0 = blockIdx.x * rows_per_block;
    int r1 = min(NN, r0 + rows_per_block);
    int c0 = threadIdx.x;
    int c1 = threadIdx.x + 256;
    float s0 = 0.f, q0 = 0.f, s1 = 0.f, q1 = 0.f;
    for (int r = r0; r < r1; r++) {
        const float* row = x + (size_t)r * pitch;
        if (c0 < D) { float v = row[c0]; s0 += v; q0 += v * v; }
        if (c1 < D) { float v = row[c1]; s1 += v; q1 += v * v; }
    }
    if (c0 < D) { atomicAdd(&colsum[c0], s0); atomicAdd(&colsumsq[c0], q0); }
    if (c1 < D) { atomicAdd(&colsum[c1], s1); atomicAdd(&colsumsq[c1], q1); }
}

// ---------------- host orchestration ----------------

static inline size_t align_up(size_t v, size_t a) { return (v + a - 1) / a * a; }

extern "C" void kernel_launch(void* const* d_in, const int* in_sizes, int n_in,
                              void* d_out, int out_size, void* d_ws, size_t ws_size,
                              hipStream_t stream) {
    const float* x_in = (const float*)d_in[0];
    const int* ei     = (const int*)d_in[1];
    const float* ew   = (const float*)d_in[2];

    char* pws = (char*)d_ws;
    size_t off_b = 0;
    auto alloc = [&](size_t bytes) -> void* {
        void* rp = pws + off_b;
        off_b = align_up(off_b + bytes, 256);
        return rp;
    };
    float* B0      = (float*)alloc((size_t)NN * 500 * 4);      // GEMM f32 out (pitch HC)
    float* B1      = (float*)alloc((size_t)NN * 512 * 4);      // activations (pitched to Kp_next)
    unsigned short* H16 = (unsigned short*)alloc((size_t)NN * 500 * 2);
    float* alpha_t = (float*)alloc((size_t)ET * 5 * 4);
    unsigned short* Wt_hi = (unsigned short*)alloc((size_t)600 * 512 * 2);
    unsigned short* Wt_lo = (unsigned short*)alloc((size_t)600 * 512 * 2);
    float* al_src  = (float*)alloc((size_t)NN * 5 * 4);
    float* al_dst  = (float*)alloc((size_t)NN * 5 * 4);
    float* ea      = (float*)alloc((size_t)ET * 4);
    float* csr_ea  = (float*)alloc((size_t)ET * 4);
    int* srcv      = (int*)alloc((size_t)ET * 4);
    int* dstv      = (int*)alloc((size_t)ET * 4);
    int* csr_src   = (int*)alloc((size_t)ET * 4);
    int* offarr    = (int*)alloc((size_t)(NN + 1) * 4);
    int* wptr      = (int*)alloc((size_t)NN * 4);
    float* esum    = (float*)alloc(4);                 // esum+cnt adjacent: one memset
    int* cnt       = (int*)alloc((size_t)NN * 4);
    float* we_dot  = (float*)alloc(40 * 4);
    float* colsum  = (float*)alloc(512 * 4);
    float* colsumsq= (float*)alloc(512 * 4);
    (void)ws_size; (void)n_in; (void)in_sizes; (void)out_size;

    int Kp[5], Np[5];
    size_t wtoff[5];
    size_t acc_off = 0;
    for (int l = 0; l < 5; l++) {
        int K = g_cfg[l].cin, HC = g_cfg[l].C * g_cfg[l].H;
        Kp[l] = (K + 31) / 32 * 32;
        Np[l] = (HC + 127) / 128 * 128;
        wtoff[l] = acc_off;
        acc_off += (size_t)Kp[l] * Np[l];
    }

    PrepArgs pa;
    for (int l = 0; l < 5; l++) {
        pa.W[l]  = (const float*)d_in[3 + l * 6 + 0];
        pa.We[l] = (const float*)d_in[3 + l * 6 + 3];
        pa.ae[l] = (const float*)d_in[3 + l * 6 + 4];
        pa.bh[l] = Wt_hi + wtoff[l];
        pa.bl[l] = Wt_lo + wtoff[l];
        pa.K[l] = g_cfg[l].cin;
        pa.N[l] = g_cfg[l].C * g_cfg[l].H;
        pa.Kp[l] = Kp[l];
        pa.Np[l] = Np[l];
        pa.C[l] = g_cfg[l].C;
        pa.H[l] = g_cfg[l].H;
    }
    pa.wedot = we_dot;

    // graph & CSR build (esum + cnt zeroed in one shot — adjacent in ws)
    hipMemsetAsync(esum, 0, ((char*)(cnt + NN)) - ((char*)esum), stream);
    ewsum_kernel<<<256, 256, 0, stream>>>(ew, esum, EE);
    int ebl = (ET + 255) / 256;
    build_edges_kernel<<<ebl, 256, 0, stream>>>(ei, ew, esum, srcv, dstv, ea, cnt);
    scan_kernel<<<1, 1024, 0, stream>>>(cnt, offarr, wptr);
    fill_kernel<<<ebl, 256, 0, stream>>>(dstv, srcv, ea, wptr, csr_src, csr_ea);

    // all-layer weight prep
    wedot_all_kernel<<<1, 64, 0, stream>>>(pa);
    transpose_all_kernel<<<dim3(16, 16, 5), dim3(32, 8), 0, stream>>>(pa);

    for (int l = 0; l < 5; l++) {
        const LayerCfg& cf = g_cfg[l];
        int H = cf.H, C = cf.C;
        int HC = H * C;
        const float* a_s = (const float*)d_in[3 + l * 6 + 1];
        const float* a_d = (const float*)d_in[3 + l * 6 + 2];
        const float* b   = (const float*)d_in[3 + l * 6 + 5];

        const float* X = (l == 0) ? x_in : B1;
        float* hbuf = B0;
        float* outbuf = (l == 4) ? (float*)d_out : B1;
        bool big = (l < 3);                       // layers 1-3: bf16 gather path
        int opitch = (l == 4) ? 1 : Kp[l + 1];    // out pitch = next layer's Kp
        int NH = NN * H;

        if (l == 4) {
            gemv_l5_kernel<<<(NN + 255) / 256, 256, 0, stream>>>(
                X, pa.W[4], a_s, a_d, hbuf, al_src, al_dst);
        } else {
            // layers 1..3 read BN'd input: fold BN+ReLU into A-staging
            const float* cs = (l >= 1) ? colsum : nullptr;
            const float* cq = (l >= 1) ? colsumsq : nullptr;
            const float* gg = (l >= 1) ? (const float*)d_in[33 + (l - 1) * 2 + 0] : nullptr;
            const float* bb = (l >= 1) ? (const float*)d_in[33 + (l - 1) * 2 + 1] : nullptr;
            int Din = (l >= 1) ? g_cfg[l - 1].C * g_cfg[l - 1].H : 0;
            dim3 ggrid(Np[l] / GBNT, (NN + GBM - 1) / GBM);
            gemm_split_kernel<<<ggrid, 256, 0, stream>>>(X, Wt_hi + wtoff[l], Wt_lo + wtoff[l],
                                                         hbuf, big ? H16 : nullptr,
                                                         NN, Kp[l], HC, cs, cq, gg, bb, Din);
            int alblocks = (NN * 64 + 255) / 256;
            al_wave_kernel<<<alblocks, 256, 0, stream>>>(hbuf, a_s, a_d, al_src, al_dst, H, C, HC);
        }

        attn_kernel<<<(NH + 255) / 256, 256, 0, stream>>>(al_src, al_dst, csr_src, csr_ea,
                                                          we_dot + l * 8, offarr, alpha_t, H, NH);

        if (big && (C & 3) == 0) {
            int HC4 = HC / 4;
            int total4 = NN * HC4;
            aggregate_v4h_kernel<<<(total4 + 255) / 256, 256, 0, stream>>>(
                H16, alpha_t, offarr, csr_src, b, outbuf, C, HC, HC4, total4, opitch);
        } else if (big) {
            int HC2 = HC / 2;
            int total2 = NN * HC2;
            aggregate_v2h_kernel<<<(total2 + 255) / 256, 256, 0, stream>>>(
                H16, alpha_t, offarr, csr_src, b, outbuf, C, HC, HC2, total2, opitch);
        } else if (l == 3) {
            int HC4 = HC / 4;
            int total4 = NN * HC4;
            aggregate_v4_kernel<<<(total4 + 255) / 256, 256, 0, stream>>>(
                hbuf, alpha_t, offarr, csr_src, b, outbuf, C, HC, HC4, total4, 1, opitch);
        } else {
            aggregate_kernel<<<(NN + 255) / 256, 256, 0, stream>>>(
                hbuf, alpha_t, offarr, csr_src, b, outbuf, NN);
        }

        // BN stats for layers 0..2 (consumed by next layer's GEMM staging)
        if (l < 3) {
            int D = HC;
            hipMemsetAsync(colsum, 0, 2 * 512 * 4, stream);
            bn_stats_kernel<<<512, 256, 0, stream>>>(outbuf, colsum, colsumsq, D, opitch);
        }
    }
}

// Round 13
// 881.971 us; speedup vs baseline: 2.4457x; 1.0098x over previous
//
#include <hip/hip_runtime.h>
#include <hip/hip_bf16.h>
#include <math.h>

// ---------------- problem constants ----------------
#define NN 30000
#define EE 480000
#define ET (EE + NN)   // edges + self loops = 510000
#define NEG_SLOPE 0.2f
#define BN_EPS 1e-5f

struct LayerCfg { int cin, C, H; };
static const LayerCfg g_cfg[5] = {
    {128, 100, 5}, {500, 50, 5}, {250, 32, 4}, {128, 8, 4}, {32, 1, 1}
};

typedef short short8 __attribute__((ext_vector_type(8)));
typedef float f32x4 __attribute__((ext_vector_type(4)));

__device__ __forceinline__ unsigned short f2bf(float f) {
    unsigned int u = __builtin_bit_cast(unsigned int, f);
    u = (u + 0x7FFFu + ((u >> 16) & 1u)) >> 16;
    return (unsigned short)u;
}
__device__ __forceinline__ float bf2f(unsigned short h) {
    unsigned int u = ((unsigned int)h) << 16;
    return __builtin_bit_cast(float, u);
}

// ---------------- graph / CSR kernels ----------------

__global__ void ewsum_kernel(const float* __restrict__ ew, float* __restrict__ out, int E) {
    __shared__ float sdata[256];
    int tid = threadIdx.x;
    float s = 0.f;
    for (int i = blockIdx.x * blockDim.x + tid; i < E; i += gridDim.x * blockDim.x)
        s += ew[i];
    sdata[tid] = s;
    __syncthreads();
    for (int off = 128; off > 0; off >>= 1) {
        if (tid < off) sdata[tid] += sdata[tid + off];
        __syncthreads();
    }
    if (tid == 0) atomicAdd(out, sdata[0]);
}

__global__ void build_edges_kernel(const int* __restrict__ ei, const float* __restrict__ ew,
                                   const float* __restrict__ sum,
                                   int* __restrict__ srcv, int* __restrict__ dstv,
                                   float* __restrict__ ea, int* __restrict__ cnt) {
    int e = blockIdx.x * blockDim.x + threadIdx.x;
    if (e >= ET) return;
    int d;
    if (e < EE) {
        srcv[e] = ei[e];
        d = ei[EE + e];
        dstv[e] = d;
        ea[e]   = ew[e];
    } else {
        int n = e - EE;
        srcv[e] = n;
        d = n;
        dstv[e] = n;
        ea[e]   = sum[0] * (1.0f / (float)EE);
    }
    atomicAdd(&cnt[d], 1);
}

__global__ void scan_kernel(const int* __restrict__ cnt, int* __restrict__ off,
                            int* __restrict__ wptr) {
    __shared__ int lsum[1024];
    __shared__ int loff[1024];
    const int T = 1024;
    int t = threadIdx.x;
    int chunk = (NN + T - 1) / T;
    int base = t * chunk;
    int end = min(NN, base + chunk);
    int s = 0;
    for (int i = base; i < end; i++) s += cnt[i];
    lsum[t] = s;
    __syncthreads();
    if (t == 0) {
        int run = 0;
        for (int i = 0; i < T; i++) { loff[i] = run; run += lsum[i]; }
    }
    __syncthreads();
    int run = loff[t];
    for (int i = base; i < end; i++) {
        off[i] = run;
        wptr[i] = run;
        run += cnt[i];
    }
    if (t == 0) off[NN] = ET;
}

__global__ void fill_kernel(const int* __restrict__ dstv, const int* __restrict__ srcv,
                            const float* __restrict__ ea,
                            int* __restrict__ wptr, int* __restrict__ csr_src,
                            float* __restrict__ csr_ea) {
    int e = blockIdx.x * blockDim.x + threadIdx.x;
    if (e >= ET) return;
    int p = atomicAdd(&wptr[dstv[e]], 1);
    csr_src[p] = srcv[e];
    csr_ea[p]  = ea[e];
}

// ---------------- all-layer weight prep ----------------

struct PrepArgs {
    const float* W[5];
    const float* We[5];
    const float* ae[5];
    unsigned short* bh[5];
    unsigned short* bl[5];
    float* wedot;            // out: [5][8]
    int K[5], N[5], Kp[5], Np[5], C[5], H[5];
};

__global__ void wedot_all_kernel(PrepArgs a) {
    int tid = threadIdx.x;   // 64
    int l = tid >> 3, hd = tid & 7;
    if (l < 5 && hd < a.H[l]) {
        int C = a.C[l];
        const float* We = a.We[l] + hd * C;
        const float* ae = a.ae[l] + hd * C;
        float s = 0.f;
        for (int c = 0; c < C; c++) s += We[c] * ae[c];
        a.wedot[l * 8 + hd] = s;
    }
}

__global__ void transpose_all_kernel(PrepArgs a) {
    int l = blockIdx.z;
    int Kp = a.Kp[l], Np = a.Np[l], K = a.K[l], N = a.N[l];
    int kb = blockIdx.x * 32, nb = blockIdx.y * 32;
    if (kb >= Kp || nb >= Np) return;
    const float* B = a.W[l];
    unsigned short* Bth = a.bh[l];
    unsigned short* Btl = a.bl[l];
    __shared__ float tile[32][33];
    int tx = threadIdx.x, ty = threadIdx.y;   // 32 x 8
#pragma unroll
    for (int i = 0; i < 4; i++) {
        int k = kb + ty + i * 8, n = nb + tx;
        tile[ty + i * 8][tx] = (k < K && n < N) ? B[(size_t)k * N + n] : 0.f;
    }
    __syncthreads();
#pragma unroll
    for (int i = 0; i < 4; i++) {
        int n = nb + ty + i * 8, k = kb + tx;
        if (n < Np && k < Kp) {
            float v = tile[tx][ty + i * 8];
            unsigned short hi = f2bf(v);
            unsigned short lo = f2bf(v - bf2f(hi));
            size_t idx = (size_t)n * Kp + k;
            Bth[idx] = hi;
            Btl[idx] = lo;
        }
    }
}

// ---------------- split-bf16 MFMA GEMM with optional fused BN+ReLU on A ----------------
// A pitched (Apitch=Kp), padded to Kp cols. If colsum!=null, staging applies
// v = max(v*scale[c]+shift[c], 0) (pad cols get scale=shift=0).
// Cm (f32) and Ch16 (bf16) outputs are each optional.
#define GBM 128
#define GBNT 128
#define GBK 32
#define ASTR 36
__global__ __launch_bounds__(256) void gemm_split_kernel(const float* __restrict__ A,
                                                         const unsigned short* __restrict__ Bt_hi,
                                                         const unsigned short* __restrict__ Bt_lo,
                                                         float* __restrict__ Cm,
                                                         unsigned short* __restrict__ Ch16,
                                                         int M, int Kp, int Nc,
                                                         const float* __restrict__ colsum,
                                                         const float* __restrict__ colsumsq,
                                                         const float* __restrict__ g,
                                                         const float* __restrict__ beta,
                                                         int D) {
    __shared__ short AsH[GBM * ASTR];
    __shared__ short AsL[GBM * ASTR];
    __shared__ short BsH[GBNT * ASTR];
    __shared__ short BsL[GBNT * ASTR];
    __shared__ float sscale[512];
    __shared__ float sshift[512];
    int tid = threadIdx.x;
    bool bn = (colsum != nullptr);
    if (bn) {
        for (int c = tid; c < Kp; c += 256) {
            float sc = 0.f, sh = 0.f;
            if (c < D) {
                float mu = colsum[c] * (1.0f / (float)NN);
                float var = colsumsq[c] * (1.0f / (float)NN) - mu * mu;
                sc = g[c] * rsqrtf(var + BN_EPS);
                sh = beta[c] - mu * sc;
            }
            sscale[c] = sc;
            sshift[c] = sh;
        }
        __syncthreads();
    }
    int wave = tid >> 6, lane = tid & 63;
    int q = lane >> 4, r = lane & 15;
    int m0 = blockIdx.y * GBM, n0 = blockIdx.x * GBNT;
    int wm = (wave & 1) * 64, wn = (wave >> 1) * 64;
    f32x4 acc[4][4];
#pragma unroll
    for (int i = 0; i < 4; i++)
#pragma unroll
        for (int j = 0; j < 4; j++) acc[i][j] = (f32x4)(0.f);

    int arow2 = tid >> 1;          // 0..127
    int acol2 = (tid & 1) * 16;    // 0 or 16
    int brow = tid >> 2;
    int bcol = (tid & 3) * 8;

    int ksteps = Kp / GBK;
    for (int ks = 0; ks < ksteps; ks++) {
        int k0 = ks * GBK;
        {
            int m = m0 + arow2;
            float v[16];
            if (m < M) {
                const float* Ap = A + (size_t)m * Kp + k0 + acol2;
                float4 f0 = *(const float4*)(Ap);
                float4 f1 = *(const float4*)(Ap + 4);
                float4 f2 = *(const float4*)(Ap + 8);
                float4 f3 = *(const float4*)(Ap + 12);
                v[0]=f0.x; v[1]=f0.y; v[2]=f0.z; v[3]=f0.w;
                v[4]=f1.x; v[5]=f1.y; v[6]=f1.z; v[7]=f1.w;
                v[8]=f2.x; v[9]=f2.y; v[10]=f2.z; v[11]=f2.w;
                v[12]=f3.x; v[13]=f3.y; v[14]=f3.z; v[15]=f3.w;
                if (bn) {
                    int cb = k0 + acol2;
#pragma unroll
                    for (int i = 0; i < 16; i++)
                        v[i] = fmaxf(v[i] * sscale[cb + i] + sshift[cb + i], 0.f);
                }
            } else {
#pragma unroll
                for (int i = 0; i < 16; i++) v[i] = 0.f;
            }
#pragma unroll
            for (int i = 0; i < 16; i++) {
                unsigned short hi = f2bf(v[i]);
                unsigned short lo = f2bf(v[i] - bf2f(hi));
                AsH[arow2 * ASTR + acol2 + i] = (short)hi;
                AsL[arow2 * ASTR + acol2 + i] = (short)lo;
            }
        }
#pragma unroll
        for (int p = 0; p < 2; p++) {
            int row = p * 64 + brow;
            size_t gidx = (size_t)(n0 + row) * Kp + k0 + bcol;
            *((uint4*)(BsH + row * ASTR + bcol)) = *((const uint4*)(Bt_hi + gidx));
            *((uint4*)(BsL + row * ASTR + bcol)) = *((const uint4*)(Bt_lo + gidx));
        }
        __syncthreads();
        short8 ah[4], al[4], bh[4], bl[4];
#pragma unroll
        for (int i = 0; i < 4; i++) {
            ah[i] = *((const short8*)(AsH + (wm + i * 16 + r) * ASTR + q * 8));
            al[i] = *((const short8*)(AsL + (wm + i * 16 + r) * ASTR + q * 8));
        }
#pragma unroll
        for (int j = 0; j < 4; j++) {
            bh[j] = *((const short8*)(BsH + (wn + j * 16 + r) * ASTR + q * 8));
            bl[j] = *((const short8*)(BsL + (wn + j * 16 + r) * ASTR + q * 8));
        }
#pragma unroll
        for (int i = 0; i < 4; i++)
#pragma unroll
            for (int j = 0; j < 4; j++) {
                acc[i][j] = __builtin_amdgcn_mfma_f32_16x16x32_bf16(ah[i], bh[j], acc[i][j], 0, 0, 0);
                acc[i][j] = __builtin_amdgcn_mfma_f32_16x16x32_bf16(ah[i], bl[j], acc[i][j], 0, 0, 0);
                acc[i][j] = __builtin_amdgcn_mfma_f32_16x16x32_bf16(al[i], bh[j], acc[i][j], 0, 0, 0);
            }
        __syncthreads();
    }
#pragma unroll
    for (int i = 0; i < 4; i++) {
#pragma unroll
        for (int j = 0; j < 4; j++) {
#pragma unroll
            for (int reg = 0; reg < 4; reg++) {
                int mrow = m0 + wm + i * 16 + q * 4 + reg;
                int ncol = n0 + wn + j * 16 + r;
                if (mrow < M && ncol < Nc) {
                    float val = acc[i][j][reg];
                    if (Cm)   Cm[(size_t)mrow * Nc + ncol] = val;
                    if (Ch16) Ch16[(size_t)mrow * Nc + ncol] = f2bf(val);
                }
            }
        }
    }
}

// layer-5 fused GEMV: h = X @ w (K=32, Nc=1) + al_src/al_dst scalars
__global__ void gemv_l5_kernel(const float* __restrict__ X, const float* __restrict__ W,
                               const float* __restrict__ a_s, const float* __restrict__ a_d,
                               float* __restrict__ h, float* __restrict__ al_src,
                               float* __restrict__ al_dst) {
    __shared__ float w[32];
    if (threadIdx.x < 32) w[threadIdx.x] = W[threadIdx.x];
    __syncthreads();
    int n = blockIdx.x * blockDim.x + threadIdx.x;
    if (n >= NN) return;
    const float* row = X + (size_t)n * 32;
    float s = 0.f;
#pragma unroll
    for (int i = 0; i < 8; i++) {
        float4 f = *(const float4*)(row + i * 4);
        s += f.x * w[i * 4] + f.y * w[i * 4 + 1] + f.z * w[i * 4 + 2] + f.w * w[i * 4 + 3];
    }
    h[n] = s;
    al_src[n] = s * a_s[0];
    al_dst[n] = s * a_d[0];
}

// wave-per-node attention dots, f32 h (layer 4)
__global__ void al_wave_kernel(const float* __restrict__ h, const float* __restrict__ a_s,
                               const float* __restrict__ a_d, float* __restrict__ al_src,
                               float* __restrict__ al_dst, int H, int C, int HC) {
    int w = (blockIdx.x * blockDim.x + threadIdx.x) >> 6;
    int lane = threadIdx.x & 63;
    if (w >= NN) return;
    const float* row = h + (size_t)w * HC;
    float s1[5] = {0.f, 0.f, 0.f, 0.f, 0.f};
    float s2[5] = {0.f, 0.f, 0.f, 0.f, 0.f};
#pragma unroll
    for (int hd = 0; hd < 5; hd++) {
        if (hd >= H) break;
        int base = hd * C;
        for (int c = lane; c < C; c += 64) {
            float v = row[base + c];
            s1[hd] += v * a_s[base + c];
            s2[hd] += v * a_d[base + c];
        }
    }
#pragma unroll
    for (int hd = 0; hd < 5; hd++) {
        if (hd >= H) break;
#pragma unroll
        for (int off = 32; off > 0; off >>= 1) {
            s1[hd] += __shfl_xor(s1[hd], off, 64);
            s2[hd] += __shfl_xor(s2[hd], off, 64);
        }
    }
    if (lane == 0) {
#pragma unroll
        for (int hd = 0; hd < 5; hd++) {
            if (hd >= H) break;
            al_src[(size_t)w * H + hd] = s1[hd];
            al_dst[(size_t)w * H + hd] = s2[hd];
        }
    }
}

// wave-per-node attention dots, bf16 h (layers 1-3); 2 bf16 per lane-load
__global__ void al_wave_h16_kernel(const unsigned short* __restrict__ h16,
                                   const float* __restrict__ a_s,
                                   const float* __restrict__ a_d,
                                   float* __restrict__ al_src, float* __restrict__ al_dst,
                                   int H, int C, int HC) {
    int w = (blockIdx.x * blockDim.x + threadIdx.x) >> 6;
    int lane = threadIdx.x & 63;
    if (w >= NN) return;
    const unsigned short* row = h16 + (size_t)w * HC;
    float s1[5] = {0.f, 0.f, 0.f, 0.f, 0.f};
    float s2[5] = {0.f, 0.f, 0.f, 0.f, 0.f};
#pragma unroll
    for (int hd = 0; hd < 5; hd++) {
        if (hd >= H) break;
        int base = hd * C;   // C even -> base even -> 4B aligned
        for (int c = lane * 2; c < C; c += 128) {
            unsigned int u = *(const unsigned int*)(row + base + c);
            float v0 = bf2f((unsigned short)(u & 0xffffu));
            float v1 = bf2f((unsigned short)(u >> 16));
            s1[hd] += v0 * a_s[base + c] + v1 * a_s[base + c + 1];
            s2[hd] += v0 * a_d[base + c] + v1 * a_d[base + c + 1];
        }
    }
#pragma unroll
    for (int hd = 0; hd < 5; hd++) {
        if (hd >= H) break;
#pragma unroll
        for (int off = 32; off > 0; off >>= 1) {
            s1[hd] += __shfl_xor(s1[hd], off, 64);
            s2[hd] += __shfl_xor(s2[hd], off, 64);
        }
    }
    if (lane == 0) {
#pragma unroll
        for (int hd = 0; hd < 5; hd++) {
            if (hd >= H) break;
            al_src[(size_t)w * H + hd] = s1[hd];
            al_dst[(size_t)w * H + hd] = s2[hd];
        }
    }
}

// fused logit + ONLINE segment softmax
__global__ void attn_kernel(const float* __restrict__ al_src,
                            const float* __restrict__ al_dst,
                            const int* __restrict__ csr_src,
                            const float* __restrict__ csr_ea,
                            const float* __restrict__ we_dot,
                            const int* __restrict__ off,
                            float* __restrict__ alpha_t, int H, int NH) {
    int t = blockIdx.x * blockDim.x + threadIdx.x;
    if (t >= NH) return;
    int n = t / H, hd = t - n * H;
    int s = off[n], e = off[n + 1];
    float ad = al_dst[(size_t)n * H + hd];
    float wd = we_dot[hd];
    float* arow = alpha_t + (size_t)hd * ET;
    float m = -INFINITY, l = 0.f;
    int p = s;
    for (; p + 3 < e; p += 4) {
        int s0 = csr_src[p], s1 = csr_src[p + 1], s2 = csr_src[p + 2], s3 = csr_src[p + 3];
        float w0 = csr_ea[p], w1 = csr_ea[p + 1], w2 = csr_ea[p + 2], w3 = csr_ea[p + 3];
        float l0 = al_src[(size_t)s0 * H + hd] + ad + w0 * wd;
        float l1 = al_src[(size_t)s1 * H + hd] + ad + w1 * wd;
        float l2 = al_src[(size_t)s2 * H + hd] + ad + w2 * wd;
        float l3 = al_src[(size_t)s3 * H + hd] + ad + w3 * wd;
        l0 = (l0 >= 0.f) ? l0 : NEG_SLOPE * l0;
        l1 = (l1 >= 0.f) ? l1 : NEG_SLOPE * l1;
        l2 = (l2 >= 0.f) ? l2 : NEG_SLOPE * l2;
        l3 = (l3 >= 0.f) ? l3 : NEG_SLOPE * l3;
        arow[p] = l0; arow[p + 1] = l1; arow[p + 2] = l2; arow[p + 3] = l3;
        float mq = fmaxf(fmaxf(l0, l1), fmaxf(l2, l3));
        float nm = fmaxf(m, mq);
        l = l * __expf(m - nm)
          + __expf(l0 - nm) + __expf(l1 - nm) + __expf(l2 - nm) + __expf(l3 - nm);
        m = nm;
    }
    for (; p < e; p++) {
        float lg = al_src[(size_t)csr_src[p] * H + hd] + ad + csr_ea[p] * wd;
        lg = (lg >= 0.f) ? lg : NEG_SLOPE * lg;
        arow[p] = lg;
        float nm = fmaxf(m, lg);
        l = l * __expf(m - nm) + __expf(lg - nm);
        m = nm;
    }
    float inv = 1.f / fmaxf(l, 1e-16f);
    for (p = s; p < e; p++) arow[p] = __expf(arow[p] - m) * inv;
}

// bf16 gather aggregate, 4 cols/thread (4|C); pitched output
__global__ void aggregate_v4h_kernel(const unsigned short* __restrict__ h16,
                                     const float* __restrict__ alpha_t,
                                     const int* __restrict__ off,
                                     const int* __restrict__ csr_src,
                                     const float* __restrict__ bias,
                                     float* __restrict__ out,
                                     int C, int HC, int HC4, int total4, int opitch) {
    int t = blockIdx.x * blockDim.x + threadIdx.x;
    if (t >= total4) return;
    int n = t / HC4, j4 = t - n * HC4;
    int j = j4 * 4;
    int hd = j / C;
    const float* arow = alpha_t + (size_t)hd * ET;
    int s = off[n], e = off[n + 1];
    float4 acc = make_float4(0.f, 0.f, 0.f, 0.f);
    int p = s;
    for (; p + 3 < e; p += 4) {
        int idx[4]; float a[4];
#pragma unroll
        for (int u = 0; u < 4; u++) { idx[u] = csr_src[p + u]; a[u] = arow[p + u]; }
#pragma unroll
        for (int u = 0; u < 4; u++) {
            ushort4 uv = *(const ushort4*)(h16 + (size_t)idx[u] * HC + j);
            acc.x += a[u] * bf2f(uv.x);
            acc.y += a[u] * bf2f(uv.y);
            acc.z += a[u] * bf2f(uv.z);
            acc.w += a[u] * bf2f(uv.w);
        }
    }
    for (; p < e; p++) {
        int s0 = csr_src[p];
        float a0 = arow[p];
        ushort4 uv = *(const ushort4*)(h16 + (size_t)s0 * HC + j);
        acc.x += a0 * bf2f(uv.x);
        acc.y += a0 * bf2f(uv.y);
        acc.z += a0 * bf2f(uv.z);
        acc.w += a0 * bf2f(uv.w);
    }
    float4 bi = *(const float4*)(bias + j);
    float4 rr = make_float4(acc.x + bi.x, acc.y + bi.y, acc.z + bi.z, acc.w + bi.w);
    *(float4*)(out + (size_t)n * opitch + j) = rr;
}

// bf16 gather aggregate, 2 cols/thread (2|C) — C=50; pitched output
__global__ void aggregate_v2h_kernel(const unsigned short* __restrict__ h16,
                                     const float* __restrict__ alpha_t,
                                     const int* __restrict__ off,
                                     const int* __restrict__ csr_src,
                                     const float* __restrict__ bias,
                                     float* __restrict__ out,
                                     int C, int HC, int HC2, int total2, int opitch) {
    int t = blockIdx.x * blockDim.x + threadIdx.x;
    if (t >= total2) return;
    int n = t / HC2, j2 = t - n * HC2;
    int j = j2 * 2;
    int hd = j / C;
    const float* arow = alpha_t + (size_t)hd * ET;
    int s = off[n], e = off[n + 1];
    float2 acc = make_float2(0.f, 0.f);
    int p = s;
    for (; p + 3 < e; p += 4) {
        int idx[4]; float a[4];
#pragma unroll
        for (int u = 0; u < 4; u++) { idx[u] = csr_src[p + u]; a[u] = arow[p + u]; }
#pragma unroll
        for (int u = 0; u < 4; u++) {
            ushort2 uv = *(const ushort2*)(h16 + (size_t)idx[u] * HC + j);
            acc.x += a[u] * bf2f(uv.x);
            acc.y += a[u] * bf2f(uv.y);
        }
    }
    for (; p < e; p++) {
        int s0 = csr_src[p];
        float a0 = arow[p];
        ushort2 uv = *(const ushort2*)(h16 + (size_t)s0 * HC + j);
        acc.x += a0 * bf2f(uv.x);
        acc.y += a0 * bf2f(uv.y);
    }
    float2 bi = *(const float2*)(bias + j);
    *(float2*)(out + (size_t)n * opitch + j) = make_float2(acc.x + bi.x, acc.y + bi.y);
}

// f32 float4 aggregate (layer 4); fused relu; pitched output
__global__ void aggregate_v4_kernel(const float* __restrict__ hfeat,
                                    const float* __restrict__ alpha_t,
                                    const int* __restrict__ off,
                                    const int* __restrict__ csr_src,
                                    const float* __restrict__ bias,
                                    float* __restrict__ out,
                                    int C, int HC, int HC4, int total4, int relu, int opitch) {
    int t = blockIdx.x * blockDim.x + threadIdx.x;
    if (t >= total4) return;
    int n = t / HC4, j4 = t - n * HC4;
    int j = j4 * 4;
    int hd = j / C;
    const float* arow = alpha_t + (size_t)hd * ET;
    int s = off[n], e = off[n + 1];
    float4 acc = make_float4(0.f, 0.f, 0.f, 0.f);
    int p = s;
    for (; p + 3 < e; p += 4) {
        int idx[4]; float a[4];
#pragma unroll
        for (int u = 0; u < 4; u++) { idx[u] = csr_src[p + u]; a[u] = arow[p + u]; }
#pragma unroll
        for (int u = 0; u < 4; u++) {
            float4 f = *(const float4*)(hfeat + (size_t)idx[u] * HC + j);
            acc.x += a[u] * f.x; acc.y += a[u] * f.y; acc.z += a[u] * f.z; acc.w += a[u] * f.w;
        }
    }
    for (; p < e; p++) {
        int s0 = csr_src[p];
        float a0 = arow[p];
        float4 f0 = *(const float4*)(hfeat + (size_t)s0 * HC + j);
        acc.x += a0 * f0.x; acc.y += a0 * f0.y; acc.z += a0 * f0.z; acc.w += a0 * f0.w;
    }
    float4 bi = *(const float4*)(bias + j);
    float4 rr = make_float4(acc.x + bi.x, acc.y + bi.y, acc.z + bi.z, acc.w + bi.w);
    if (relu) {
        rr.x = fmaxf(rr.x, 0.f); rr.y = fmaxf(rr.y, 0.f);
        rr.z = fmaxf(rr.z, 0.f); rr.w = fmaxf(rr.w, 0.f);
    }
    *(float4*)(out + (size_t)n * opitch + j) = rr;
}

// scalar fallback (layer 5, HC==1)
__global__ void aggregate_kernel(const float* __restrict__ hfeat,
                                 const float* __restrict__ alpha_t,
                                 const int* __restrict__ off, const int* __restrict__ csr_src,
                                 const float* __restrict__ bias, float* __restrict__ out,
                                 int total) {
    int t = blockIdx.x * blockDim.x + threadIdx.x;
    if (t >= total) return;
    int n = t;
    int s = off[n], e = off[n + 1];
    float acc = 0.f;
    int p = s;
    for (; p + 3 < e; p += 4) {
        acc += alpha_t[p] * hfeat[csr_src[p]]
             + alpha_t[p + 1] * hfeat[csr_src[p + 1]]
             + alpha_t[p + 2] * hfeat[csr_src[p + 2]]
             + alpha_t[p + 3] * hfeat[csr_src[p + 3]];
    }
    for (; p < e; p++) acc += alpha_t[p] * hfeat[csr_src[p]];
    out[n] = acc + bias[0];
}

// ---------------- BN stats (pitched) ----------------

__global__ void bn_stats_kernel(const float* __restrict__ x, float* __restrict__ colsum,
                                float* __restrict__ colsumsq, int D, int pitch) {
    int rows_per_block = (NN + gridDim.x - 1) / gridDim.x;
    int r0 = blockIdx.x * rows_per_block;
    int r1 = min(NN, r0 + rows_per_block);
    int c0 = threadIdx.x;
    int c1 = threadIdx.x + 256;
    float s0 = 0.f, q0 = 0.f, s1 = 0.f, q1 = 0.f;
    for (int r = r0; r < r1; r++) {
        const float* row = x + (size_t)r * pitch;
        if (c0 < D) { float v = row[c0]; s0 += v; q0 += v * v; }
        if (c1 < D) { float v = row[c1]; s1 += v; q1 += v * v; }
    }
    if (c0 < D) { atomicAdd(&colsum[c0], s0); atomicAdd(&colsumsq[c0], q0); }
    if (c1 < D) { atomicAdd(&colsum[c1], s1); atomicAdd(&colsumsq[c1], q1); }
}

// ---------------- host orchestration ----------------

static inline size_t align_up(size_t v, size_t a) { return (v + a - 1) / a * a; }

extern "C" void kernel_launch(void* const* d_in, const int* in_sizes, int n_in,
                              void* d_out, int out_size, void* d_ws, size_t ws_size,
                              hipStream_t stream) {
    const float* x_in = (const float*)d_in[0];
    const int* ei     = (const int*)d_in[1];
    const float* ew   = (const float*)d_in[2];

    char* pws = (char*)d_ws;
    size_t off_b = 0;
    auto alloc = [&](size_t bytes) -> void* {
        void* rp = pws + off_b;
        off_b = align_up(off_b + bytes, 256);
        return rp;
    };
    float* B0      = (float*)alloc((size_t)NN * 500 * 4);      // f32 h (layer 4 only) / l5 h
    float* B1      = (float*)alloc((size_t)NN * 512 * 4);      // activations (pitched)
    unsigned short* H16 = (unsigned short*)alloc((size_t)NN * 500 * 2);
    float* alpha_t = (float*)alloc((size_t)ET * 5 * 4);
    unsigned short* Wt_hi = (unsigned short*)alloc((size_t)600 * 512 * 2);
    unsigned short* Wt_lo = (unsigned short*)alloc((size_t)600 * 512 * 2);
    float* al_src  = (float*)alloc((size_t)NN * 5 * 4);
    float* al_dst  = (float*)alloc((size_t)NN * 5 * 4);
    float* ea      = (float*)alloc((size_t)ET * 4);
    float* csr_ea  = (float*)alloc((size_t)ET * 4);
    int* srcv      = (int*)alloc((size_t)ET * 4);
    int* dstv      = (int*)alloc((size_t)ET * 4);
    int* csr_src   = (int*)alloc((size_t)ET * 4);
    int* offarr    = (int*)alloc((size_t)(NN + 1) * 4);
    int* wptr      = (int*)alloc((size_t)NN * 4);
    float* esum    = (float*)alloc(4);                 // esum+cnt adjacent: one memset
    int* cnt       = (int*)alloc((size_t)NN * 4);
    float* we_dot  = (float*)alloc(40 * 4);
    float* colsum  = (float*)alloc(512 * 4);
    float* colsumsq= (float*)alloc(512 * 4);
    (void)ws_size; (void)n_in; (void)in_sizes; (void)out_size;

    int Kp[5], Np[5];
    size_t wtoff[5];
    size_t acc_off = 0;
    for (int l = 0; l < 5; l++) {
        int K = g_cfg[l].cin, HC = g_cfg[l].C * g_cfg[l].H;
        Kp[l] = (K + 31) / 32 * 32;
        Np[l] = (HC + 127) / 128 * 128;
        wtoff[l] = acc_off;
        acc_off += (size_t)Kp[l] * Np[l];
    }

    PrepArgs pa;
    for (int l = 0; l < 5; l++) {
        pa.W[l]  = (const float*)d_in[3 + l * 6 + 0];
        pa.We[l] = (const float*)d_in[3 + l * 6 + 3];
        pa.ae[l] = (const float*)d_in[3 + l * 6 + 4];
        pa.bh[l] = Wt_hi + wtoff[l];
        pa.bl[l] = Wt_lo + wtoff[l];
        pa.K[l] = g_cfg[l].cin;
        pa.N[l] = g_cfg[l].C * g_cfg[l].H;
        pa.Kp[l] = Kp[l];
        pa.Np[l] = Np[l];
        pa.C[l] = g_cfg[l].C;
        pa.H[l] = g_cfg[l].H;
    }
    pa.wedot = we_dot;

    // graph & CSR build (esum + cnt zeroed in one shot — adjacent in ws)
    hipMemsetAsync(esum, 0, ((char*)(cnt + NN)) - ((char*)esum), stream);
    ewsum_kernel<<<256, 256, 0, stream>>>(ew, esum, EE);
    int ebl = (ET + 255) / 256;
    build_edges_kernel<<<ebl, 256, 0, stream>>>(ei, ew, esum, srcv, dstv, ea, cnt);
    scan_kernel<<<1, 1024, 0, stream>>>(cnt, offarr, wptr);
    fill_kernel<<<ebl, 256, 0, stream>>>(dstv, srcv, ea, wptr, csr_src, csr_ea);

    // all-layer weight prep
    wedot_all_kernel<<<1, 64, 0, stream>>>(pa);
    transpose_all_kernel<<<dim3(16, 16, 5), dim3(32, 8), 0, stream>>>(pa);

    for (int l = 0; l < 5; l++) {
        const LayerCfg& cf = g_cfg[l];
        int H = cf.H, C = cf.C;
        int HC = H * C;
        const float* a_s = (const float*)d_in[3 + l * 6 + 1];
        const float* a_d = (const float*)d_in[3 + l * 6 + 2];
        const float* b   = (const float*)d_in[3 + l * 6 + 5];

        const float* X = (l == 0) ? x_in : B1;
        float* hbuf = B0;
        float* outbuf = (l == 4) ? (float*)d_out : B1;
        bool big = (l < 3);                       // layers 1-3: bf16-only h
        int opitch = (l == 4) ? 1 : Kp[l + 1];    // out pitch = next layer's Kp
        int NH = NN * H;

        if (l == 4) {
            gemv_l5_kernel<<<(NN + 255) / 256, 256, 0, stream>>>(
                X, pa.W[4], a_s, a_d, hbuf, al_src, al_dst);
        } else {
            const float* cs = (l >= 1) ? colsum : nullptr;
            const float* cq = (l >= 1) ? colsumsq : nullptr;
            const float* gg = (l >= 1) ? (const float*)d_in[33 + (l - 1) * 2 + 0] : nullptr;
            const float* bb = (l >= 1) ? (const float*)d_in[33 + (l - 1) * 2 + 1] : nullptr;
            int Din = (l >= 1) ? g_cfg[l - 1].C * g_cfg[l - 1].H : 0;
            dim3 ggrid(Np[l] / GBNT, (NN + GBM - 1) / GBM);
            gemm_split_kernel<<<ggrid, 256, 0, stream>>>(X, Wt_hi + wtoff[l], Wt_lo + wtoff[l],
                                                         big ? nullptr : hbuf,
                                                         big ? H16 : nullptr,
                                                         NN, Kp[l], HC, cs, cq, gg, bb, Din);
            int alblocks = (NN * 64 + 255) / 256;
            if (big) {
                al_wave_h16_kernel<<<alblocks, 256, 0, stream>>>(H16, a_s, a_d, al_src, al_dst, H, C, HC);
            } else {
                al_wave_kernel<<<alblocks, 256, 0, stream>>>(hbuf, a_s, a_d, al_src, al_dst, H, C, HC);
            }
        }

        attn_kernel<<<(NH + 255) / 256, 256, 0, stream>>>(al_src, al_dst, csr_src, csr_ea,
                                                          we_dot + l * 8, offarr, alpha_t, H, NH);

        if (big && (C & 3) == 0) {
            int HC4 = HC / 4;
            int total4 = NN * HC4;
            aggregate_v4h_kernel<<<(total4 + 255) / 256, 256, 0, stream>>>(
                H16, alpha_t, offarr, csr_src, b, outbuf, C, HC, HC4, total4, opitch);
        } else if (big) {
            int HC2 = HC / 2;
            int total2 = NN * HC2;
            aggregate_v2h_kernel<<<(total2 + 255) / 256, 256, 0, stream>>>(
                H16, alpha_t, offarr, csr_src, b, outbuf, C, HC, HC2, total2, opitch);
        } else if (l == 3) {
            int HC4 = HC / 4;
            int total4 = NN * HC4;
            aggregate_v4_kernel<<<(total4 + 255) / 256, 256, 0, stream>>>(
                hbuf, alpha_t, offarr, csr_src, b, outbuf, C, HC, HC4, total4, 1, opitch);
        } else {
            aggregate_kernel<<<(NN + 255) / 256, 256, 0, stream>>>(
                hbuf, alpha_t, offarr, csr_src, b, outbuf, NN);
        }

        // BN stats for layers 0..2 (consumed by next layer's GEMM staging)
        if (l < 3) {
            int D = HC;
            hipMemsetAsync(colsum, 0, 2 * 512 * 4, stream);
            bn_stats_kernel<<<512, 256, 0, stream>>>(outbuf, colsum, colsumsq, D, opitch);
        }
    }
}